// Round 5
// baseline (639.271 us; speedup 1.0000x reference)
//
#include <hip/hip_runtime.h>
#include <math.h>

#define BB 4
#define NN 1024
#define KK 512
#define HH 8
#define DHh 64
#define HIDd 2048
#define BN (BB*NN)

typedef unsigned short u16;
typedef __attribute__((ext_vector_type(8))) short bf16x8;
typedef __attribute__((ext_vector_type(4))) float f32x4;

// ---------------------------------------------------------------- helpers
__device__ __forceinline__ float gelu_tanh(float x){
    float x3 = x*x*x;
    float t = tanhf(0.7978845608028654f*(x + 0.044715f*x3));
    return 0.5f*x*(1.0f+t);
}
__device__ __forceinline__ u16 f2bf(float x){
    unsigned int u = __float_as_uint(x);
    unsigned int r = (u + 0x7fffu + ((u>>16)&1u)) >> 16;
    return (u16)r;
}
__device__ __forceinline__ float bf2f(u16 b){
    return __uint_as_float(((unsigned int)b)<<16);
}
__device__ __forceinline__ void gload16(const void* g, void* l){
    __builtin_amdgcn_global_load_lds((__attribute__((address_space(1))) void*)g,
                                     (__attribute__((address_space(3))) void*)l, 16, 0, 0);
}
__device__ __forceinline__ void wsplit(u16* hi, u16* lo, size_t o, float v){
    u16 h = f2bf(v);
    hi[o] = h;
    if (lo) lo[o] = f2bf(v - bf2f(h));
}

// ---------------------------------------------------------------- generic transpose-split (used for h^T in phase E)
__global__ __launch_bounds__(256) void split_t_k(
    const float* __restrict__ src, u16* __restrict__ hi, u16* __restrict__ lo,
    int Kc, int Nc, long sS, long sD, int square)
{
    __shared__ float t[32][33];
    const int n0 = blockIdx.x*32, k0 = blockIdx.y*32, bz = blockIdx.z;
    const float* S = src + (long)bz*sS;
    const int tx = threadIdx.x & 31, ty = threadIdx.x >> 5;
    for (int r = ty; r < 32; r += 8){
        float v = S[(long)(k0+r)*Nc + n0+tx];
        if (square) v *= v;
        t[r][tx] = v;
    }
    __syncthreads();
    for (int r = ty; r < 32; r += 8){
        float v = t[tx][r];
        long o = (long)bz*sD + (long)(n0+r)*Kc + k0 + tx;
        wsplit(hi, lo, o, v);
    }
}

// ---------------------------------------------------------------- all weight prep in one dispatch, grid (64,16,9)
__global__ __launch_bounds__(256) void wmega_k(
    const float* __restrict__ Wq, const float* __restrict__ Wk,
    const float* __restrict__ Wv, const float* __restrict__ Wo,
    const float* __restrict__ W1, const float* __restrict__ W2,
    const float* __restrict__ gen,
    u16* __restrict__ WQKVh, u16* __restrict__ WQKVl, u16* __restrict__ WoTh,
    u16* __restrict__ WSQKh, u16* __restrict__ WSQKl,
    u16* __restrict__ W1Th, u16* __restrict__ W2Th, u16* __restrict__ GFh)
{
    const int z = blockIdx.z;
    const int tid = threadIdx.x;
    if (z == 8){   // gflat: copy gen(3,K,K) -> GFh[k][g*512+l]
        if (blockIdx.x >= 48) return;
        const int c0 = blockIdx.x*32, k0 = blockIdx.y*32;
        const int tx = tid&31, ty = tid>>5;
        const int g = c0/KK, l0 = c0%KK;
        for (int r=ty; r<32; r+=8)
            GFh[(size_t)(k0+r)*(3*KK) + c0+tx] =
                f2bf(gen[(size_t)g*KK*KK + (size_t)(k0+r)*KK + l0+tx]);
        return;
    }
    __shared__ float t[32][33];
    const float* src; u16* hi; u16* lo=0; int sq=0;
    int n0, k0, Kc, Nc;
    const size_t KK2 = (size_t)KK*KK;
    if (z < 6){
        if (blockIdx.x >= 16) return;
        n0 = blockIdx.x*32; k0 = blockIdx.y*32; Kc=KK; Nc=KK;
        if      (z==0){ src=Wq; hi=WQKVh;       lo=WQKVl; }
        else if (z==1){ src=Wk; hi=WQKVh+KK2;   lo=WQKVl+KK2; }
        else if (z==2){ src=Wv; hi=WQKVh+2*KK2; lo=WQKVl+2*KK2; }
        else if (z==3){ src=Wo; hi=WoTh; }
        else if (z==4){ src=Wq; hi=WSQKh;       lo=WSQKl; sq=1; }
        else          { src=Wk; hi=WSQKh+KK2;   lo=WSQKl+KK2; sq=1; }
    } else if (z == 6){  // W1 [512][2048] -> [2048][512]
        src=W1; hi=W1Th; Kc=KK; Nc=HIDd;
        n0 = blockIdx.x*32; k0 = blockIdx.y*32;
    } else {             // W2 [2048][512] -> [512][2048]
        src=W2; hi=W2Th; Kc=HIDd; Nc=KK;
        n0 = blockIdx.y*32; k0 = blockIdx.x*32;
    }
    const int tx=tid&31, ty=tid>>5;
    for (int r=ty;r<32;r+=8){
        float v = src[(long)(k0+r)*Nc + n0+tx];
        if (sq) v*=v;
        t[r][tx]=v;
    }
    __syncthreads();
    for (int r=ty;r<32;r+=8){
        float v = t[tx][r];
        long o = (long)(n0+r)*Kc + k0+tx;
        wsplit(hi, lo, o, v);
    }
}

// ---------------------------------------------------------------- MFMA GEMM 128x128, single product
// depth-2 / single-__syncthreads pipeline, 32 KB LDS. xyflip swaps grid roles.
__global__ __launch_bounds__(256) void gemm_mfma_k(
    const u16* __restrict__ Ah, const u16* __restrict__ Bh,
    float* __restrict__ C, u16* __restrict__ Chi, u16* __restrict__ Clo,
    int M, int Kc, int Nc, int lda,
    long sA, long sB, long sC, const float* __restrict__ bias, int act,
    int xyflip)
{
    __shared__ u16 shA[2][128*32], shB[2][128*32];
    const int bx = xyflip ? blockIdx.y : blockIdx.x;
    const int by = xyflip ? blockIdx.x : blockIdx.y;
    const int m0 = bx*128, n0 = by*128;
    const int bz = blockIdx.z;
    const u16* gAh = Ah + (long)bz*sA;
    const u16* gBh = Bh + (long)bz*sB;
    const int tid = threadIdx.x;
    const int wave = tid >> 6, lane = tid & 63;
    const int quad = lane >> 4, r16 = lane & 15;
    const int wm = (wave>>1)*64, wn = (wave&1)*64;

    f32x4 acc[4][4];
    #pragma unroll
    for (int i=0;i<4;i++)
        #pragma unroll
        for (int j=0;j<4;j++) acc[i][j] = (f32x4){0.f,0.f,0.f,0.f};

    auto stage = [&](int sel, int k0){
        #pragma unroll
        for (int half=0; half<2; ++half){
            int c = half*256 + tid;
            int row = c >> 2;
            int kg = ((c & 3) ^ ((row >> 1) & 3))*8;   // pre-swizzled global slot
            gload16(gAh + (long)(m0+row)*lda + k0 + kg, &shA[sel][c*8]);
            gload16(gBh + (long)(n0+row)*Kc  + k0 + kg, &shB[sel][c*8]);
        }
    };

    const int nsteps = Kc >> 5;
    stage(0, 0);
    __syncthreads();
    int cur = 0;
    const int swz = (quad ^ ((r16 >> 1) & 3))*8;       // undo swizzle on read
    for (int t = 0; t < nsteps; ++t){
        if (t+1 < nsteps) stage(cur^1, (t+1)<<5);
        bf16x8 afh[4], bfh[4];
        #pragma unroll
        for (int i=0;i<4;i++){
            afh[i] = *(const bf16x8*)&shA[cur][(wm+i*16+r16)*32 + swz];
            bfh[i] = *(const bf16x8*)&shB[cur][(wn+i*16+r16)*32 + swz];
        }
        #pragma unroll
        for (int i=0;i<4;i++)
            #pragma unroll
            for (int j=0;j<4;j++)
                acc[i][j] = __builtin_amdgcn_mfma_f32_16x16x32_bf16(afh[i], bfh[j], acc[i][j], 0,0,0);
        __syncthreads();
        cur ^= 1;
    }
    #pragma unroll
    for (int i=0;i<4;i++){
        #pragma unroll
        for (int j=0;j<4;j++){
            int gc = n0 + wn + j*16 + r16;
            if (gc >= Nc) continue;
            float bv = bias ? bias[gc] : 0.f;
            #pragma unroll
            for (int r=0;r<4;r++){
                long gr = m0 + wm + i*16 + quad*4 + r;
                float v = acc[i][j][r] + bv;
                if (act) v = gelu_tanh(v);
                long o = (long)bz*sC + gr*Nc + gc;
                if (C) C[o] = v;
                if (Chi){ u16 t = f2bf(v); Chi[o] = t; if (Clo) Clo[o] = f2bf(v - bf2f(t)); }
            }
        }
    }
}

// ---------------------------------------------------------------- MFMA GEMM 128x128, 3-product via VIRTUAL K
// K_virt = 3*Kc; segment 0: Ah*Bh, 1: Al*Bh, 2: Ah*Bl (pointer switch in staging).
// 32 KB LDS -> ~4 blocks/CU (vs 64 KB / 2 for the old PRODS=3 kernel).
__global__ __launch_bounds__(256) void gemm_v3_k(
    const u16* __restrict__ Ah, const u16* __restrict__ Al,
    const u16* __restrict__ Bh, const u16* __restrict__ Bl,
    float* __restrict__ C,
    int M, int Kc, int Nc, int lda,
    long sA, long sB, long sC, int cskip)
{
    __shared__ u16 shA[2][128*32], shB[2][128*32];
    const int m0 = blockIdx.x*128, n0 = blockIdx.y*128;
    if (cskip == 1 && n0 > m0 + 127) return;
    const int bz = blockIdx.z;
    const u16* gAh = Ah + (long)bz*sA;
    const u16* gAl = Al + (long)bz*sA;
    const u16* gBh = Bh + (long)bz*sB;
    const u16* gBl = Bl + (long)bz*sB;
    const int tid = threadIdx.x;
    const int wave = tid >> 6, lane = tid & 63;
    const int quad = lane >> 4, r16 = lane & 15;
    const int wm = (wave>>1)*64, wn = (wave&1)*64;

    f32x4 acc[4][4];
    #pragma unroll
    for (int i=0;i<4;i++)
        #pragma unroll
        for (int j=0;j<4;j++) acc[i][j] = (f32x4){0.f,0.f,0.f,0.f};

    const int segsteps = Kc >> 5;
    const int nsteps = 3*segsteps;
    auto stage = [&](int sel, int t){
        int seg = (t >= segsteps) + (t >= 2*segsteps);
        int k0 = (t - seg*segsteps) << 5;
        const u16* a = (seg==1) ? gAl : gAh;
        const u16* b = (seg==2) ? gBl : gBh;
        #pragma unroll
        for (int half=0; half<2; ++half){
            int c = half*256 + tid;
            int row = c >> 2;
            int kg = ((c & 3) ^ ((row >> 1) & 3))*8;
            gload16(a + (long)(m0+row)*lda + k0 + kg, &shA[sel][c*8]);
            gload16(b + (long)(n0+row)*Kc  + k0 + kg, &shB[sel][c*8]);
        }
    };

    stage(0, 0);
    __syncthreads();
    int cur = 0;
    const int swz = (quad ^ ((r16 >> 1) & 3))*8;
    for (int t = 0; t < nsteps; ++t){
        if (t+1 < nsteps) stage(cur^1, t+1);
        bf16x8 afh[4], bfh[4];
        #pragma unroll
        for (int i=0;i<4;i++){
            afh[i] = *(const bf16x8*)&shA[cur][(wm+i*16+r16)*32 + swz];
            bfh[i] = *(const bf16x8*)&shB[cur][(wn+i*16+r16)*32 + swz];
        }
        #pragma unroll
        for (int i=0;i<4;i++)
            #pragma unroll
            for (int j=0;j<4;j++)
                acc[i][j] = __builtin_amdgcn_mfma_f32_16x16x32_bf16(afh[i], bfh[j], acc[i][j], 0,0,0);
        __syncthreads();
        cur ^= 1;
    }
    #pragma unroll
    for (int i=0;i<4;i++){
        #pragma unroll
        for (int j=0;j<4;j++){
            int gc = n0 + wn + j*16 + r16;
            if (gc >= Nc) continue;
            #pragma unroll
            for (int r=0;r<4;r++){
                long gr = m0 + wm + i*16 + quad*4 + r;
                long o = (long)bz*sC + gr*Nc + gc;
                C[o] = acc[i][j][r];
            }
        }
    }
}

// ---------------------------------------------------------------- transport GEMM 64x64:
// out[r][n] = sum_g (esign*phi[r][g]) * sum_kd A[r][kd]*gen[g][n][kd]
// = virtual-K GEMM over GF[n*1536 + g*512 + kd] with per-segment register fold.
// Replaces the phi-expanded X3 buffers entirely.
__global__ __launch_bounds__(256) void tgemm_k(
    const u16* __restrict__ Ahh,   // [M][512] bf16
    const u16* __restrict__ GFh,   // [n][g*512+kd]
    const float* __restrict__ phi, float esign,
    float* __restrict__ C, u16* __restrict__ Chi, u16* __restrict__ Clo,
    const float* __restrict__ t_x, const float* __restrict__ t_a1,
    const float* __restrict__ t_res)
{
    __shared__ u16 shA[2][64*64], shB[2][64*64];
    const int m0 = blockIdx.x*64, n0 = blockIdx.y*64;
    const int tid = threadIdx.x;
    const int wave = tid >> 6, lane = tid & 63;
    const int quad = lane >> 4, r16 = lane & 15;
    const int wr = wave*16;

    float ph[3][4];
    #pragma unroll
    for (int sgi=0; sgi<3; ++sgi)
        #pragma unroll
        for (int r=0; r<4; ++r)
            ph[sgi][r] = esign*phi[(size_t)(m0+wr+quad*4+r)*3 + sgi];

    f32x4 acc[4], tot[4];
    #pragma unroll
    for (int j=0;j<4;j++){ acc[j] = (f32x4){0.f,0.f,0.f,0.f}; tot[j] = acc[j]; }

    auto stage = [&](int sel, int t){
        int seg = t >> 3, k0 = (t & 7) << 6;
        #pragma unroll
        for (int rep=0; rep<2; ++rep){
            int c = rep*256 + tid;
            int row = c >> 3;
            int kg = ((c & 7) ^ (row & 7))*8;
            gload16(Ahh + (long)(m0+row)*KK + k0 + kg, &shA[sel][c*8]);
            gload16(GFh + (long)(n0+row)*(3*KK) + seg*KK + k0 + kg, &shB[sel][c*8]);
        }
    };

    stage(0, 0);
    __syncthreads();
    int cur = 0;
    for (int t = 0; t < 24; ++t){
        if (t+1 < 24) stage(cur^1, t+1);
        #pragma unroll
        for (int kk=0; kk<2; ++kk){
            const int s = (((kk<<2)+quad) ^ (r16 & 7))*8;
            bf16x8 af = *(const bf16x8*)&shA[cur][(wr+r16)*64 + s];
            #pragma unroll
            for (int j=0;j<4;j++){
                bf16x8 bh = *(const bf16x8*)&shB[cur][(j*16+r16)*64 + s];
                acc[j] = __builtin_amdgcn_mfma_f32_16x16x32_bf16(af, bh, acc[j], 0,0,0);
            }
        }
        if ((t & 7) == 7){
            int sgi = t >> 3;
            #pragma unroll
            for (int j=0;j<4;j++){
                #pragma unroll
                for (int r=0;r<4;r++) tot[j][r] += ph[sgi][r]*acc[j][r];
                acc[j] = (f32x4){0.f,0.f,0.f,0.f};
            }
        }
        __syncthreads();
        cur ^= 1;
    }
    #pragma unroll
    for (int j=0;j<4;j++){
        int gc = n0 + j*16 + r16;
        #pragma unroll
        for (int r=0;r<4;r++){
            long gr = m0 + wr + quad*4 + r;
            float v = tot[j][r];
            long o = gr*(long)KK + gc;
            if (t_x){
                v = t_x[o] + t_a1[o] + 0.5f*v;
                if (t_res) v += t_res[o];
            }
            if (C) C[o] = v;
            if (Chi){ u16 t2 = f2bf(v); Chi[o] = t2; if (Clo) Clo[o] = f2bf(v - bf2f(t2)); }
        }
    }
}

// ---------------------------------------------------------------- MFMA GEMM 64x64
// depth-2 / single-__syncthreads pipeline, 32KB LDS. K-step 64. xyflip for L2 reuse.
// epilogue: fused FFN update (fmode 1=mid, 2=final)
__global__ __launch_bounds__(256) void gemm64_k(
    const u16* __restrict__ Ah, const u16* __restrict__ Bh,
    float* __restrict__ C, u16* __restrict__ Chi, u16* __restrict__ Clo,
    int M, int Kc, int Nc, int lda,
    long sA, long sB, long sC, const float* __restrict__ bias, int act,
    int ktrim, int xyflip,
    const float* __restrict__ f_hin, const float* __restrict__ f_bmh,
    const float* __restrict__ f_mup, const float* __restrict__ f_lr,
    u16* __restrict__ f_hh, float* __restrict__ f_hout,
    const float* __restrict__ f_mrb, const float* __restrict__ f_mn2,
    float* __restrict__ f_out, int fmode)
{
    __shared__ u16 shA[2][64*64], shB[2][64*64];
    const int bx = xyflip ? blockIdx.y : blockIdx.x;
    const int by = xyflip ? blockIdx.x : blockIdx.y;
    const int m0 = bx*64, n0 = by*64;
    const int bz = blockIdx.z;
    const u16* gA = Ah + (long)bz*sA;
    const u16* gB = Bh + (long)bz*sB;
    const int tid = threadIdx.x;
    const int wave = tid >> 6, lane = tid & 63;
    const int quad = lane >> 4, r16 = lane & 15;
    const int wr = wave*16;
    const int kend = ktrim ? min(Kc, m0 + 64) : Kc;
    const int nsteps = kend >> 6;

    f32x4 acc[4];
    #pragma unroll
    for (int j=0;j<4;j++) acc[j] = (f32x4){0.f,0.f,0.f,0.f};

    auto stage = [&](int sel, int k0){
        #pragma unroll
        for (int rep=0; rep<2; ++rep){
            int c = rep*256 + tid;
            int row = c >> 3;
            int kg = ((c & 7) ^ (row & 7))*8;     // pre-swizzled global slot
            gload16(gA + (long)(m0+row)*lda + k0 + kg, &shA[sel][c*8]);
            gload16(gB + (long)(n0+row)*Kc + k0 + kg, &shB[sel][c*8]);
        }
    };

    stage(0, 0);
    __syncthreads();
    int cur = 0;
    for (int t = 0; t < nsteps; ++t){
        if (t+1 < nsteps) stage(cur^1, (t+1)<<6);
        #pragma unroll
        for (int kk=0; kk<2; ++kk){
            const int s = (((kk<<2)+quad) ^ (r16 & 7))*8;   // undo swizzle on read
            bf16x8 af = *(const bf16x8*)&shA[cur][(wr+r16)*64 + s];
            #pragma unroll
            for (int j=0;j<4;j++){
                bf16x8 bh = *(const bf16x8*)&shB[cur][(j*16+r16)*64 + s];
                acc[j] = __builtin_amdgcn_mfma_f32_16x16x32_bf16(af, bh, acc[j], 0,0,0);
            }
        }
        __syncthreads();
        cur ^= 1;
    }
    float lrv = 0.f;
    if (fmode) lrv = *f_lr;
    #pragma unroll
    for (int j=0;j<4;j++){
        int gc = n0 + j*16 + r16;
        float bv = bias ? bias[gc] : 0.f;
        #pragma unroll
        for (int r=0;r<4;r++){
            long gr = m0 + wr + quad*4 + r;
            float v = acc[j][r] + bv;
            if (act) v = gelu_tanh(v);
            long o = (long)bz*sC + gr*Nc + gc;
            if (fmode){
                float hv = f_hin[o];
                float val = hv + lrv*(v - (1e-3f*(hv - f_mup[o]) + (hv - f_bmh[o])));
                if (fmode == 1){ f_hout[o] = val; f_hh[o] = f2bf(val); }
                else           { f_out[o] = f_mrb[o] + val - f_mn2[o]; }
            } else {
                if (C) C[o] = v;
                if (Chi){ u16 t = f2bf(v); Chi[o] = t; if (Clo) Clo[o] = f2bf(v - bf2f(t)); }
            }
        }
    }
}

// ---------------------------------------------------------------- LayerNorm (+bf16 out, +sigma split, +output copies)
__global__ __launch_bounds__(256) void ln_k(
    const float* __restrict__ x, const float* __restrict__ g,
    const float* __restrict__ be, float* __restrict__ y,
    u16* __restrict__ yh16,
    const float* __restrict__ sg, u16* __restrict__ sgh, u16* __restrict__ sgl,
    float* __restrict__ osig, const float* __restrict__ phi, float* __restrict__ ophi)
{
    __shared__ float sh[8];
    const int r = blockIdx.x, tid = threadIdx.x;
    const float* xr = x + (long)r*KK;
    float2 v = *(const float2*)(xr + tid*2);
    float s = v.x+v.y, s2 = v.x*v.x+v.y*v.y;
    #pragma unroll
    for (int o=32;o>0;o>>=1){ s += __shfl_down(s,o); s2 += __shfl_down(s2,o); }
    if ((tid&63)==0){ sh[tid>>6]=s; sh[4+(tid>>6)]=s2; }
    __syncthreads();
    s  = sh[0]+sh[1]+sh[2]+sh[3];
    s2 = sh[4]+sh[5]+sh[6]+sh[7];
    const float mean = s*(1.f/KK);
    const float var  = s2*(1.f/KK) - mean*mean;
    const float rs = rsqrtf(var + 1e-5f);
    float2 gg = *(const float2*)(g + tid*2);
    float2 bb = *(const float2*)(be + tid*2);
    float ox = (v.x-mean)*rs*gg.x + bb.x;
    float oy = (v.y-mean)*rs*gg.y + bb.y;
    long o = (long)r*KK + tid*2;
    *(float2*)(y + o) = make_float2(ox, oy);
    if (yh16){ yh16[o] = f2bf(ox); yh16[o+1] = f2bf(oy); }
    if (sgh){
        float2 sv = *(const float2*)(sg + o);
        wsplit(sgh, sgl, o,   sv.x);
        wsplit(sgh, sgl, o+1, sv.y);
        if (osig) *(float2*)(osig + o) = sv;
    }
    if (ophi && tid < 3) ophi[(size_t)r*3 + tid] = phi[(size_t)r*3 + tid];
}

// ---------------------------------------------------------------- merged attention prep + V transpose
__global__ __launch_bounds__(512) void prepvt_k(
    const float* __restrict__ QKV, const float* __restrict__ SQSK,
    u16* __restrict__ CFh, u16* __restrict__ CFl,
    u16* __restrict__ KSh, u16* __restrict__ KSl, float* __restrict__ dvec,
    u16* __restrict__ VTh)
{
    __shared__ float t[64][65];
    const int bx = blockIdx.x;
    const int tid = threadIdx.x;
    if (bx < BN){
        const int bn = bx;
        const int b = bn / NN, n = bn % NN;
        const int h = tid >> 6, d = tid & 63;
        float q  = QKV[(size_t)bn*1536 + h*DHh + d];
        float k  = QKV[(size_t)bn*1536 + KK + h*DHh + d];
        float sq = SQSK[(size_t)bn*1024 + h*DHh + d] + 1e-8f;
        float sk = SQSK[(size_t)bn*1024 + KK + h*DHh + d] + 1e-8f;
        float inv = 1.f/sq;
        float nqi = -2.f*q*inv;
        float skk = sk + k*k;
        const size_t base = ((size_t)(h*BB + b)*NN + n)*128;
        wsplit(CFh, CFl, base+d,    inv);
        wsplit(CFh, CFl, base+64+d, nqi);
        wsplit(KSh, KSl, base+d,    skk);
        wsplit(KSh, KSl, base+64+d, k);
        float dv = __logf(sk);
        #pragma unroll
        for (int o=32;o>0;o>>=1) dv += __shfl_down(dv,o);
        if (d==0) dvec[((size_t)h*BB + b)*NN + n] = dv;
        return;
    }
    const int idx = bx - BN;
    const int n0 = (idx & 15)*64;
    const int h = (idx>>4)&7;
    const int b = idx>>7;
    const int c4 = (tid & 15) * 4;
    const int r0 = tid >> 4;     // 0..31
    for (int rr = r0; rr < 64; rr += 32){
        float4 v = *(const float4*)(QKV + (size_t)(b*NN + n0 + rr)*1536 + 1024 + h*DHh + c4);
        t[c4+0][rr] = v.x; t[c4+1][rr] = v.y; t[c4+2][rr] = v.z; t[c4+3][rr] = v.w;
    }
    __syncthreads();
    for (int dd = r0; dd < 64; dd += 32){
        size_t base = ((size_t)(h*BB + b)*64 + dd)*NN + n0 + c4;
        #pragma unroll
        for (int q=0;q<4;q++) VTh[base+q] = f2bf(t[dd][c4+q]);
    }
}

// ---------------------------------------------------------------- softmax, all 8 heads in one pass
__global__ __launch_bounds__(256) void softmax_all_k(
    float* __restrict__ S, const float* __restrict__ dvec, u16* __restrict__ BMh)
{
    __shared__ float s_sc[NN];
    __shared__ float s_bm[NN];
    __shared__ float s_red[4];
    const int tid = threadIdx.x;
    const int b = blockIdx.x / NN, i = blockIdx.x % NN;
    const int L = i + 1;
    const int JEND = ((i >> 6) + 1) << 6;
    for (int j=tid;j<JEND;j+=256) s_bm[j]=0.f;
    for (int h=0; h<8; ++h){
        const int z = h*BB + b;
        float* row = S + ((long)z*NN + i)*NN;
        const float* dp = dvec + (size_t)z*NN;
        float lm = -3.0e38f;
        for (int j=tid;j<L;j+=256){
            float sc = -0.5f*row[j] + 0.5f*dp[j];
            s_sc[j] = sc;
            lm = fmaxf(lm, sc);
        }
        #pragma unroll
        for (int o=32;o>0;o>>=1) lm = fmaxf(lm, __shfl_xor(lm, o));
        __syncthreads();
        if ((tid&63)==0) s_red[tid>>6] = lm;
        __syncthreads();
        const float mx = fmaxf(fmaxf(s_red[0],s_red[1]), fmaxf(s_red[2],s_red[3]));
        float ps = 0.f;
        for (int j=tid;j<L;j+=256){
            float e = __expf(s_sc[j]-mx);
            s_sc[j] = e;
            ps += e;
        }
        #pragma unroll
        for (int o=32;o>0;o>>=1) ps += __shfl_xor(ps, o);
        __syncthreads();
        if ((tid&63)==0) s_red[tid>>6] = ps;
        __syncthreads();
        const float isum = 1.f/(s_red[0]+s_red[1]+s_red[2]+s_red[3]);
        u16* brow = (u16*)row;
        for (int j=tid;j<JEND;j+=256){
            if (j < L){
                float w = s_sc[j]*isum;
                brow[j] = f2bf(w);
                s_bm[j] += 0.125f*w;
            } else {
                brow[j] = 0;
            }
        }
        __syncthreads();
    }
    const long bmrow = ((long)b*NN + i)*NN;
    for (int j=tid;j<JEND;j+=256) BMh[bmrow+j] = f2bf(s_bm[j]);
}

// ---------------------------------------------------------------- PV, all 32 (head,batch) slices, grid (NN/64, 32)
__global__ __launch_bounds__(256) void pv_k(
    const u16* __restrict__ Sbeta,
    const u16* __restrict__ VTh,
    u16* __restrict__ xh)
{
    __shared__ u16 shA[2][64*64], shB[2][64*64];
    const int m0 = blockIdx.x*64;
    const int z = blockIdx.y;              // z = head*BB + b
    const int b = z & 3, head = z >> 2;
    const int tid = threadIdx.x;
    const int wave = tid>>6, lane = tid&63;
    const int quad = lane>>4, r16 = lane&15;
    f32x4 acc[4];
    #pragma unroll
    for (int j=0;j<4;j++) acc[j]=(f32x4){0.f,0.f,0.f,0.f};
    const int nsteps = (m0 >> 6) + 1;

    auto stage = [&](int sel, int j0){
        #pragma unroll
        for (int rep=0; rep<2; ++rep){
            int c = rep*256 + tid;
            int row = c >> 3;
            int k8 = ((c & 7) ^ (row & 7))*8;
            gload16(Sbeta + ((size_t)(z*NN + m0 + row))*(2*NN) + j0 + k8, &shA[sel][c*8]);
            gload16(VTh + ((size_t)(z*64 + row))*NN + j0 + k8, &shB[sel][c*8]);
        }
    };

    stage(0, 0);
    __syncthreads();
    int cur = 0;
    for (int t = 0; t < nsteps; ++t){
        if (t+1 < nsteps) stage(cur^1, (t+1)<<6);
        #pragma unroll
        for (int kk=0; kk<2; ++kk){
            const int s = (((kk<<2)+quad) ^ (r16 & 7))*8;
            bf16x8 af = *(const bf16x8*)&shA[cur][(wave*16 + r16)*64 + s];
            #pragma unroll
            for (int nj=0; nj<4; ++nj){
                bf16x8 bh = *(const bf16x8*)&shB[cur][(nj*16 + r16)*64 + s];
                acc[nj] = __builtin_amdgcn_mfma_f32_16x16x32_bf16(af, bh, acc[nj], 0,0,0);
            }
        }
        __syncthreads();
        cur ^= 1;
    }
    #pragma unroll
    for (int nj=0;nj<4;nj++){
        #pragma unroll
        for (int r=0;r<4;r++){
            int i = m0 + wave*16 + quad*4 + r;
            int d = nj*16 + r16;
            size_t o = ((size_t)(b*NN)+i)*KK + head*64 + d;
            xh[o] = f2bf(acc[nj][r]);
        }
    }
}

// ---------------------------------------------------------------- launch
extern "C" void kernel_launch(void* const* d_in, const int* in_sizes, int n_in,
                              void* d_out, int out_size, void* d_ws, size_t ws_size,
                              hipStream_t stream) {
    const float* mu_q    = (const float*)d_in[0];
    const float* sigma_q = (const float*)d_in[1];
    const float* phi     = (const float*)d_in[2];
    const float* gen     = (const float*)d_in[3];
    const float* mu_prior= (const float*)d_in[5];
    const float* Wq = (const float*)d_in[6];
    const float* Wk = (const float*)d_in[7];
    const float* Wv = (const float*)d_in[8];
    const float* Wo = (const float*)d_in[9];
    const float* g1 = (const float*)d_in[10];
    const float* be1= (const float*)d_in[11];
    const float* g2 = (const float*)d_in[12];
    const float* be2= (const float*)d_in[13];
    const float* W1 = (const float*)d_in[14];
    const float* bh1= (const float*)d_in[15];
    const float* W2 = (const float*)d_in[16];
    const float* bh2= (const float*)d_in[17];
    const float* lr = (const float*)d_in[18];
    float* out = (float*)d_out;

    float* w = (float*)d_ws;
    size_t off = 0;
    auto alloc = [&](size_t n){ float* p = w + off; off += (n+3)&~(size_t)3; return p; };
    auto ualloc = [&](size_t n){ return (u16*)alloc((n+1)/2); };

    // Xb..REG is one contiguous 32*NN*NN-float region reused as Sbig in phase C.
    float* Xb   = alloc((size_t)BN*KK);        // mu_n; later mn2
    float* A1b  = alloc((size_t)BN*KK);        // a1 / bmh
    float* A2b  = alloc((size_t)BN*KK);        // (spacer; part of Sbig)
    float* QKVb = alloc((size_t)BN*3*KK);      // QKV; later WOb / Hb / MRb
    float* SQSKb= alloc((size_t)BN*2*KK);
    float* REG  = alloc((size_t)16*NN*NN);     // SGh/SGl/Xh/A1h/WOh | Sbig tail | ZH
    float* Sbig = Xb;                          // 32 * NN*NN floats
    u16*  SGh   = (u16*)REG;
    u16*  SGl   = SGh + (size_t)BN*KK;
    u16*  Xh    = SGl + (size_t)BN*KK;
    u16*  A1h   = Xh  + (size_t)BN*KK;
    u16*  WOh   = A1h + (size_t)BN*KK;
    u16*  ZH    = (u16*)REG;
    float* Db_  = alloc((size_t)HH*BB*NN);
    u16* AH  = ualloc((size_t)BN*HIDd); u16* AL  = ualloc((size_t)BN*HIDd);
    u16* CFh = AH;
    u16* CFl = AH + (size_t)HH*BB*NN*128;
    u16* KSh = AL;
    u16* KSl = AL + (size_t)HH*BB*NN*128;
    u16* VTh = ualloc((size_t)HH*BB*64*NN);
    u16* GFh = ualloc((size_t)3*KK*KK);
    u16* WQKVh= ualloc((size_t)3*KK*KK); u16* WQKVl= ualloc((size_t)3*KK*KK);
    u16* WSQKh= ualloc((size_t)2*KK*KK); u16* WSQKl= ualloc((size_t)2*KK*KK);
    u16* WoTh= ualloc((size_t)KK*KK);
    u16* W1Th= ualloc((size_t)KK*HIDd);
    u16* W2Th= ualloc((size_t)KK*HIDd);
    u16* BMh = ualloc((size_t)BB*NN*NN);
    u16* HTh = ualloc((size_t)BB*KK*NN);
    float* WOb = QKVb;
    float* Hb  = QKVb + (size_t)BN*KK;
    float* MRb = QKVb + 2*(size_t)BN*KK;
    float* MN2b= Xb;
    (void)A2b;

    // ---- weight prep: one dispatch ----
    {
        dim3 gw(64, 16, 9);
        wmega_k<<<gw, 256, 0, stream>>>(Wq, Wk, Wv, Wo, W1, W2, gen,
                                        WQKVh, WQKVl, WoTh, WSQKh, WSQKl,
                                        W1Th, W2Th, GFh);
    }

    // ---- phase A: LN1 (+bf16 out, +sigma split, +output copies) + forward transport ----
    ln_k<<<BN, 256, 0, stream>>>(mu_q, g1, be1, Xb, Xh, sigma_q, SGh, SGl,
                                 out + (size_t)BN*KK, phi, out + 2*(size_t)BN*KK);
    {
        dim3 tg(BN/64, KK/64, 1);
        tgemm_k<<<tg, 256, 0, stream>>>(Xh, GFh, phi, 1.f, A1b, A1h, 0, 0, 0, 0);
        tgemm_k<<<tg, 256, 0, stream>>>(A1h, GFh, phi, 1.f, 0, AH, AL, Xb, A1b, 0);
    }

    // ---- phase B: projections (virtual-K 3-product) + merged attention prep ----
    {
        dim3 gq(BN/128, (3*KK)/128, 1);   // (32,12)
        gemm_v3_k<<<gq, 256, 0, stream>>>(AH, AL, WQKVh, WQKVl, QKVb,
            BN, KK, 3*KK, KK, 0, 0, 0, 0);
        dim3 gs(BN/128, (2*KK)/128, 1);   // (32,8)
        gemm_v3_k<<<gs, 256, 0, stream>>>(SGh, SGl, WSQKh, WSQKl, SQSKb,
            BN, KK, 2*KK, KK, 0, 0, 0, 0);
    }
    prepvt_k<<<BN + 512, 512, 0, stream>>>(QKVb, SQSKb, CFh, CFl, KSh, KSl, Db_, VTh);

    // ---- phase C: attention, all 8 heads in 3 dispatches (Sbig = Xb..REG, 134 MB) ----
    {
        dim3 sg(NN/128, NN/128, 32);
        gemm_v3_k<<<sg, 256, 0, stream>>>(CFh, CFl, KSh, KSl, Sbig,
            NN, 128, NN, 128, (long)NN*128, (long)NN*128, (long)NN*NN, 1);
        softmax_all_k<<<BB*NN, 256, 0, stream>>>(Sbig, Db_, BMh);
        dim3 pg(NN/64, 32, 1);
        pv_k<<<pg, 256, 0, stream>>>((const u16*)Sbig, VTh, AH);
    }

    // ---- phase D: output proj + back transport (fused mrb) + LN2 ----
    {
        dim3 wg(BN/64, KK/64, 1);
        gemm64_k<<<wg, 256, 0, stream>>>(AH, WoTh, WOb, WOh, 0,
            BN, KK, KK, KK, 0,0,0, nullptr, 0, 0, 0,
            0,0,0,0,0,0,0,0,0,0);
        dim3 tg(BN/64, KK/64, 1);
        tgemm_k<<<tg, 256, 0, stream>>>(WOh, GFh, phi, -1.f, A1b, A1h, 0, 0, 0, 0);
        tgemm_k<<<tg, 256, 0, stream>>>(A1h, GFh, phi, -1.f, MRb, 0, 0, WOb, A1b, mu_q);
    }
    ln_k<<<BN, 256, 0, stream>>>(MRb, g2, be2, MN2b, AH, 0, 0, 0, 0, 0, 0);

    // ---- phase E: 2 VFE iterations (bmh first, then W1, then W2 with fused update) ----
    for (int it=0; it<2; ++it){
        const float* hin = (it==0) ? MN2b : Hb;
        {
            dim3 tg(KK/32, NN/32, BB);
            split_t_k<<<tg, 256, 0, stream>>>(hin, HTh, 0, NN, KK,
                                              (long)NN*KK, (long)KK*NN, 0);
        }
        {
            dim3 bg(NN/64, KK/64, BB);
            gemm64_k<<<bg, 256, 0, stream>>>(BMh, HTh, A1b, 0,0,
                                             NN, NN, KK, NN,
                                             (long)NN*NN, (long)KK*NN, (long)NN*KK,
                                             nullptr, 0, 1, 0,
                                             0,0,0,0,0,0,0,0,0,0);
        }
        {
            dim3 wg1(HIDd/128, BN/128, 1);   // xyflip=1: x=n fastest, share A-tile
            gemm_mfma_k<<<wg1, 256, 0, stream>>>(AH, W1Th, 0, ZH, 0,
                BN, KK, HIDd, KK, 0, 0, 0, bh1, 1, 1);
        }
        {   // W2 + fused FFN update (xyflip=1)
            dim3 wg(KK/64, BN/64, 1);
            gemm64_k<<<wg, 256, 0, stream>>>(ZH, W2Th, 0,0,0,
                                             BN, HIDd, KK, HIDd, 0,0,0, bh2, 0, 0, 1,
                                             hin, A1b, mu_prior, lr, AH, Hb, MRb, MN2b, out,
                                             (it==0) ? 1 : 2);
        }
    }

    (void)in_sizes; (void)n_in; (void)out_size; (void)ws_size;
}

// Round 6
// 605.711 us; speedup vs baseline: 1.0554x; 1.0554x over previous
//
#include <hip/hip_runtime.h>
#include <math.h>

#define BB 4
#define NN 1024
#define KK 512
#define HH 8
#define DHh 64
#define HIDd 2048
#define BN (BB*NN)

typedef unsigned short u16;
typedef __attribute__((ext_vector_type(8))) short bf16x8;
typedef __attribute__((ext_vector_type(4))) float f32x4;

// ---------------------------------------------------------------- helpers
__device__ __forceinline__ float gelu_tanh(float x){
    // tanh-gelu via fast exp: 0.5x(1+tanh(u)) = x*t/(t+1), t=e^{2u}
    float u = 0.7978845608028654f*(x + 0.044715f*x*x*x);
    u = fminf(fmaxf(u, -15.f), 15.f);
    float t = __expf(2.f*u);
    return x*t/(t+1.f);
}
__device__ __forceinline__ u16 f2bf(float x){
    unsigned int u = __float_as_uint(x);
    unsigned int r = (u + 0x7fffu + ((u>>16)&1u)) >> 16;
    return (u16)r;
}
__device__ __forceinline__ float bf2f(u16 b){
    return __uint_as_float(((unsigned int)b)<<16);
}
__device__ __forceinline__ void gload16(const void* g, void* l){
    __builtin_amdgcn_global_load_lds((__attribute__((address_space(1))) void*)g,
                                     (__attribute__((address_space(3))) void*)l, 16, 0, 0);
}
__device__ __forceinline__ void wsplit(u16* hi, u16* lo, size_t o, float v){
    u16 h = f2bf(v);
    hi[o] = h;
    if (lo) lo[o] = f2bf(v - bf2f(h));
}

// ---------------------------------------------------------------- generic transpose-split (used for h^T in phase E)
__global__ __launch_bounds__(256) void split_t_k(
    const float* __restrict__ src, u16* __restrict__ hi, u16* __restrict__ lo,
    int Kc, int Nc, long sS, long sD, int square)
{
    __shared__ float t[32][33];
    const int n0 = blockIdx.x*32, k0 = blockIdx.y*32, bz = blockIdx.z;
    const float* S = src + (long)bz*sS;
    const int tx = threadIdx.x & 31, ty = threadIdx.x >> 5;
    for (int r = ty; r < 32; r += 8){
        float v = S[(long)(k0+r)*Nc + n0+tx];
        if (square) v *= v;
        t[r][tx] = v;
    }
    __syncthreads();
    for (int r = ty; r < 32; r += 8){
        float v = t[tx][r];
        long o = (long)bz*sD + (long)(n0+r)*Kc + k0 + tx;
        wsplit(hi, lo, o, v);
    }
}

// ---------------------------------------------------------------- all weight prep in one dispatch, grid (64,16,9)
__global__ __launch_bounds__(256) void wmega_k(
    const float* __restrict__ Wq, const float* __restrict__ Wk,
    const float* __restrict__ Wv, const float* __restrict__ Wo,
    const float* __restrict__ W1, const float* __restrict__ W2,
    const float* __restrict__ gen,
    u16* __restrict__ WQKVh, u16* __restrict__ WQKVl, u16* __restrict__ WoTh,
    u16* __restrict__ WSQKh, u16* __restrict__ WSQKl,
    u16* __restrict__ W1Th, u16* __restrict__ W2Th, u16* __restrict__ GFh)
{
    const int z = blockIdx.z;
    const int tid = threadIdx.x;
    if (z == 8){   // gflat: copy gen(3,K,K) -> GFh[k][g*512+l]
        if (blockIdx.x >= 48) return;
        const int c0 = blockIdx.x*32, k0 = blockIdx.y*32;
        const int tx = tid&31, ty = tid>>5;
        const int g = c0/KK, l0 = c0%KK;
        for (int r=ty; r<32; r+=8)
            GFh[(size_t)(k0+r)*(3*KK) + c0+tx] =
                f2bf(gen[(size_t)g*KK*KK + (size_t)(k0+r)*KK + l0+tx]);
        return;
    }
    __shared__ float t[32][33];
    const float* src; u16* hi; u16* lo=0; int sq=0;
    int n0, k0, Kc, Nc;
    const size_t KK2 = (size_t)KK*KK;
    if (z < 6){
        if (blockIdx.x >= 16) return;
        n0 = blockIdx.x*32; k0 = blockIdx.y*32; Kc=KK; Nc=KK;
        if      (z==0){ src=Wq; hi=WQKVh;       lo=WQKVl; }
        else if (z==1){ src=Wk; hi=WQKVh+KK2;   lo=WQKVl+KK2; }
        else if (z==2){ src=Wv; hi=WQKVh+2*KK2; lo=WQKVl+2*KK2; }
        else if (z==3){ src=Wo; hi=WoTh; }
        else if (z==4){ src=Wq; hi=WSQKh;       lo=WSQKl; sq=1; }
        else          { src=Wk; hi=WSQKh+KK2;   lo=WSQKl+KK2; sq=1; }
    } else if (z == 6){  // W1 [512][2048] -> [2048][512]
        src=W1; hi=W1Th; Kc=KK; Nc=HIDd;
        n0 = blockIdx.x*32; k0 = blockIdx.y*32;
    } else {             // W2 [2048][512] -> [512][2048]
        src=W2; hi=W2Th; Kc=HIDd; Nc=KK;
        n0 = blockIdx.y*32; k0 = blockIdx.x*32;
    }
    const int tx=tid&31, ty=tid>>5;
    for (int r=ty;r<32;r+=8){
        float v = src[(long)(k0+r)*Nc + n0+tx];
        if (sq) v*=v;
        t[r][tx]=v;
    }
    __syncthreads();
    for (int r=ty;r<32;r+=8){
        float v = t[tx][r];
        long o = (long)(n0+r)*Kc + k0+tx;
        wsplit(hi, lo, o, v);
    }
}

// ---------------------------------------------------------------- MFMA GEMM 128x128, single product
// depth-2 / single-__syncthreads pipeline, 32 KB LDS.
// swz=1: 8x4 supertile remap — consecutive 32 blocks cover 8 M-tiles x 4 N-tiles,
// so L2 holds a 2MB A-band + 0.5MB B-band and concurrent blocks read DISTINCT
// tiles (no same-line hotspot — the r5 xyflip lesson).
__global__ __launch_bounds__(256) void gemm_mfma_k(
    const u16* __restrict__ Ah, const u16* __restrict__ Bh,
    float* __restrict__ C, u16* __restrict__ Chi, u16* __restrict__ Clo,
    int M, int Kc, int Nc, int lda,
    long sA, long sB, long sC, const float* __restrict__ bias, int act,
    int swz)
{
    __shared__ u16 shA[2][128*32], shB[2][128*32];
    int bx = blockIdx.x, by = blockIdx.y;
    if (swz){
        int lin = bx + gridDim.x*by;
        int within = lin & 31, st = lin >> 5;
        int stm = gridDim.x >> 3;
        bx = (st % stm)*8 + (within & 7);
        by = (st / stm)*4 + (within >> 3);
    }
    const int m0 = bx*128, n0 = by*128;
    const int bz = blockIdx.z;
    const u16* gAh = Ah + (long)bz*sA;
    const u16* gBh = Bh + (long)bz*sB;
    const int tid = threadIdx.x;
    const int wave = tid >> 6, lane = tid & 63;
    const int quad = lane >> 4, r16 = lane & 15;
    const int wm = (wave>>1)*64, wn = (wave&1)*64;

    f32x4 acc[4][4];
    #pragma unroll
    for (int i=0;i<4;i++)
        #pragma unroll
        for (int j=0;j<4;j++) acc[i][j] = (f32x4){0.f,0.f,0.f,0.f};

    auto stage = [&](int sel, int k0){
        #pragma unroll
        for (int half=0; half<2; ++half){
            int c = half*256 + tid;
            int row = c >> 2;
            int kg = ((c & 3) ^ ((row >> 1) & 3))*8;   // pre-swizzled global slot
            gload16(gAh + (long)(m0+row)*lda + k0 + kg, &shA[sel][c*8]);
            gload16(gBh + (long)(n0+row)*Kc  + k0 + kg, &shB[sel][c*8]);
        }
    };

    const int nsteps = Kc >> 5;
    stage(0, 0);
    __syncthreads();
    int cur = 0;
    const int swr = (quad ^ ((r16 >> 1) & 3))*8;       // undo swizzle on read
    for (int t = 0; t < nsteps; ++t){
        if (t+1 < nsteps) stage(cur^1, (t+1)<<5);
        bf16x8 afh[4], bfh[4];
        #pragma unroll
        for (int i=0;i<4;i++){
            afh[i] = *(const bf16x8*)&shA[cur][(wm+i*16+r16)*32 + swr];
            bfh[i] = *(const bf16x8*)&shB[cur][(wn+i*16+r16)*32 + swr];
        }
        #pragma unroll
        for (int i=0;i<4;i++)
            #pragma unroll
            for (int j=0;j<4;j++)
                acc[i][j] = __builtin_amdgcn_mfma_f32_16x16x32_bf16(afh[i], bfh[j], acc[i][j], 0,0,0);
        __syncthreads();
        cur ^= 1;
    }
    #pragma unroll
    for (int i=0;i<4;i++){
        #pragma unroll
        for (int j=0;j<4;j++){
            int gc = n0 + wn + j*16 + r16;
            if (gc >= Nc) continue;
            float bv = bias ? bias[gc] : 0.f;
            #pragma unroll
            for (int r=0;r<4;r++){
                long gr = m0 + wm + i*16 + quad*4 + r;
                float v = acc[i][j][r] + bv;
                if (act) v = gelu_tanh(v);
                long o = (long)bz*sC + gr*Nc + gc;
                if (C) C[o] = v;
                if (Chi){ u16 t = f2bf(v); Chi[o] = t; if (Clo) Clo[o] = f2bf(v - bf2f(t)); }
            }
        }
    }
}

// ---------------------------------------------------------------- MFMA GEMM 128x128, 3-product via VIRTUAL K
// K_virt = 3*Kc; segment 0: Ah*Bh, 1: Al*Bh, 2: Ah*Bl (pointer switch in staging).
__global__ __launch_bounds__(256) void gemm_v3_k(
    const u16* __restrict__ Ah, const u16* __restrict__ Al,
    const u16* __restrict__ Bh, const u16* __restrict__ Bl,
    float* __restrict__ C,
    int M, int Kc, int Nc, int lda,
    long sA, long sB, long sC, int cskip)
{
    __shared__ u16 shA[2][128*32], shB[2][128*32];
    const int m0 = blockIdx.x*128, n0 = blockIdx.y*128;
    if (cskip == 1 && n0 > m0 + 127) return;
    const int bz = blockIdx.z;
    const u16* gAh = Ah + (long)bz*sA;
    const u16* gAl = Al + (long)bz*sA;
    const u16* gBh = Bh + (long)bz*sB;
    const u16* gBl = Bl + (long)bz*sB;
    const int tid = threadIdx.x;
    const int wave = tid >> 6, lane = tid & 63;
    const int quad = lane >> 4, r16 = lane & 15;
    const int wm = (wave>>1)*64, wn = (wave&1)*64;

    f32x4 acc[4][4];
    #pragma unroll
    for (int i=0;i<4;i++)
        #pragma unroll
        for (int j=0;j<4;j++) acc[i][j] = (f32x4){0.f,0.f,0.f,0.f};

    const int segsteps = Kc >> 5;
    const int nsteps = 3*segsteps;
    auto stage = [&](int sel, int t){
        int seg = (t >= segsteps) + (t >= 2*segsteps);
        int k0 = (t - seg*segsteps) << 5;
        const u16* a = (seg==1) ? gAl : gAh;
        const u16* b = (seg==2) ? gBl : gBh;
        #pragma unroll
        for (int half=0; half<2; ++half){
            int c = half*256 + tid;
            int row = c >> 2;
            int kg = ((c & 3) ^ ((row >> 1) & 3))*8;
            gload16(a + (long)(m0+row)*lda + k0 + kg, &shA[sel][c*8]);
            gload16(b + (long)(n0+row)*Kc  + k0 + kg, &shB[sel][c*8]);
        }
    };

    stage(0, 0);
    __syncthreads();
    int cur = 0;
    const int swr = (quad ^ ((r16 >> 1) & 3))*8;
    for (int t = 0; t < nsteps; ++t){
        if (t+1 < nsteps) stage(cur^1, t+1);
        bf16x8 afh[4], bfh[4];
        #pragma unroll
        for (int i=0;i<4;i++){
            afh[i] = *(const bf16x8*)&shA[cur][(wm+i*16+r16)*32 + swr];
            bfh[i] = *(const bf16x8*)&shB[cur][(wn+i*16+r16)*32 + swr];
        }
        #pragma unroll
        for (int i=0;i<4;i++)
            #pragma unroll
            for (int j=0;j<4;j++)
                acc[i][j] = __builtin_amdgcn_mfma_f32_16x16x32_bf16(afh[i], bfh[j], acc[i][j], 0,0,0);
        __syncthreads();
        cur ^= 1;
    }
    #pragma unroll
    for (int i=0;i<4;i++){
        #pragma unroll
        for (int j=0;j<4;j++){
            int gc = n0 + wn + j*16 + r16;
            if (gc >= Nc) continue;
            #pragma unroll
            for (int r=0;r<4;r++){
                long gr = m0 + wm + i*16 + quad*4 + r;
                long o = (long)bz*sC + gr*Nc + gc;
                C[o] = acc[i][j][r];
            }
        }
    }
}

// ---------------------------------------------------------------- transport GEMM 64x64:
// out[r][n] = sum_g (esign*phi[r][g]) * sum_kd A[r][kd]*gen[g][n][kd]
// = virtual-K GEMM over GF[n*1536 + g*512 + kd] with per-segment register fold.
__global__ __launch_bounds__(256) void tgemm_k(
    const u16* __restrict__ Ahh,   // [M][512] bf16
    const u16* __restrict__ GFh,   // [n][g*512+kd]
    const float* __restrict__ phi, float esign,
    float* __restrict__ C, u16* __restrict__ Chi, u16* __restrict__ Clo,
    const float* __restrict__ t_x, const float* __restrict__ t_a1,
    const float* __restrict__ t_res)
{
    __shared__ u16 shA[2][64*64], shB[2][64*64];
    const int m0 = blockIdx.x*64, n0 = blockIdx.y*64;
    const int tid = threadIdx.x;
    const int wave = tid >> 6, lane = tid & 63;
    const int quad = lane >> 4, r16 = lane & 15;
    const int wr = wave*16;

    float ph[3][4];
    #pragma unroll
    for (int sgi=0; sgi<3; ++sgi)
        #pragma unroll
        for (int r=0; r<4; ++r)
            ph[sgi][r] = esign*phi[(size_t)(m0+wr+quad*4+r)*3 + sgi];

    f32x4 acc[4], tot[4];
    #pragma unroll
    for (int j=0;j<4;j++){ acc[j] = (f32x4){0.f,0.f,0.f,0.f}; tot[j] = acc[j]; }

    auto stage = [&](int sel, int t){
        int seg = t >> 3, k0 = (t & 7) << 6;
        #pragma unroll
        for (int rep=0; rep<2; ++rep){
            int c = rep*256 + tid;
            int row = c >> 3;
            int kg = ((c & 7) ^ (row & 7))*8;
            gload16(Ahh + (long)(m0+row)*KK + k0 + kg, &shA[sel][c*8]);
            gload16(GFh + (long)(n0+row)*(3*KK) + seg*KK + k0 + kg, &shB[sel][c*8]);
        }
    };

    stage(0, 0);
    __syncthreads();
    int cur = 0;
    for (int t = 0; t < 24; ++t){
        if (t+1 < 24) stage(cur^1, t+1);
        #pragma unroll
        for (int kk=0; kk<2; ++kk){
            const int s = (((kk<<2)+quad) ^ (r16 & 7))*8;
            bf16x8 af = *(const bf16x8*)&shA[cur][(wr+r16)*64 + s];
            #pragma unroll
            for (int j=0;j<4;j++){
                bf16x8 bh = *(const bf16x8*)&shB[cur][(j*16+r16)*64 + s];
                acc[j] = __builtin_amdgcn_mfma_f32_16x16x32_bf16(af, bh, acc[j], 0,0,0);
            }
        }
        if ((t & 7) == 7){
            int sgi = t >> 3;
            #pragma unroll
            for (int j=0;j<4;j++){
                #pragma unroll
                for (int r=0;r<4;r++) tot[j][r] += ph[sgi][r]*acc[j][r];
                acc[j] = (f32x4){0.f,0.f,0.f,0.f};
            }
        }
        __syncthreads();
        cur ^= 1;
    }
    #pragma unroll
    for (int j=0;j<4;j++){
        int gc = n0 + j*16 + r16;
        #pragma unroll
        for (int r=0;r<4;r++){
            long gr = m0 + wr + quad*4 + r;
            float v = tot[j][r];
            long o = gr*(long)KK + gc;
            if (t_x){
                v = t_x[o] + t_a1[o] + 0.5f*v;
                if (t_res) v += t_res[o];
            }
            if (C) C[o] = v;
            if (Chi){ u16 t2 = f2bf(v); Chi[o] = t2; if (Clo) Clo[o] = f2bf(v - bf2f(t2)); }
        }
    }
}

// ---------------------------------------------------------------- MFMA GEMM 64x64
// depth-2 / single-__syncthreads pipeline, 32KB LDS. K-step 64.
// swz=1: 8x4 supertile remap (same rationale as gemm_mfma_k).
// epilogue: fused FFN update (fmode 1=mid, 2=final)
__global__ __launch_bounds__(256) void gemm64_k(
    const u16* __restrict__ Ah, const u16* __restrict__ Bh,
    float* __restrict__ C, u16* __restrict__ Chi, u16* __restrict__ Clo,
    int M, int Kc, int Nc, int lda,
    long sA, long sB, long sC, const float* __restrict__ bias, int act,
    int ktrim, int swz,
    const float* __restrict__ f_hin, const float* __restrict__ f_bmh,
    const float* __restrict__ f_mup, const float* __restrict__ f_lr,
    u16* __restrict__ f_hh, float* __restrict__ f_hout,
    const float* __restrict__ f_mrb, const float* __restrict__ f_mn2,
    float* __restrict__ f_out, int fmode)
{
    __shared__ u16 shA[2][64*64], shB[2][64*64];
    int bx = blockIdx.x, by = blockIdx.y;
    if (swz){
        int lin = bx + gridDim.x*by;
        int within = lin & 31, st = lin >> 5;
        int stm = gridDim.x >> 3;
        bx = (st % stm)*8 + (within & 7);
        by = (st / stm)*4 + (within >> 3);
    }
    const int m0 = bx*64, n0 = by*64;
    const int bz = blockIdx.z;
    const u16* gA = Ah + (long)bz*sA;
    const u16* gB = Bh + (long)bz*sB;
    const int tid = threadIdx.x;
    const int wave = tid >> 6, lane = tid & 63;
    const int quad = lane >> 4, r16 = lane & 15;
    const int wr = wave*16;
    const int kend = ktrim ? min(Kc, m0 + 64) : Kc;
    const int nsteps = kend >> 6;

    f32x4 acc[4];
    #pragma unroll
    for (int j=0;j<4;j++) acc[j] = (f32x4){0.f,0.f,0.f,0.f};

    auto stage = [&](int sel, int k0){
        #pragma unroll
        for (int rep=0; rep<2; ++rep){
            int c = rep*256 + tid;
            int row = c >> 3;
            int kg = ((c & 7) ^ (row & 7))*8;     // pre-swizzled global slot
            gload16(gA + (long)(m0+row)*lda + k0 + kg, &shA[sel][c*8]);
            gload16(gB + (long)(n0+row)*Kc + k0 + kg, &shB[sel][c*8]);
        }
    };

    stage(0, 0);
    __syncthreads();
    int cur = 0;
    for (int t = 0; t < nsteps; ++t){
        if (t+1 < nsteps) stage(cur^1, (t+1)<<6);
        #pragma unroll
        for (int kk=0; kk<2; ++kk){
            const int s = (((kk<<2)+quad) ^ (r16 & 7))*8;   // undo swizzle on read
            bf16x8 af = *(const bf16x8*)&shA[cur][(wr+r16)*64 + s];
            #pragma unroll
            for (int j=0;j<4;j++){
                bf16x8 bh = *(const bf16x8*)&shB[cur][(j*16+r16)*64 + s];
                acc[j] = __builtin_amdgcn_mfma_f32_16x16x32_bf16(af, bh, acc[j], 0,0,0);
            }
        }
        __syncthreads();
        cur ^= 1;
    }
    float lrv = 0.f;
    if (fmode) lrv = *f_lr;
    #pragma unroll
    for (int j=0;j<4;j++){
        int gc = n0 + j*16 + r16;
        float bv = bias ? bias[gc] : 0.f;
        #pragma unroll
        for (int r=0;r<4;r++){
            long gr = m0 + wr + quad*4 + r;
            float v = acc[j][r] + bv;
            if (act) v = gelu_tanh(v);
            long o = (long)bz*sC + gr*Nc + gc;
            if (fmode){
                float hv = f_hin[o];
                float val = hv + lrv*(v - (1e-3f*(hv - f_mup[o]) + (hv - f_bmh[o])));
                if (fmode == 1){ f_hout[o] = val; f_hh[o] = f2bf(val); }
                else           { f_out[o] = f_mrb[o] + val - f_mn2[o]; }
            } else {
                if (C) C[o] = v;
                if (Chi){ u16 t = f2bf(v); Chi[o] = t; if (Clo) Clo[o] = f2bf(v - bf2f(t)); }
            }
        }
    }
}

// ---------------------------------------------------------------- LayerNorm (+bf16 out, +sigma split, +output copies)
__global__ __launch_bounds__(256) void ln_k(
    const float* __restrict__ x, const float* __restrict__ g,
    const float* __restrict__ be, float* __restrict__ y,
    u16* __restrict__ yh16,
    const float* __restrict__ sg, u16* __restrict__ sgh, u16* __restrict__ sgl,
    float* __restrict__ osig, const float* __restrict__ phi, float* __restrict__ ophi)
{
    __shared__ float sh[8];
    const int r = blockIdx.x, tid = threadIdx.x;
    const float* xr = x + (long)r*KK;
    float2 v = *(const float2*)(xr + tid*2);
    float s = v.x+v.y, s2 = v.x*v.x+v.y*v.y;
    #pragma unroll
    for (int o=32;o>0;o>>=1){ s += __shfl_down(s,o); s2 += __shfl_down(s2,o); }
    if ((tid&63)==0){ sh[tid>>6]=s; sh[4+(tid>>6)]=s2; }
    __syncthreads();
    s  = sh[0]+sh[1]+sh[2]+sh[3];
    s2 = sh[4]+sh[5]+sh[6]+sh[7];
    const float mean = s*(1.f/KK);
    const float var  = s2*(1.f/KK) - mean*mean;
    const float rs = rsqrtf(var + 1e-5f);
    float2 gg = *(const float2*)(g + tid*2);
    float2 bb = *(const float2*)(be + tid*2);
    float ox = (v.x-mean)*rs*gg.x + bb.x;
    float oy = (v.y-mean)*rs*gg.y + bb.y;
    long o = (long)r*KK + tid*2;
    *(float2*)(y + o) = make_float2(ox, oy);
    if (yh16){ yh16[o] = f2bf(ox); yh16[o+1] = f2bf(oy); }
    if (sgh){
        float2 sv = *(const float2*)(sg + o);
        wsplit(sgh, sgl, o,   sv.x);
        wsplit(sgh, sgl, o+1, sv.y);
        if (osig) *(float2*)(osig + o) = sv;
    }
    if (ophi && tid < 3) ophi[(size_t)r*3 + tid] = phi[(size_t)r*3 + tid];
}

// ---------------------------------------------------------------- merged attention prep + V transpose
__global__ __launch_bounds__(512) void prepvt_k(
    const float* __restrict__ QKV, const float* __restrict__ SQSK,
    u16* __restrict__ CFh, u16* __restrict__ CFl,
    u16* __restrict__ KSh, u16* __restrict__ KSl, float* __restrict__ dvec,
    u16* __restrict__ VTh)
{
    __shared__ float t[64][65];
    const int bx = blockIdx.x;
    const int tid = threadIdx.x;
    if (bx < BN){
        const int bn = bx;
        const int b = bn / NN, n = bn % NN;
        const int h = tid >> 6, d = tid & 63;
        float q  = QKV[(size_t)bn*1536 + h*DHh + d];
        float k  = QKV[(size_t)bn*1536 + KK + h*DHh + d];
        float sq = SQSK[(size_t)bn*1024 + h*DHh + d] + 1e-8f;
        float sk = SQSK[(size_t)bn*1024 + KK + h*DHh + d] + 1e-8f;
        float inv = 1.f/sq;
        float nqi = -2.f*q*inv;
        float skk = sk + k*k;
        const size_t base = ((size_t)(h*BB + b)*NN + n)*128;
        wsplit(CFh, CFl, base+d,    inv);
        wsplit(CFh, CFl, base+64+d, nqi);
        wsplit(KSh, KSl, base+d,    skk);
        wsplit(KSh, KSl, base+64+d, k);
        float dv = __logf(sk);
        #pragma unroll
        for (int o=32;o>0;o>>=1) dv += __shfl_down(dv,o);
        if (d==0) dvec[((size_t)h*BB + b)*NN + n] = dv;
        return;
    }
    const int idx = bx - BN;
    const int n0 = (idx & 15)*64;
    const int h = (idx>>4)&7;
    const int b = idx>>7;
    const int c4 = (tid & 15) * 4;
    const int r0 = tid >> 4;     // 0..31
    for (int rr = r0; rr < 64; rr += 32){
        float4 v = *(const float4*)(QKV + (size_t)(b*NN + n0 + rr)*1536 + 1024 + h*DHh + c4);
        t[c4+0][rr] = v.x; t[c4+1][rr] = v.y; t[c4+2][rr] = v.z; t[c4+3][rr] = v.w;
    }
    __syncthreads();
    for (int dd = r0; dd < 64; dd += 32){
        size_t base = ((size_t)(h*BB + b)*64 + dd)*NN + n0 + c4;
        #pragma unroll
        for (int q=0;q<4;q++) VTh[base+q] = f2bf(t[dd][c4+q]);
    }
}

// ---------------------------------------------------------------- softmax, all 8 heads in one pass
__global__ __launch_bounds__(256) void softmax_all_k(
    float* __restrict__ S, const float* __restrict__ dvec, u16* __restrict__ BMh)
{
    __shared__ float s_sc[NN];
    __shared__ float s_bm[NN];
    __shared__ float s_red[4];
    const int tid = threadIdx.x;
    const int b = blockIdx.x / NN, i = blockIdx.x % NN;
    const int L = i + 1;
    const int JEND = ((i >> 6) + 1) << 6;
    for (int j=tid;j<JEND;j+=256) s_bm[j]=0.f;
    for (int h=0; h<8; ++h){
        const int z = h*BB + b;
        float* row = S + ((long)z*NN + i)*NN;
        const float* dp = dvec + (size_t)z*NN;
        float lm = -3.0e38f;
        for (int j=tid;j<L;j+=256){
            float sc = -0.5f*row[j] + 0.5f*dp[j];
            s_sc[j] = sc;
            lm = fmaxf(lm, sc);
        }
        #pragma unroll
        for (int o=32;o>0;o>>=1) lm = fmaxf(lm, __shfl_xor(lm, o));
        __syncthreads();
        if ((tid&63)==0) s_red[tid>>6] = lm;
        __syncthreads();
        const float mx = fmaxf(fmaxf(s_red[0],s_red[1]), fmaxf(s_red[2],s_red[3]));
        float ps = 0.f;
        for (int j=tid;j<L;j+=256){
            float e = __expf(s_sc[j]-mx);
            s_sc[j] = e;
            ps += e;
        }
        #pragma unroll
        for (int o=32;o>0;o>>=1) ps += __shfl_xor(ps, o);
        __syncthreads();
        if ((tid&63)==0) s_red[tid>>6] = ps;
        __syncthreads();
        const float isum = 1.f/(s_red[0]+s_red[1]+s_red[2]+s_red[3]);
        u16* brow = (u16*)row;
        for (int j=tid;j<JEND;j+=256){
            if (j < L){
                float w = s_sc[j]*isum;
                brow[j] = f2bf(w);
                s_bm[j] += 0.125f*w;
            } else {
                brow[j] = 0;
            }
        }
        __syncthreads();
    }
    const long bmrow = ((long)b*NN + i)*NN;
    for (int j=tid;j<JEND;j+=256) BMh[bmrow+j] = f2bf(s_bm[j]);
}

// ---------------------------------------------------------------- PV, all 32 (head,batch) slices, grid (NN/64, 32)
__global__ __launch_bounds__(256) void pv_k(
    const u16* __restrict__ Sbeta,
    const u16* __restrict__ VTh,
    u16* __restrict__ xh)
{
    __shared__ u16 shA[2][64*64], shB[2][64*64];
    const int m0 = blockIdx.x*64;
    const int z = blockIdx.y;              // z = head*BB + b
    const int b = z & 3, head = z >> 2;
    const int tid = threadIdx.x;
    const int wave = tid>>6, lane = tid&63;
    const int quad = lane>>4, r16 = lane&15;
    f32x4 acc[4];
    #pragma unroll
    for (int j=0;j<4;j++) acc[j]=(f32x4){0.f,0.f,0.f,0.f};
    const int nsteps = (m0 >> 6) + 1;

    auto stage = [&](int sel, int j0){
        #pragma unroll
        for (int rep=0; rep<2; ++rep){
            int c = rep*256 + tid;
            int row = c >> 3;
            int k8 = ((c & 7) ^ (row & 7))*8;
            gload16(Sbeta + ((size_t)(z*NN + m0 + row))*(2*NN) + j0 + k8, &shA[sel][c*8]);
            gload16(VTh + ((size_t)(z*64 + row))*NN + j0 + k8, &shB[sel][c*8]);
        }
    };

    stage(0, 0);
    __syncthreads();
    int cur = 0;
    for (int t = 0; t < nsteps; ++t){
        if (t+1 < nsteps) stage(cur^1, (t+1)<<6);
        #pragma unroll
        for (int kk=0; kk<2; ++kk){
            const int s = (((kk<<2)+quad) ^ (r16 & 7))*8;
            bf16x8 af = *(const bf16x8*)&shA[cur][(wave*16 + r16)*64 + s];
            #pragma unroll
            for (int nj=0; nj<4; ++nj){
                bf16x8 bh = *(const bf16x8*)&shB[cur][(nj*16 + r16)*64 + s];
                acc[nj] = __builtin_amdgcn_mfma_f32_16x16x32_bf16(af, bh, acc[nj], 0,0,0);
            }
        }
        __syncthreads();
        cur ^= 1;
    }
    #pragma unroll
    for (int nj=0;nj<4;nj++){
        #pragma unroll
        for (int r=0;r<4;r++){
            int i = m0 + wave*16 + quad*4 + r;
            int d = nj*16 + r16;
            size_t o = ((size_t)(b*NN)+i)*KK + head*64 + d;
            xh[o] = f2bf(acc[nj][r]);
        }
    }
}

// ---------------------------------------------------------------- launch
extern "C" void kernel_launch(void* const* d_in, const int* in_sizes, int n_in,
                              void* d_out, int out_size, void* d_ws, size_t ws_size,
                              hipStream_t stream) {
    const float* mu_q    = (const float*)d_in[0];
    const float* sigma_q = (const float*)d_in[1];
    const float* phi     = (const float*)d_in[2];
    const float* gen     = (const float*)d_in[3];
    const float* mu_prior= (const float*)d_in[5];
    const float* Wq = (const float*)d_in[6];
    const float* Wk = (const float*)d_in[7];
    const float* Wv = (const float*)d_in[8];
    const float* Wo = (const float*)d_in[9];
    const float* g1 = (const float*)d_in[10];
    const float* be1= (const float*)d_in[11];
    const float* g2 = (const float*)d_in[12];
    const float* be2= (const float*)d_in[13];
    const float* W1 = (const float*)d_in[14];
    const float* bh1= (const float*)d_in[15];
    const float* W2 = (const float*)d_in[16];
    const float* bh2= (const float*)d_in[17];
    const float* lr = (const float*)d_in[18];
    float* out = (float*)d_out;

    float* w = (float*)d_ws;
    size_t off = 0;
    auto alloc = [&](size_t n){ float* p = w + off; off += (n+3)&~(size_t)3; return p; };
    auto ualloc = [&](size_t n){ return (u16*)alloc((n+1)/2); };

    // Xb..REG is one contiguous 32*NN*NN-float region reused as Sbig in phase C.
    float* Xb   = alloc((size_t)BN*KK);        // mu_n; later mn2
    float* A1b  = alloc((size_t)BN*KK);        // a1 / bmh
    float* A2b  = alloc((size_t)BN*KK);        // (spacer; part of Sbig)
    float* QKVb = alloc((size_t)BN*3*KK);      // QKV; later WOb / Hb / MRb
    float* SQSKb= alloc((size_t)BN*2*KK);
    float* REG  = alloc((size_t)16*NN*NN);     // SGh/SGl/Xh/A1h/WOh | Sbig tail | ZH
    float* Sbig = Xb;                          // 32 * NN*NN floats
    u16*  SGh   = (u16*)REG;
    u16*  SGl   = SGh + (size_t)BN*KK;
    u16*  Xh    = SGl + (size_t)BN*KK;
    u16*  A1h   = Xh  + (size_t)BN*KK;
    u16*  WOh   = A1h + (size_t)BN*KK;
    u16*  ZH    = (u16*)REG;
    float* Db_  = alloc((size_t)HH*BB*NN);
    u16* AH  = ualloc((size_t)BN*HIDd); u16* AL  = ualloc((size_t)BN*HIDd);
    u16* CFh = AH;
    u16* CFl = AH + (size_t)HH*BB*NN*128;
    u16* KSh = AL;
    u16* KSl = AL + (size_t)HH*BB*NN*128;
    u16* VTh = ualloc((size_t)HH*BB*64*NN);
    u16* GFh = ualloc((size_t)3*KK*KK);
    u16* WQKVh= ualloc((size_t)3*KK*KK); u16* WQKVl= ualloc((size_t)3*KK*KK);
    u16* WSQKh= ualloc((size_t)2*KK*KK); u16* WSQKl= ualloc((size_t)2*KK*KK);
    u16* WoTh= ualloc((size_t)KK*KK);
    u16* W1Th= ualloc((size_t)KK*HIDd);
    u16* W2Th= ualloc((size_t)KK*HIDd);
    u16* BMh = ualloc((size_t)BB*NN*NN);
    u16* HTh = ualloc((size_t)BB*KK*NN);
    float* WOb = QKVb;
    float* Hb  = QKVb + (size_t)BN*KK;
    float* MRb = QKVb + 2*(size_t)BN*KK;
    float* MN2b= Xb;
    (void)A2b;

    // ---- weight prep: one dispatch ----
    {
        dim3 gw(64, 16, 9);
        wmega_k<<<gw, 256, 0, stream>>>(Wq, Wk, Wv, Wo, W1, W2, gen,
                                        WQKVh, WQKVl, WoTh, WSQKh, WSQKl,
                                        W1Th, W2Th, GFh);
    }

    // ---- phase A: LN1 (+bf16 out, +sigma split, +output copies) + forward transport ----
    ln_k<<<BN, 256, 0, stream>>>(mu_q, g1, be1, Xb, Xh, sigma_q, SGh, SGl,
                                 out + (size_t)BN*KK, phi, out + 2*(size_t)BN*KK);
    {
        dim3 tg(BN/64, KK/64, 1);
        tgemm_k<<<tg, 256, 0, stream>>>(Xh, GFh, phi, 1.f, A1b, A1h, 0, 0, 0, 0);
        tgemm_k<<<tg, 256, 0, stream>>>(A1h, GFh, phi, 1.f, 0, AH, AL, Xb, A1b, 0);
    }

    // ---- phase B: projections (virtual-K 3-product) + merged attention prep ----
    {
        dim3 gq(BN/128, (3*KK)/128, 1);   // (32,12)
        gemm_v3_k<<<gq, 256, 0, stream>>>(AH, AL, WQKVh, WQKVl, QKVb,
            BN, KK, 3*KK, KK, 0, 0, 0, 0);
        dim3 gs(BN/128, (2*KK)/128, 1);   // (32,8)
        gemm_v3_k<<<gs, 256, 0, stream>>>(SGh, SGl, WSQKh, WSQKl, SQSKb,
            BN, KK, 2*KK, KK, 0, 0, 0, 0);
    }
    prepvt_k<<<BN + 512, 512, 0, stream>>>(QKVb, SQSKb, CFh, CFl, KSh, KSl, Db_, VTh);

    // ---- phase C: attention, all 8 heads in 3 dispatches (Sbig = Xb..REG, 134 MB) ----
    {
        dim3 sg(NN/128, NN/128, 32);
        gemm_v3_k<<<sg, 256, 0, stream>>>(CFh, CFl, KSh, KSl, Sbig,
            NN, 128, NN, 128, (long)NN*128, (long)NN*128, (long)NN*NN, 1);
        softmax_all_k<<<BB*NN, 256, 0, stream>>>(Sbig, Db_, BMh);
        dim3 pg(NN/64, 32, 1);
        pv_k<<<pg, 256, 0, stream>>>((const u16*)Sbig, VTh, AH);
    }

    // ---- phase D: output proj + back transport (fused mrb) + LN2 ----
    {
        dim3 wg(BN/64, KK/64, 1);
        gemm64_k<<<wg, 256, 0, stream>>>(AH, WoTh, WOb, WOh, 0,
            BN, KK, KK, KK, 0,0,0, nullptr, 0, 0, 0,
            0,0,0,0,0,0,0,0,0,0);
        dim3 tg(BN/64, KK/64, 1);
        tgemm_k<<<tg, 256, 0, stream>>>(WOh, GFh, phi, -1.f, A1b, A1h, 0, 0, 0, 0);
        tgemm_k<<<tg, 256, 0, stream>>>(A1h, GFh, phi, -1.f, MRb, 0, 0, WOb, A1b, mu_q);
    }
    ln_k<<<BN, 256, 0, stream>>>(MRb, g2, be2, MN2b, AH, 0, 0, 0, 0, 0, 0);

    // ---- phase E: 2 VFE iterations (bmh first, then W1, then W2 with fused update) ----
    for (int it=0; it<2; ++it){
        const float* hin = (it==0) ? MN2b : Hb;
        {
            dim3 tg(KK/32, NN/32, BB);
            split_t_k<<<tg, 256, 0, stream>>>(hin, HTh, 0, NN, KK,
                                              (long)NN*KK, (long)KK*NN, 0);
        }
        {
            dim3 bg(NN/64, KK/64, BB);
            gemm64_k<<<bg, 256, 0, stream>>>(BMh, HTh, A1b, 0,0,
                                             NN, NN, KK, NN,
                                             (long)NN*NN, (long)KK*NN, (long)NN*KK,
                                             nullptr, 0, 1, 0,
                                             0,0,0,0,0,0,0,0,0,0);
        }
        {
            dim3 wg1(BN/128, HIDd/128, 1);   // (32,16), supertile swizzle
            gemm_mfma_k<<<wg1, 256, 0, stream>>>(AH, W1Th, 0, ZH, 0,
                BN, KK, HIDd, KK, 0, 0, 0, bh1, 1, 1);
        }
        {   // W2 + fused FFN update, (64,8), supertile swizzle
            dim3 wg(BN/64, KK/64, 1);
            gemm64_k<<<wg, 256, 0, stream>>>(ZH, W2Th, 0,0,0,
                                             BN, HIDd, KK, HIDd, 0,0,0, bh2, 0, 0, 1,
                                             hin, A1b, mu_prior, lr, AH, Hb, MRb, MN2b, out,
                                             (it==0) ? 1 : 2);
        }
    }

    (void)in_sizes; (void)n_in; (void)out_size; (void)ws_size;
}

// Round 7
// 585.924 us; speedup vs baseline: 1.0910x; 1.0338x over previous
//
#include <hip/hip_runtime.h>
#include <math.h>

#define BB 4
#define NN 1024
#define KK 512
#define HH 8
#define DHh 64
#define HIDd 2048
#define BN (BB*NN)

typedef unsigned short u16;
typedef __attribute__((ext_vector_type(8))) short bf16x8;
typedef __attribute__((ext_vector_type(4))) float f32x4;

// ---------------------------------------------------------------- helpers
__device__ __forceinline__ float gelu_tanh(float x){
    // tanh-gelu via fast exp: 0.5x(1+tanh(u)) = x*t/(t+1), t=e^{2u}
    float u = 0.7978845608028654f*(x + 0.044715f*x*x*x);
    u = fminf(fmaxf(u, -15.f), 15.f);
    float t = __expf(2.f*u);
    return x*t/(t+1.f);
}
__device__ __forceinline__ u16 f2bf(float x){
    unsigned int u = __float_as_uint(x);
    unsigned int r = (u + 0x7fffu + ((u>>16)&1u)) >> 16;
    return (u16)r;
}
__device__ __forceinline__ float bf2f(u16 b){
    return __uint_as_float(((unsigned int)b)<<16);
}
__device__ __forceinline__ void gload16(const void* g, void* l){
    __builtin_amdgcn_global_load_lds((__attribute__((address_space(1))) void*)g,
                                     (__attribute__((address_space(3))) void*)l, 16, 0, 0);
}
__device__ __forceinline__ void wsplit(u16* hi, u16* lo, size_t o, float v){
    u16 h = f2bf(v);
    hi[o] = h;
    if (lo) lo[o] = f2bf(v - bf2f(h));
}

// ---------------------------------------------------------------- generic transpose-split (used for h^T in phase E)
__global__ __launch_bounds__(256) void split_t_k(
    const float* __restrict__ src, u16* __restrict__ hi, u16* __restrict__ lo,
    int Kc, int Nc, long sS, long sD, int square)
{
    __shared__ float t[32][33];
    const int n0 = blockIdx.x*32, k0 = blockIdx.y*32, bz = blockIdx.z;
    const float* S = src + (long)bz*sS;
    const int tx = threadIdx.x & 31, ty = threadIdx.x >> 5;
    for (int r = ty; r < 32; r += 8){
        float v = S[(long)(k0+r)*Nc + n0+tx];
        if (square) v *= v;
        t[r][tx] = v;
    }
    __syncthreads();
    for (int r = ty; r < 32; r += 8){
        float v = t[tx][r];
        long o = (long)bz*sD + (long)(n0+r)*Kc + k0 + tx;
        wsplit(hi, lo, o, v);
    }
}

// ---------------------------------------------------------------- all weight prep in one dispatch, grid (64,16,9)
__global__ __launch_bounds__(256) void wmega_k(
    const float* __restrict__ Wq, const float* __restrict__ Wk,
    const float* __restrict__ Wv, const float* __restrict__ Wo,
    const float* __restrict__ W1, const float* __restrict__ W2,
    const float* __restrict__ gen,
    u16* __restrict__ WQKVh, u16* __restrict__ WQKVl, u16* __restrict__ WoTh,
    u16* __restrict__ WSQKh, u16* __restrict__ WSQKl,
    u16* __restrict__ W1Th, u16* __restrict__ W2Th, u16* __restrict__ GFh)
{
    const int z = blockIdx.z;
    const int tid = threadIdx.x;
    if (z == 8){   // gflat: copy gen(3,K,K) -> GFh[k][g*512+l]
        if (blockIdx.x >= 48) return;
        const int c0 = blockIdx.x*32, k0 = blockIdx.y*32;
        const int tx = tid&31, ty = tid>>5;
        const int g = c0/KK, l0 = c0%KK;
        for (int r=ty; r<32; r+=8)
            GFh[(size_t)(k0+r)*(3*KK) + c0+tx] =
                f2bf(gen[(size_t)g*KK*KK + (size_t)(k0+r)*KK + l0+tx]);
        return;
    }
    __shared__ float t[32][33];
    const float* src; u16* hi; u16* lo=0; int sq=0;
    int n0, k0, Kc, Nc;
    const size_t KK2 = (size_t)KK*KK;
    if (z < 6){
        if (blockIdx.x >= 16) return;
        n0 = blockIdx.x*32; k0 = blockIdx.y*32; Kc=KK; Nc=KK;
        if      (z==0){ src=Wq; hi=WQKVh;       lo=WQKVl; }
        else if (z==1){ src=Wk; hi=WQKVh+KK2;   lo=WQKVl+KK2; }
        else if (z==2){ src=Wv; hi=WQKVh+2*KK2; lo=WQKVl+2*KK2; }
        else if (z==3){ src=Wo; hi=WoTh; }
        else if (z==4){ src=Wq; hi=WSQKh;       lo=WSQKl; sq=1; }
        else          { src=Wk; hi=WSQKh+KK2;   lo=WSQKl+KK2; sq=1; }
    } else if (z == 6){  // W1 [512][2048] -> [2048][512]
        src=W1; hi=W1Th; Kc=KK; Nc=HIDd;
        n0 = blockIdx.x*32; k0 = blockIdx.y*32;
    } else {             // W2 [2048][512] -> [512][2048]
        src=W2; hi=W2Th; Kc=HIDd; Nc=KK;
        n0 = blockIdx.y*32; k0 = blockIdx.x*32;
    }
    const int tx=tid&31, ty=tid>>5;
    for (int r=ty;r<32;r+=8){
        float v = src[(long)(k0+r)*Nc + n0+tx];
        if (sq) v*=v;
        t[r][tx]=v;
    }
    __syncthreads();
    for (int r=ty;r<32;r+=8){
        float v = t[tx][r];
        long o = (long)(n0+r)*Kc + k0+tx;
        wsplit(hi, lo, o, v);
    }
}

// ---------------------------------------------------------------- MFMA GEMM 128x128, single product
// depth-2 / single-__syncthreads pipeline, 32 KB LDS.
// swz=1: 8x4 supertile remap — consecutive 32 blocks cover 8 M-tiles x 4 N-tiles.
__global__ __launch_bounds__(256) void gemm_mfma_k(
    const u16* __restrict__ Ah, const u16* __restrict__ Bh,
    float* __restrict__ C, u16* __restrict__ Chi, u16* __restrict__ Clo,
    int M, int Kc, int Nc, int lda,
    long sA, long sB, long sC, const float* __restrict__ bias, int act,
    int swz)
{
    __shared__ u16 shA[2][128*32], shB[2][128*32];
    int bx = blockIdx.x, by = blockIdx.y;
    if (swz){
        int lin = bx + gridDim.x*by;
        int within = lin & 31, st = lin >> 5;
        int stm = gridDim.x >> 3;
        bx = (st % stm)*8 + (within & 7);
        by = (st / stm)*4 + (within >> 3);
    }
    const int m0 = bx*128, n0 = by*128;
    const int bz = blockIdx.z;
    const u16* gAh = Ah + (long)bz*sA;
    const u16* gBh = Bh + (long)bz*sB;
    const int tid = threadIdx.x;
    const int wave = tid >> 6, lane = tid & 63;
    const int quad = lane >> 4, r16 = lane & 15;
    const int wm = (wave>>1)*64, wn = (wave&1)*64;

    f32x4 acc[4][4];
    #pragma unroll
    for (int i=0;i<4;i++)
        #pragma unroll
        for (int j=0;j<4;j++) acc[i][j] = (f32x4){0.f,0.f,0.f,0.f};

    auto stage = [&](int sel, int k0){
        #pragma unroll
        for (int half=0; half<2; ++half){
            int c = half*256 + tid;
            int row = c >> 2;
            int kg = ((c & 3) ^ ((row >> 1) & 3))*8;   // pre-swizzled global slot
            gload16(gAh + (long)(m0+row)*lda + k0 + kg, &shA[sel][c*8]);
            gload16(gBh + (long)(n0+row)*Kc  + k0 + kg, &shB[sel][c*8]);
        }
    };

    const int nsteps = Kc >> 5;
    stage(0, 0);
    __syncthreads();
    int cur = 0;
    const int swr = (quad ^ ((r16 >> 1) & 3))*8;       // undo swizzle on read
    for (int t = 0; t < nsteps; ++t){
        if (t+1 < nsteps) stage(cur^1, (t+1)<<5);
        bf16x8 afh[4], bfh[4];
        #pragma unroll
        for (int i=0;i<4;i++){
            afh[i] = *(const bf16x8*)&shA[cur][(wm+i*16+r16)*32 + swr];
            bfh[i] = *(const bf16x8*)&shB[cur][(wn+i*16+r16)*32 + swr];
        }
        #pragma unroll
        for (int i=0;i<4;i++)
            #pragma unroll
            for (int j=0;j<4;j++)
                acc[i][j] = __builtin_amdgcn_mfma_f32_16x16x32_bf16(afh[i], bfh[j], acc[i][j], 0,0,0);
        __syncthreads();
        cur ^= 1;
    }
    #pragma unroll
    for (int i=0;i<4;i++){
        #pragma unroll
        for (int j=0;j<4;j++){
            int gc = n0 + wn + j*16 + r16;
            if (gc >= Nc) continue;
            float bv = bias ? bias[gc] : 0.f;
            #pragma unroll
            for (int r=0;r<4;r++){
                long gr = m0 + wm + i*16 + quad*4 + r;
                float v = acc[i][j][r] + bv;
                if (act) v = gelu_tanh(v);
                long o = (long)bz*sC + gr*Nc + gc;
                if (C) C[o] = v;
                if (Chi){ u16 t = f2bf(v); Chi[o] = t; if (Clo) Clo[o] = f2bf(v - bf2f(t)); }
            }
        }
    }
}

// ---------------------------------------------------------------- MFMA GEMM 128x128, 3-product via VIRTUAL K
// K_virt = 3*Kc; segment 0: Ah*Bh, 1: Al*Bh, 2: Ah*Bl (pointer switch in staging).
__global__ __launch_bounds__(256) void gemm_v3_k(
    const u16* __restrict__ Ah, const u16* __restrict__ Al,
    const u16* __restrict__ Bh, const u16* __restrict__ Bl,
    float* __restrict__ C,
    int M, int Kc, int Nc, int lda,
    long sA, long sB, long sC, int cskip)
{
    __shared__ u16 shA[2][128*32], shB[2][128*32];
    const int m0 = blockIdx.x*128, n0 = blockIdx.y*128;
    if (cskip == 1 && n0 > m0 + 127) return;
    const int bz = blockIdx.z;
    const u16* gAh = Ah + (long)bz*sA;
    const u16* gAl = Al + (long)bz*sA;
    const u16* gBh = Bh + (long)bz*sB;
    const u16* gBl = Bl + (long)bz*sB;
    const int tid = threadIdx.x;
    const int wave = tid >> 6, lane = tid & 63;
    const int quad = lane >> 4, r16 = lane & 15;
    const int wm = (wave>>1)*64, wn = (wave&1)*64;

    f32x4 acc[4][4];
    #pragma unroll
    for (int i=0;i<4;i++)
        #pragma unroll
        for (int j=0;j<4;j++) acc[i][j] = (f32x4){0.f,0.f,0.f,0.f};

    const int segsteps = Kc >> 5;
    const int nsteps = 3*segsteps;
    auto stage = [&](int sel, int t){
        int seg = (t >= segsteps) + (t >= 2*segsteps);
        int k0 = (t - seg*segsteps) << 5;
        const u16* a = (seg==1) ? gAl : gAh;
        const u16* b = (seg==2) ? gBl : gBh;
        #pragma unroll
        for (int half=0; half<2; ++half){
            int c = half*256 + tid;
            int row = c >> 2;
            int kg = ((c & 3) ^ ((row >> 1) & 3))*8;
            gload16(a + (long)(m0+row)*lda + k0 + kg, &shA[sel][c*8]);
            gload16(b + (long)(n0+row)*Kc  + k0 + kg, &shB[sel][c*8]);
        }
    };

    stage(0, 0);
    __syncthreads();
    int cur = 0;
    const int swr = (quad ^ ((r16 >> 1) & 3))*8;
    for (int t = 0; t < nsteps; ++t){
        if (t+1 < nsteps) stage(cur^1, t+1);
        bf16x8 afh[4], bfh[4];
        #pragma unroll
        for (int i=0;i<4;i++){
            afh[i] = *(const bf16x8*)&shA[cur][(wm+i*16+r16)*32 + swr];
            bfh[i] = *(const bf16x8*)&shB[cur][(wn+i*16+r16)*32 + swr];
        }
        #pragma unroll
        for (int i=0;i<4;i++)
            #pragma unroll
            for (int j=0;j<4;j++)
                acc[i][j] = __builtin_amdgcn_mfma_f32_16x16x32_bf16(afh[i], bfh[j], acc[i][j], 0,0,0);
        __syncthreads();
        cur ^= 1;
    }
    #pragma unroll
    for (int i=0;i<4;i++){
        #pragma unroll
        for (int j=0;j<4;j++){
            int gc = n0 + wn + j*16 + r16;
            if (gc >= Nc) continue;
            #pragma unroll
            for (int r=0;r<4;r++){
                long gr = m0 + wm + i*16 + quad*4 + r;
                long o = (long)bz*sC + gr*Nc + gc;
                C[o] = acc[i][j][r];
            }
        }
    }
}

// ---------------------------------------------------------------- transport GEMM 64x64:
// out[r][n] = sum_g (esign*phi[r][g]) * sum_kd A[r][kd]*gen[g][n][kd]
// = virtual-K GEMM over GF[n*1536 + g*512 + kd] with per-segment register fold.
__global__ __launch_bounds__(256) void tgemm_k(
    const u16* __restrict__ Ahh,   // [M][512] bf16
    const u16* __restrict__ GFh,   // [n][g*512+kd]
    const float* __restrict__ phi, float esign,
    float* __restrict__ C, u16* __restrict__ Chi, u16* __restrict__ Clo,
    const float* __restrict__ t_x, const float* __restrict__ t_a1,
    const float* __restrict__ t_res)
{
    __shared__ u16 shA[2][64*64], shB[2][64*64];
    const int m0 = blockIdx.x*64, n0 = blockIdx.y*64;
    const int tid = threadIdx.x;
    const int wave = tid >> 6, lane = tid & 63;
    const int quad = lane >> 4, r16 = lane & 15;
    const int wr = wave*16;

    float ph[3][4];
    #pragma unroll
    for (int sgi=0; sgi<3; ++sgi)
        #pragma unroll
        for (int r=0; r<4; ++r)
            ph[sgi][r] = esign*phi[(size_t)(m0+wr+quad*4+r)*3 + sgi];

    f32x4 acc[4], tot[4];
    #pragma unroll
    for (int j=0;j<4;j++){ acc[j] = (f32x4){0.f,0.f,0.f,0.f}; tot[j] = acc[j]; }

    auto stage = [&](int sel, int t){
        int seg = t >> 3, k0 = (t & 7) << 6;
        #pragma unroll
        for (int rep=0; rep<2; ++rep){
            int c = rep*256 + tid;
            int row = c >> 3;
            int kg = ((c & 7) ^ (row & 7))*8;
            gload16(Ahh + (long)(m0+row)*KK + k0 + kg, &shA[sel][c*8]);
            gload16(GFh + (long)(n0+row)*(3*KK) + seg*KK + k0 + kg, &shB[sel][c*8]);
        }
    };

    stage(0, 0);
    __syncthreads();
    int cur = 0;
    for (int t = 0; t < 24; ++t){
        if (t+1 < 24) stage(cur^1, t+1);
        #pragma unroll
        for (int kk=0; kk<2; ++kk){
            const int s = (((kk<<2)+quad) ^ (r16 & 7))*8;
            bf16x8 af = *(const bf16x8*)&shA[cur][(wr+r16)*64 + s];
            #pragma unroll
            for (int j=0;j<4;j++){
                bf16x8 bh = *(const bf16x8*)&shB[cur][(j*16+r16)*64 + s];
                acc[j] = __builtin_amdgcn_mfma_f32_16x16x32_bf16(af, bh, acc[j], 0,0,0);
            }
        }
        if ((t & 7) == 7){
            int sgi = t >> 3;
            #pragma unroll
            for (int j=0;j<4;j++){
                #pragma unroll
                for (int r=0;r<4;r++) tot[j][r] += ph[sgi][r]*acc[j][r];
                acc[j] = (f32x4){0.f,0.f,0.f,0.f};
            }
        }
        __syncthreads();
        cur ^= 1;
    }
    #pragma unroll
    for (int j=0;j<4;j++){
        int gc = n0 + j*16 + r16;
        #pragma unroll
        for (int r=0;r<4;r++){
            long gr = m0 + wr + quad*4 + r;
            float v = tot[j][r];
            long o = gr*(long)KK + gc;
            if (t_x){
                v = t_x[o] + t_a1[o] + 0.5f*v;
                if (t_res) v += t_res[o];
            }
            if (C) C[o] = v;
            if (Chi){ u16 t2 = f2bf(v); Chi[o] = t2; if (Clo) Clo[o] = f2bf(v - bf2f(t2)); }
        }
    }
}

// ---------------------------------------------------------------- MFMA GEMM 64x64
// depth-2 / single-__syncthreads pipeline, 32KB LDS. K-step 64.
// swz=1: 8x4 supertile remap. epilogue: fused FFN update (fmode 1=mid, 2=final)
__global__ __launch_bounds__(256) void gemm64_k(
    const u16* __restrict__ Ah, const u16* __restrict__ Bh,
    float* __restrict__ C, u16* __restrict__ Chi, u16* __restrict__ Clo,
    int M, int Kc, int Nc, int lda,
    long sA, long sB, long sC, const float* __restrict__ bias, int act,
    int ktrim, int swz,
    const float* __restrict__ f_hin, const float* __restrict__ f_bmh,
    const float* __restrict__ f_mup, const float* __restrict__ f_lr,
    u16* __restrict__ f_hh, float* __restrict__ f_hout,
    const float* __restrict__ f_mrb, const float* __restrict__ f_mn2,
    float* __restrict__ f_out, int fmode)
{
    __shared__ u16 shA[2][64*64], shB[2][64*64];
    int bx = blockIdx.x, by = blockIdx.y;
    if (swz){
        int lin = bx + gridDim.x*by;
        int within = lin & 31, st = lin >> 5;
        int stm = gridDim.x >> 3;
        bx = (st % stm)*8 + (within & 7);
        by = (st / stm)*4 + (within >> 3);
    }
    const int m0 = bx*64, n0 = by*64;
    const int bz = blockIdx.z;
    const u16* gA = Ah + (long)bz*sA;
    const u16* gB = Bh + (long)bz*sB;
    const int tid = threadIdx.x;
    const int wave = tid >> 6, lane = tid & 63;
    const int quad = lane >> 4, r16 = lane & 15;
    const int wr = wave*16;
    const int kend = ktrim ? min(Kc, m0 + 64) : Kc;
    const int nsteps = kend >> 6;

    f32x4 acc[4];
    #pragma unroll
    for (int j=0;j<4;j++) acc[j] = (f32x4){0.f,0.f,0.f,0.f};

    auto stage = [&](int sel, int k0){
        #pragma unroll
        for (int rep=0; rep<2; ++rep){
            int c = rep*256 + tid;
            int row = c >> 3;
            int kg = ((c & 7) ^ (row & 7))*8;     // pre-swizzled global slot
            gload16(gA + (long)(m0+row)*lda + k0 + kg, &shA[sel][c*8]);
            gload16(gB + (long)(n0+row)*Kc + k0 + kg, &shB[sel][c*8]);
        }
    };

    stage(0, 0);
    __syncthreads();
    int cur = 0;
    for (int t = 0; t < nsteps; ++t){
        if (t+1 < nsteps) stage(cur^1, (t+1)<<6);
        #pragma unroll
        for (int kk=0; kk<2; ++kk){
            const int s = (((kk<<2)+quad) ^ (r16 & 7))*8;   // undo swizzle on read
            bf16x8 af = *(const bf16x8*)&shA[cur][(wr+r16)*64 + s];
            #pragma unroll
            for (int j=0;j<4;j++){
                bf16x8 bh = *(const bf16x8*)&shB[cur][(j*16+r16)*64 + s];
                acc[j] = __builtin_amdgcn_mfma_f32_16x16x32_bf16(af, bh, acc[j], 0,0,0);
            }
        }
        __syncthreads();
        cur ^= 1;
    }
    float lrv = 0.f;
    if (fmode) lrv = *f_lr;
    #pragma unroll
    for (int j=0;j<4;j++){
        int gc = n0 + j*16 + r16;
        float bv = bias ? bias[gc] : 0.f;
        #pragma unroll
        for (int r=0;r<4;r++){
            long gr = m0 + wr + quad*4 + r;
            float v = acc[j][r] + bv;
            if (act) v = gelu_tanh(v);
            long o = (long)bz*sC + gr*Nc + gc;
            if (fmode){
                float hv = f_hin[o];
                float val = hv + lrv*(v - (1e-3f*(hv - f_mup[o]) + (hv - f_bmh[o])));
                if (fmode == 1){ f_hout[o] = val; f_hh[o] = f2bf(val); }
                else           { f_out[o] = f_mrb[o] + val - f_mn2[o]; }
            } else {
                if (C) C[o] = v;
                if (Chi){ u16 t = f2bf(v); Chi[o] = t; if (Clo) Clo[o] = f2bf(v - bf2f(t)); }
            }
        }
    }
}

// ---------------------------------------------------------------- LayerNorm (+bf16 out, +sigma split, +output copies)
__global__ __launch_bounds__(256) void ln_k(
    const float* __restrict__ x, const float* __restrict__ g,
    const float* __restrict__ be, float* __restrict__ y,
    u16* __restrict__ yh16,
    const float* __restrict__ sg, u16* __restrict__ sgh, u16* __restrict__ sgl,
    float* __restrict__ osig, const float* __restrict__ phi, float* __restrict__ ophi)
{
    __shared__ float sh[8];
    const int r = blockIdx.x, tid = threadIdx.x;
    const float* xr = x + (long)r*KK;
    float2 v = *(const float2*)(xr + tid*2);
    float s = v.x+v.y, s2 = v.x*v.x+v.y*v.y;
    #pragma unroll
    for (int o=32;o>0;o>>=1){ s += __shfl_down(s,o); s2 += __shfl_down(s2,o); }
    if ((tid&63)==0){ sh[tid>>6]=s; sh[4+(tid>>6)]=s2; }
    __syncthreads();
    s  = sh[0]+sh[1]+sh[2]+sh[3];
    s2 = sh[4]+sh[5]+sh[6]+sh[7];
    const float mean = s*(1.f/KK);
    const float var  = s2*(1.f/KK) - mean*mean;
    const float rs = rsqrtf(var + 1e-5f);
    float2 gg = *(const float2*)(g + tid*2);
    float2 bb = *(const float2*)(be + tid*2);
    float ox = (v.x-mean)*rs*gg.x + bb.x;
    float oy = (v.y-mean)*rs*gg.y + bb.y;
    long o = (long)r*KK + tid*2;
    *(float2*)(y + o) = make_float2(ox, oy);
    if (yh16){ yh16[o] = f2bf(ox); yh16[o+1] = f2bf(oy); }
    if (sgh){
        float2 sv = *(const float2*)(sg + o);
        wsplit(sgh, sgl, o,   sv.x);
        wsplit(sgh, sgl, o+1, sv.y);
        if (osig) *(float2*)(osig + o) = sv;
    }
    if (ophi && tid < 3) ophi[(size_t)r*3 + tid] = phi[(size_t)r*3 + tid];
}

// ---------------------------------------------------------------- merged attention prep + V transpose
__global__ __launch_bounds__(512) void prepvt_k(
    const float* __restrict__ QKV, const float* __restrict__ SQSK,
    u16* __restrict__ CFh, u16* __restrict__ CFl,
    u16* __restrict__ KSh, u16* __restrict__ KSl, float* __restrict__ dvec,
    u16* __restrict__ VTh)
{
    __shared__ float t[64][65];
    const int bx = blockIdx.x;
    const int tid = threadIdx.x;
    if (bx < BN){
        const int bn = bx;
        const int b = bn / NN, n = bn % NN;
        const int h = tid >> 6, d = tid & 63;
        float q  = QKV[(size_t)bn*1536 + h*DHh + d];
        float k  = QKV[(size_t)bn*1536 + KK + h*DHh + d];
        float sq = SQSK[(size_t)bn*1024 + h*DHh + d] + 1e-8f;
        float sk = SQSK[(size_t)bn*1024 + KK + h*DHh + d] + 1e-8f;
        float inv = 1.f/sq;
        float nqi = -2.f*q*inv;
        float skk = sk + k*k;
        const size_t base = ((size_t)(h*BB + b)*NN + n)*128;
        wsplit(CFh, CFl, base+d,    inv);
        wsplit(CFh, CFl, base+64+d, nqi);
        wsplit(KSh, KSl, base+d,    skk);
        wsplit(KSh, KSl, base+64+d, k);
        float dv = __logf(sk);
        #pragma unroll
        for (int o=32;o>0;o>>=1) dv += __shfl_down(dv,o);
        if (d==0) dvec[((size_t)h*BB + b)*NN + n] = dv;
        return;
    }
    const int idx = bx - BN;
    const int n0 = (idx & 15)*64;
    const int h = (idx>>4)&7;
    const int b = idx>>7;
    const int c4 = (tid & 15) * 4;
    const int r0 = tid >> 4;     // 0..31
    for (int rr = r0; rr < 64; rr += 32){
        float4 v = *(const float4*)(QKV + (size_t)(b*NN + n0 + rr)*1536 + 1024 + h*DHh + c4);
        t[c4+0][rr] = v.x; t[c4+1][rr] = v.y; t[c4+2][rr] = v.z; t[c4+3][rr] = v.w;
    }
    __syncthreads();
    for (int dd = r0; dd < 64; dd += 32){
        size_t base = ((size_t)(h*BB + b)*64 + dd)*NN + n0 + c4;
        #pragma unroll
        for (int q=0;q<4;q++) VTh[base+q] = f2bf(t[dd][c4+q]);
    }
}

// ---------------------------------------------------------------- softmax, all 8 heads, register-resident
// 256 threads x float4: thread owns columns [4*tid, 4*tid+4) for ALL heads.
// Scores live in registers (no s_sc LDS round-trips); bm accumulates in registers.
// 2 syncs/head (vs 5); next head's row+dvec prefetched under current reduce chain.
// In-place bf16 store is safe: all reads of head h complete before sync#1; stores
// happen after sync#2.
__global__ __launch_bounds__(256) void softmax_all_k(
    float* __restrict__ S, const float* __restrict__ dvec, u16* __restrict__ BMh)
{
    __shared__ float s_redA[2][4], s_redB[2][4];
    const int tid = threadIdx.x;
    const int b = blockIdx.x >> 10, i = blockIdx.x & (NN-1);
    const int L = i + 1;
    const int JEND = ((i >> 6) + 1) << 6;
    const int j4 = tid*4;
    const bool act = (j4 < JEND);
    const int wv = tid >> 6;
    const bool lane0 = ((tid & 63) == 0);

    float bm[4] = {0.f,0.f,0.f,0.f};
    float4 rv = make_float4(0,0,0,0), dpv = make_float4(0,0,0,0);
    if (act){
        rv  = *(const float4*)(S + ((long)(0*BB + b)*NN + i)*NN + j4);
        dpv = *(const float4*)(dvec + (size_t)(0*BB + b)*NN + j4);
    }
    for (int h = 0; h < 8; ++h){
        const int z = h*BB + b;
        float4 rvn = make_float4(0,0,0,0), dpn = make_float4(0,0,0,0);
        if (h < 7 && act){
            const int zn = (h+1)*BB + b;
            rvn = *(const float4*)(S + ((long)zn*NN + i)*NN + j4);
            dpn = *(const float4*)(dvec + (size_t)zn*NN + j4);
        }
        float sc[4];
        const float* rp = (const float*)&rv;
        const float* dp = (const float*)&dpv;
        #pragma unroll
        for (int e=0;e<4;e++){
            float s = -0.5f*rp[e] + 0.5f*dp[e];
            sc[e] = (act && (j4 + e < L)) ? s : -3.0e38f;
        }
        float lm = fmaxf(fmaxf(sc[0],sc[1]), fmaxf(sc[2],sc[3]));
        #pragma unroll
        for (int o=32;o>0;o>>=1) lm = fmaxf(lm, __shfl_xor(lm, o));
        if (lane0) s_redA[h&1][wv] = lm;
        __syncthreads();
        const float mx = fmaxf(fmaxf(s_redA[h&1][0],s_redA[h&1][1]),
                               fmaxf(s_redA[h&1][2],s_redA[h&1][3]));
        float w4[4], ps = 0.f;
        #pragma unroll
        for (int e=0;e<4;e++){
            float e1 = (act && (j4 + e < L)) ? __expf(sc[e]-mx) : 0.f;
            w4[e] = e1; ps += e1;
        }
        #pragma unroll
        for (int o=32;o>0;o>>=1) ps += __shfl_xor(ps, o);
        if (lane0) s_redB[h&1][wv] = ps;
        __syncthreads();
        const float isum = 1.f/(s_redB[h&1][0]+s_redB[h&1][1]+s_redB[h&1][2]+s_redB[h&1][3]);
        if (act){
            u16* brow = (u16*)(S + ((long)z*NN + i)*NN);
            ushort4 st;
            float w0=w4[0]*isum, w1=w4[1]*isum, w2=w4[2]*isum, w3=w4[3]*isum;
            bm[0]+=0.125f*w0; bm[1]+=0.125f*w1; bm[2]+=0.125f*w2; bm[3]+=0.125f*w3;
            st.x=f2bf(w0); st.y=f2bf(w1); st.z=f2bf(w2); st.w=f2bf(w3);
            *(ushort4*)(brow + j4) = st;
        }
        rv = rvn; dpv = dpn;
    }
    if (act){
        const long bmrow = ((long)b*NN + i)*NN;
        ushort4 st;
        st.x=f2bf(bm[0]); st.y=f2bf(bm[1]); st.z=f2bf(bm[2]); st.w=f2bf(bm[3]);
        *(ushort4*)(BMh + bmrow + j4) = st;
    }
}

// ---------------------------------------------------------------- PV, all 32 (head,batch) slices, grid (NN/64, 32)
__global__ __launch_bounds__(256) void pv_k(
    const u16* __restrict__ Sbeta,
    const u16* __restrict__ VTh,
    u16* __restrict__ xh)
{
    __shared__ u16 shA[2][64*64], shB[2][64*64];
    const int m0 = blockIdx.x*64;
    const int z = blockIdx.y;              // z = head*BB + b
    const int b = z & 3, head = z >> 2;
    const int tid = threadIdx.x;
    const int wave = tid>>6, lane = tid&63;
    const int quad = lane>>4, r16 = lane&15;
    f32x4 acc[4];
    #pragma unroll
    for (int j=0;j<4;j++) acc[j]=(f32x4){0.f,0.f,0.f,0.f};
    const int nsteps = (m0 >> 6) + 1;

    auto stage = [&](int sel, int j0){
        #pragma unroll
        for (int rep=0; rep<2; ++rep){
            int c = rep*256 + tid;
            int row = c >> 3;
            int k8 = ((c & 7) ^ (row & 7))*8;
            gload16(Sbeta + ((size_t)(z*NN + m0 + row))*(2*NN) + j0 + k8, &shA[sel][c*8]);
            gload16(VTh + ((size_t)(z*64 + row))*NN + j0 + k8, &shB[sel][c*8]);
        }
    };

    stage(0, 0);
    __syncthreads();
    int cur = 0;
    for (int t = 0; t < nsteps; ++t){
        if (t+1 < nsteps) stage(cur^1, (t+1)<<6);
        #pragma unroll
        for (int kk=0; kk<2; ++kk){
            const int s = (((kk<<2)+quad) ^ (r16 & 7))*8;
            bf16x8 af = *(const bf16x8*)&shA[cur][(wave*16 + r16)*64 + s];
            #pragma unroll
            for (int nj=0; nj<4; ++nj){
                bf16x8 bh = *(const bf16x8*)&shB[cur][(nj*16 + r16)*64 + s];
                acc[nj] = __builtin_amdgcn_mfma_f32_16x16x32_bf16(af, bh, acc[nj], 0,0,0);
            }
        }
        __syncthreads();
        cur ^= 1;
    }
    #pragma unroll
    for (int nj=0;nj<4;nj++){
        #pragma unroll
        for (int r=0;r<4;r++){
            int i = m0 + wave*16 + quad*4 + r;
            int d = nj*16 + r16;
            size_t o = ((size_t)(b*NN)+i)*KK + head*64 + d;
            xh[o] = f2bf(acc[nj][r]);
        }
    }
}

// ---------------------------------------------------------------- launch
extern "C" void kernel_launch(void* const* d_in, const int* in_sizes, int n_in,
                              void* d_out, int out_size, void* d_ws, size_t ws_size,
                              hipStream_t stream) {
    const float* mu_q    = (const float*)d_in[0];
    const float* sigma_q = (const float*)d_in[1];
    const float* phi     = (const float*)d_in[2];
    const float* gen     = (const float*)d_in[3];
    const float* mu_prior= (const float*)d_in[5];
    const float* Wq = (const float*)d_in[6];
    const float* Wk = (const float*)d_in[7];
    const float* Wv = (const float*)d_in[8];
    const float* Wo = (const float*)d_in[9];
    const float* g1 = (const float*)d_in[10];
    const float* be1= (const float*)d_in[11];
    const float* g2 = (const float*)d_in[12];
    const float* be2= (const float*)d_in[13];
    const float* W1 = (const float*)d_in[14];
    const float* bh1= (const float*)d_in[15];
    const float* W2 = (const float*)d_in[16];
    const float* bh2= (const float*)d_in[17];
    const float* lr = (const float*)d_in[18];
    float* out = (float*)d_out;

    float* w = (float*)d_ws;
    size_t off = 0;
    auto alloc = [&](size_t n){ float* p = w + off; off += (n+3)&~(size_t)3; return p; };
    auto ualloc = [&](size_t n){ return (u16*)alloc((n+1)/2); };

    // Xb..REG is one contiguous 32*NN*NN-float region reused as Sbig in phase C.
    float* Xb   = alloc((size_t)BN*KK);        // mu_n; later mn2
    float* A1b  = alloc((size_t)BN*KK);        // a1 / bmh
    float* A2b  = alloc((size_t)BN*KK);        // (spacer; part of Sbig)
    float* QKVb = alloc((size_t)BN*3*KK);      // QKV; later WOb / Hb / MRb
    float* SQSKb= alloc((size_t)BN*2*KK);
    float* REG  = alloc((size_t)16*NN*NN);     // SGh/SGl/Xh/A1h/WOh | Sbig tail | ZH
    float* Sbig = Xb;                          // 32 * NN*NN floats
    u16*  SGh   = (u16*)REG;
    u16*  SGl   = SGh + (size_t)BN*KK;
    u16*  Xh    = SGl + (size_t)BN*KK;
    u16*  A1h   = Xh  + (size_t)BN*KK;
    u16*  WOh   = A1h + (size_t)BN*KK;
    u16*  ZH    = (u16*)REG;
    float* Db_  = alloc((size_t)HH*BB*NN);
    u16* AH  = ualloc((size_t)BN*HIDd); u16* AL  = ualloc((size_t)BN*HIDd);
    u16* CFh = AH;
    u16* CFl = AH + (size_t)HH*BB*NN*128;
    u16* KSh = AL;
    u16* KSl = AL + (size_t)HH*BB*NN*128;
    u16* VTh = ualloc((size_t)HH*BB*64*NN);
    u16* GFh = ualloc((size_t)3*KK*KK);
    u16* WQKVh= ualloc((size_t)3*KK*KK); u16* WQKVl= ualloc((size_t)3*KK*KK);
    u16* WSQKh= ualloc((size_t)2*KK*KK); u16* WSQKl= ualloc((size_t)2*KK*KK);
    u16* WoTh= ualloc((size_t)KK*KK);
    u16* W1Th= ualloc((size_t)KK*HIDd);
    u16* W2Th= ualloc((size_t)KK*HIDd);
    u16* BMh = ualloc((size_t)BB*NN*NN);
    u16* HTh = ualloc((size_t)BB*KK*NN);
    float* WOb = QKVb;
    float* Hb  = QKVb + (size_t)BN*KK;
    float* MRb = QKVb + 2*(size_t)BN*KK;
    float* MN2b= Xb;
    (void)A2b;

    // ---- weight prep: one dispatch ----
    {
        dim3 gw(64, 16, 9);
        wmega_k<<<gw, 256, 0, stream>>>(Wq, Wk, Wv, Wo, W1, W2, gen,
                                        WQKVh, WQKVl, WoTh, WSQKh, WSQKl,
                                        W1Th, W2Th, GFh);
    }

    // ---- phase A: LN1 (+bf16 out, +sigma split, +output copies) + forward transport ----
    ln_k<<<BN, 256, 0, stream>>>(mu_q, g1, be1, Xb, Xh, sigma_q, SGh, SGl,
                                 out + (size_t)BN*KK, phi, out + 2*(size_t)BN*KK);
    {
        dim3 tg(BN/64, KK/64, 1);
        tgemm_k<<<tg, 256, 0, stream>>>(Xh, GFh, phi, 1.f, A1b, A1h, 0, 0, 0, 0);
        tgemm_k<<<tg, 256, 0, stream>>>(A1h, GFh, phi, 1.f, 0, AH, AL, Xb, A1b, 0);
    }

    // ---- phase B: projections (virtual-K 3-product) + merged attention prep ----
    {
        dim3 gq(BN/128, (3*KK)/128, 1);   // (32,12)
        gemm_v3_k<<<gq, 256, 0, stream>>>(AH, AL, WQKVh, WQKVl, QKVb,
            BN, KK, 3*KK, KK, 0, 0, 0, 0);
        dim3 gs(BN/128, (2*KK)/128, 1);   // (32,8)
        gemm_v3_k<<<gs, 256, 0, stream>>>(SGh, SGl, WSQKh, WSQKl, SQSKb,
            BN, KK, 2*KK, KK, 0, 0, 0, 0);
    }
    prepvt_k<<<BN + 512, 512, 0, stream>>>(QKVb, SQSKb, CFh, CFl, KSh, KSl, Db_, VTh);

    // ---- phase C: attention, all 8 heads in 3 dispatches (Sbig = Xb..REG, 134 MB) ----
    {
        dim3 sg(NN/128, NN/128, 32);
        gemm_v3_k<<<sg, 256, 0, stream>>>(CFh, CFl, KSh, KSl, Sbig,
            NN, 128, NN, 128, (long)NN*128, (long)NN*128, (long)NN*NN, 1);
        softmax_all_k<<<BB*NN, 256, 0, stream>>>(Sbig, Db_, BMh);
        dim3 pg(NN/64, 32, 1);
        pv_k<<<pg, 256, 0, stream>>>((const u16*)Sbig, VTh, AH);
    }

    // ---- phase D: output proj + back transport (fused mrb) + LN2 ----
    {
        dim3 wg(BN/64, KK/64, 1);
        gemm64_k<<<wg, 256, 0, stream>>>(AH, WoTh, WOb, WOh, 0,
            BN, KK, KK, KK, 0,0,0, nullptr, 0, 0, 0,
            0,0,0,0,0,0,0,0,0,0);
        dim3 tg(BN/64, KK/64, 1);
        tgemm_k<<<tg, 256, 0, stream>>>(WOh, GFh, phi, -1.f, A1b, A1h, 0, 0, 0, 0);
        tgemm_k<<<tg, 256, 0, stream>>>(A1h, GFh, phi, -1.f, MRb, 0, 0, WOb, A1b, mu_q);
    }
    ln_k<<<BN, 256, 0, stream>>>(MRb, g2, be2, MN2b, AH, 0, 0, 0, 0, 0, 0);

    // ---- phase E: 2 VFE iterations (bmh first, then W1, then W2 with fused update) ----
    for (int it=0; it<2; ++it){
        const float* hin = (it==0) ? MN2b : Hb;
        {
            dim3 tg(KK/32, NN/32, BB);
            split_t_k<<<tg, 256, 0, stream>>>(hin, HTh, 0, NN, KK,
                                              (long)NN*KK, (long)KK*NN, 0);
        }
        {
            dim3 bg(NN/64, KK/64, BB);
            gemm64_k<<<bg, 256, 0, stream>>>(BMh, HTh, A1b, 0,0,
                                             NN, NN, KK, NN,
                                             (long)NN*NN, (long)KK*NN, (long)NN*KK,
                                             nullptr, 0, 1, 0,
                                             0,0,0,0,0,0,0,0,0,0);
        }
        {
            dim3 wg1(BN/128, HIDd/128, 1);   // (32,16), supertile swizzle
            gemm_mfma_k<<<wg1, 256, 0, stream>>>(AH, W1Th, 0, ZH, 0,
                BN, KK, HIDd, KK, 0, 0, 0, bh1, 1, 1);
        }
        {   // W2 + fused FFN update, supertile swizzle
            dim3 wg(BN/64, KK/64, 1);
            gemm64_k<<<wg, 256, 0, stream>>>(ZH, W2Th, 0,0,0,
                                             BN, HIDd, KK, HIDd, 0,0,0, bh2, 0, 0, 1,
                                             hin, A1b, mu_prior, lr, AH, Hb, MRb, MN2b, out,
                                             (it==0) ? 1 : 2);
        }
    }

    (void)in_sizes; (void)n_in; (void)out_size; (void)ws_size;
}

// Round 8
// 579.055 us; speedup vs baseline: 1.1040x; 1.0119x over previous
//
#include <hip/hip_runtime.h>
#include <math.h>

#define BB 4
#define NN 1024
#define KK 512
#define HH 8
#define DHh 64
#define HIDd 2048
#define BN (BB*NN)

typedef unsigned short u16;
typedef __attribute__((ext_vector_type(8))) short bf16x8;
typedef __attribute__((ext_vector_type(4))) float f32x4;

// ---------------------------------------------------------------- helpers
__device__ __forceinline__ float gelu_tanh(float x){
    // tanh-gelu via fast exp: 0.5x(1+tanh(u)) = x*t/(t+1), t=e^{2u}
    float u = 0.7978845608028654f*(x + 0.044715f*x*x*x);
    u = fminf(fmaxf(u, -15.f), 15.f);
    float t = __expf(2.f*u);
    return x*t/(t+1.f);
}
__device__ __forceinline__ u16 f2bf(float x){
    unsigned int u = __float_as_uint(x);
    unsigned int r = (u + 0x7fffu + ((u>>16)&1u)) >> 16;
    return (u16)r;
}
__device__ __forceinline__ float bf2f(u16 b){
    return __uint_as_float(((unsigned int)b)<<16);
}
__device__ __forceinline__ void gload16(const void* g, void* l){
    __builtin_amdgcn_global_load_lds((__attribute__((address_space(1))) void*)g,
                                     (__attribute__((address_space(3))) void*)l, 16, 0, 0);
}
__device__ __forceinline__ void wsplit(u16* hi, u16* lo, size_t o, float v){
    u16 h = f2bf(v);
    hi[o] = h;
    if (lo) lo[o] = f2bf(v - bf2f(h));
}

// ---------------------------------------------------------------- generic transpose-split (used for h^T in phase E)
__global__ __launch_bounds__(256) void split_t_k(
    const float* __restrict__ src, u16* __restrict__ hi, u16* __restrict__ lo,
    int Kc, int Nc, long sS, long sD, int square)
{
    __shared__ float t[32][33];
    const int n0 = blockIdx.x*32, k0 = blockIdx.y*32, bz = blockIdx.z;
    const float* S = src + (long)bz*sS;
    const int tx = threadIdx.x & 31, ty = threadIdx.x >> 5;
    for (int r = ty; r < 32; r += 8){
        float v = S[(long)(k0+r)*Nc + n0+tx];
        if (square) v *= v;
        t[r][tx] = v;
    }
    __syncthreads();
    for (int r = ty; r < 32; r += 8){
        float v = t[tx][r];
        long o = (long)bz*sD + (long)(n0+r)*Kc + k0 + tx;
        wsplit(hi, lo, o, v);
    }
}

// ---------------------------------------------------------------- all weight prep in one dispatch, grid (64,16,9)
__global__ __launch_bounds__(256) void wmega_k(
    const float* __restrict__ Wq, const float* __restrict__ Wk,
    const float* __restrict__ Wv, const float* __restrict__ Wo,
    const float* __restrict__ W1, const float* __restrict__ W2,
    const float* __restrict__ gen,
    u16* __restrict__ WQKVh, u16* __restrict__ WQKVl, u16* __restrict__ WoTh,
    u16* __restrict__ WSQKh, u16* __restrict__ WSQKl,
    u16* __restrict__ W1Th, u16* __restrict__ W2Th, u16* __restrict__ GFh)
{
    const int z = blockIdx.z;
    const int tid = threadIdx.x;
    if (z == 8){   // gflat: copy gen(3,K,K) -> GFh[k][g*512+l]
        if (blockIdx.x >= 48) return;
        const int c0 = blockIdx.x*32, k0 = blockIdx.y*32;
        const int tx = tid&31, ty = tid>>5;
        const int g = c0/KK, l0 = c0%KK;
        for (int r=ty; r<32; r+=8)
            GFh[(size_t)(k0+r)*(3*KK) + c0+tx] =
                f2bf(gen[(size_t)g*KK*KK + (size_t)(k0+r)*KK + l0+tx]);
        return;
    }
    __shared__ float t[32][33];
    const float* src; u16* hi; u16* lo=0; int sq=0;
    int n0, k0, Kc, Nc;
    const size_t KK2 = (size_t)KK*KK;
    if (z < 6){
        if (blockIdx.x >= 16) return;
        n0 = blockIdx.x*32; k0 = blockIdx.y*32; Kc=KK; Nc=KK;
        if      (z==0){ src=Wq; hi=WQKVh;       lo=WQKVl; }
        else if (z==1){ src=Wk; hi=WQKVh+KK2;   lo=WQKVl+KK2; }
        else if (z==2){ src=Wv; hi=WQKVh+2*KK2; lo=WQKVl+2*KK2; }
        else if (z==3){ src=Wo; hi=WoTh; }
        else if (z==4){ src=Wq; hi=WSQKh;       lo=WSQKl; sq=1; }
        else          { src=Wk; hi=WSQKh+KK2;   lo=WSQKl+KK2; sq=1; }
    } else if (z == 6){  // W1 [512][2048] -> [2048][512]
        src=W1; hi=W1Th; Kc=KK; Nc=HIDd;
        n0 = blockIdx.x*32; k0 = blockIdx.y*32;
    } else {             // W2 [2048][512] -> [512][2048]
        src=W2; hi=W2Th; Kc=HIDd; Nc=KK;
        n0 = blockIdx.y*32; k0 = blockIdx.x*32;
    }
    const int tx=tid&31, ty=tid>>5;
    for (int r=ty;r<32;r+=8){
        float v = src[(long)(k0+r)*Nc + n0+tx];
        if (sq) v*=v;
        t[r][tx]=v;
    }
    __syncthreads();
    for (int r=ty;r<32;r+=8){
        float v = t[tx][r];
        long o = (long)(n0+r)*Kc + k0+tx;
        wsplit(hi, lo, o, v);
    }
}

// ---------------------------------------------------------------- MFMA GEMM 128x128, single product
// depth-2 / single-__syncthreads pipeline, 32 KB LDS.
// swz=1: 8x4 supertile remap — consecutive 32 blocks cover 8 M-tiles x 4 N-tiles.
__global__ __launch_bounds__(256) void gemm_mfma_k(
    const u16* __restrict__ Ah, const u16* __restrict__ Bh,
    float* __restrict__ C, u16* __restrict__ Chi, u16* __restrict__ Clo,
    int M, int Kc, int Nc, int lda,
    long sA, long sB, long sC, const float* __restrict__ bias, int act,
    int swz)
{
    __shared__ u16 shA[2][128*32], shB[2][128*32];
    int bx = blockIdx.x, by = blockIdx.y;
    if (swz){
        int lin = bx + gridDim.x*by;
        int within = lin & 31, st = lin >> 5;
        int stm = gridDim.x >> 3;
        bx = (st % stm)*8 + (within & 7);
        by = (st / stm)*4 + (within >> 3);
    }
    const int m0 = bx*128, n0 = by*128;
    const int bz = blockIdx.z;
    const u16* gAh = Ah + (long)bz*sA;
    const u16* gBh = Bh + (long)bz*sB;
    const int tid = threadIdx.x;
    const int wave = tid >> 6, lane = tid & 63;
    const int quad = lane >> 4, r16 = lane & 15;
    const int wm = (wave>>1)*64, wn = (wave&1)*64;

    f32x4 acc[4][4];
    #pragma unroll
    for (int i=0;i<4;i++)
        #pragma unroll
        for (int j=0;j<4;j++) acc[i][j] = (f32x4){0.f,0.f,0.f,0.f};

    auto stage = [&](int sel, int k0){
        #pragma unroll
        for (int half=0; half<2; ++half){
            int c = half*256 + tid;
            int row = c >> 2;
            int kg = ((c & 3) ^ ((row >> 1) & 3))*8;   // pre-swizzled global slot
            gload16(gAh + (long)(m0+row)*lda + k0 + kg, &shA[sel][c*8]);
            gload16(gBh + (long)(n0+row)*Kc  + k0 + kg, &shB[sel][c*8]);
        }
    };

    const int nsteps = Kc >> 5;
    stage(0, 0);
    __syncthreads();
    int cur = 0;
    const int swr = (quad ^ ((r16 >> 1) & 3))*8;       // undo swizzle on read
    for (int t = 0; t < nsteps; ++t){
        if (t+1 < nsteps) stage(cur^1, (t+1)<<5);
        bf16x8 afh[4], bfh[4];
        #pragma unroll
        for (int i=0;i<4;i++){
            afh[i] = *(const bf16x8*)&shA[cur][(wm+i*16+r16)*32 + swr];
            bfh[i] = *(const bf16x8*)&shB[cur][(wn+i*16+r16)*32 + swr];
        }
        #pragma unroll
        for (int i=0;i<4;i++)
            #pragma unroll
            for (int j=0;j<4;j++)
                acc[i][j] = __builtin_amdgcn_mfma_f32_16x16x32_bf16(afh[i], bfh[j], acc[i][j], 0,0,0);
        __syncthreads();
        cur ^= 1;
    }
    #pragma unroll
    for (int i=0;i<4;i++){
        #pragma unroll
        for (int j=0;j<4;j++){
            int gc = n0 + wn + j*16 + r16;
            if (gc >= Nc) continue;
            float bv = bias ? bias[gc] : 0.f;
            #pragma unroll
            for (int r=0;r<4;r++){
                long gr = m0 + wm + i*16 + quad*4 + r;
                float v = acc[i][j][r] + bv;
                if (act) v = gelu_tanh(v);
                long o = (long)bz*sC + gr*Nc + gc;
                if (C) C[o] = v;
                if (Chi){ u16 t = f2bf(v); Chi[o] = t; if (Clo) Clo[o] = f2bf(v - bf2f(t)); }
            }
        }
    }
}

// ---------------------------------------------------------------- MFMA GEMM 128x128, 3-product via VIRTUAL K
// K_virt = 3*Kc; segment 0: Ah*Bh, 1: Al*Bh, 2: Ah*Bl (pointer switch in staging).
// swzmode 1: 8x4 supertile remap (batch-1 projections).
// swzmode 2: XCD-slice pinning — lin%8 picks the XCD (HW round-robin), XCD x owns
//   slices {x, x+8, x+16, x+24}; per-XCD L2 working set = 4 slices x 1MB = 4MB (=L2).
// cskip=1 (causal): skip tiles above the diagonal AND skip stores with gc > gr
// (softmax never reads above-diagonal; it zero-fills [L, JEND) itself).
__global__ __launch_bounds__(256) void gemm_v3_k(
    const u16* __restrict__ Ah, const u16* __restrict__ Al,
    const u16* __restrict__ Bh, const u16* __restrict__ Bl,
    float* __restrict__ C,
    int M, int Kc, int Nc, int lda,
    long sA, long sB, long sC, int cskip, int swzmode)
{
    __shared__ u16 shA[2][128*32], shB[2][128*32];
    int bx = blockIdx.x, by = blockIdx.y, bz = blockIdx.z;
    if (swzmode == 1){
        int lin = bx + gridDim.x*by;
        int within = lin & 31, st = lin >> 5;
        int stm = gridDim.x >> 3;
        bx = (st % stm)*8 + (within & 7);
        by = (st / stm)*4 + (within >> 3);
    } else if (swzmode == 2){
        int lin = bx + gridDim.x*(by + gridDim.y*bz);
        int xcd = lin & 7, idx = lin >> 3;
        bz = xcd + 8*(idx >> 6);
        int tile = idx & 63;
        bx = tile & 7; by = tile >> 3;
    }
    const int m0 = bx*128, n0 = by*128;
    if (cskip == 1 && n0 > m0 + 127) return;
    const u16* gAh = Ah + (long)bz*sA;
    const u16* gAl = Al + (long)bz*sA;
    const u16* gBh = Bh + (long)bz*sB;
    const u16* gBl = Bl + (long)bz*sB;
    const int tid = threadIdx.x;
    const int wave = tid >> 6, lane = tid & 63;
    const int quad = lane >> 4, r16 = lane & 15;
    const int wm = (wave>>1)*64, wn = (wave&1)*64;

    f32x4 acc[4][4];
    #pragma unroll
    for (int i=0;i<4;i++)
        #pragma unroll
        for (int j=0;j<4;j++) acc[i][j] = (f32x4){0.f,0.f,0.f,0.f};

    const int segsteps = Kc >> 5;
    const int nsteps = 3*segsteps;
    auto stage = [&](int sel, int t){
        int seg = (t >= segsteps) + (t >= 2*segsteps);
        int k0 = (t - seg*segsteps) << 5;
        const u16* a = (seg==1) ? gAl : gAh;
        const u16* b = (seg==2) ? gBl : gBh;
        #pragma unroll
        for (int half=0; half<2; ++half){
            int c = half*256 + tid;
            int row = c >> 2;
            int kg = ((c & 3) ^ ((row >> 1) & 3))*8;
            gload16(a + (long)(m0+row)*lda + k0 + kg, &shA[sel][c*8]);
            gload16(b + (long)(n0+row)*Kc  + k0 + kg, &shB[sel][c*8]);
        }
    };

    stage(0, 0);
    __syncthreads();
    int cur = 0;
    const int swr = (quad ^ ((r16 >> 1) & 3))*8;
    for (int t = 0; t < nsteps; ++t){
        if (t+1 < nsteps) stage(cur^1, t+1);
        bf16x8 afh[4], bfh[4];
        #pragma unroll
        for (int i=0;i<4;i++){
            afh[i] = *(const bf16x8*)&shA[cur][(wm+i*16+r16)*32 + swr];
            bfh[i] = *(const bf16x8*)&shB[cur][(wn+i*16+r16)*32 + swr];
        }
        #pragma unroll
        for (int i=0;i<4;i++)
            #pragma unroll
            for (int j=0;j<4;j++)
                acc[i][j] = __builtin_amdgcn_mfma_f32_16x16x32_bf16(afh[i], bfh[j], acc[i][j], 0,0,0);
        __syncthreads();
        cur ^= 1;
    }
    #pragma unroll
    for (int i=0;i<4;i++){
        #pragma unroll
        for (int j=0;j<4;j++){
            int gc = n0 + wn + j*16 + r16;
            if (gc >= Nc) continue;
            #pragma unroll
            for (int r=0;r<4;r++){
                long gr = m0 + wm + i*16 + quad*4 + r;
                if (cskip == 1 && gc > gr) continue;   // above-diagonal: never read
                long o = (long)bz*sC + gr*Nc + gc;
                C[o] = acc[i][j][r];
            }
        }
    }
}

// ---------------------------------------------------------------- transport GEMM 64x64:
// out[r][n] = sum_g (esign*phi[r][g]) * sum_kd A[r][kd]*gen[g][n][kd]
// = virtual-K GEMM over GF[n*1536 + g*512 + kd] with per-segment register fold.
__global__ __launch_bounds__(256) void tgemm_k(
    const u16* __restrict__ Ahh,   // [M][512] bf16
    const u16* __restrict__ GFh,   // [n][g*512+kd]
    const float* __restrict__ phi, float esign,
    float* __restrict__ C, u16* __restrict__ Chi, u16* __restrict__ Clo,
    const float* __restrict__ t_x, const float* __restrict__ t_a1,
    const float* __restrict__ t_res)
{
    __shared__ u16 shA[2][64*64], shB[2][64*64];
    const int m0 = blockIdx.x*64, n0 = blockIdx.y*64;
    const int tid = threadIdx.x;
    const int wave = tid >> 6, lane = tid & 63;
    const int quad = lane >> 4, r16 = lane & 15;
    const int wr = wave*16;

    float ph[3][4];
    #pragma unroll
    for (int sgi=0; sgi<3; ++sgi)
        #pragma unroll
        for (int r=0; r<4; ++r)
            ph[sgi][r] = esign*phi[(size_t)(m0+wr+quad*4+r)*3 + sgi];

    f32x4 acc[4], tot[4];
    #pragma unroll
    for (int j=0;j<4;j++){ acc[j] = (f32x4){0.f,0.f,0.f,0.f}; tot[j] = acc[j]; }

    auto stage = [&](int sel, int t){
        int seg = t >> 3, k0 = (t & 7) << 6;
        #pragma unroll
        for (int rep=0; rep<2; ++rep){
            int c = rep*256 + tid;
            int row = c >> 3;
            int kg = ((c & 7) ^ (row & 7))*8;
            gload16(Ahh + (long)(m0+row)*KK + k0 + kg, &shA[sel][c*8]);
            gload16(GFh + (long)(n0+row)*(3*KK) + seg*KK + k0 + kg, &shB[sel][c*8]);
        }
    };

    stage(0, 0);
    __syncthreads();
    int cur = 0;
    for (int t = 0; t < 24; ++t){
        if (t+1 < 24) stage(cur^1, t+1);
        #pragma unroll
        for (int kk=0; kk<2; ++kk){
            const int s = (((kk<<2)+quad) ^ (r16 & 7))*8;
            bf16x8 af = *(const bf16x8*)&shA[cur][(wr+r16)*64 + s];
            #pragma unroll
            for (int j=0;j<4;j++){
                bf16x8 bh = *(const bf16x8*)&shB[cur][(j*16+r16)*64 + s];
                acc[j] = __builtin_amdgcn_mfma_f32_16x16x32_bf16(af, bh, acc[j], 0,0,0);
            }
        }
        if ((t & 7) == 7){
            int sgi = t >> 3;
            #pragma unroll
            for (int j=0;j<4;j++){
                #pragma unroll
                for (int r=0;r<4;r++) tot[j][r] += ph[sgi][r]*acc[j][r];
                acc[j] = (f32x4){0.f,0.f,0.f,0.f};
            }
        }
        __syncthreads();
        cur ^= 1;
    }
    #pragma unroll
    for (int j=0;j<4;j++){
        int gc = n0 + j*16 + r16;
        #pragma unroll
        for (int r=0;r<4;r++){
            long gr = m0 + wr + quad*4 + r;
            float v = tot[j][r];
            long o = gr*(long)KK + gc;
            if (t_x){
                v = t_x[o] + t_a1[o] + 0.5f*v;
                if (t_res) v += t_res[o];
            }
            if (C) C[o] = v;
            if (Chi){ u16 t2 = f2bf(v); Chi[o] = t2; if (Clo) Clo[o] = f2bf(v - bf2f(t2)); }
        }
    }
}

// ---------------------------------------------------------------- MFMA GEMM 64x64
// depth-2 / single-__syncthreads pipeline, 32KB LDS. K-step 64.
// swz=1: 8x4 supertile remap. epilogue: fused FFN update (fmode 1=mid, 2=final)
__global__ __launch_bounds__(256) void gemm64_k(
    const u16* __restrict__ Ah, const u16* __restrict__ Bh,
    float* __restrict__ C, u16* __restrict__ Chi, u16* __restrict__ Clo,
    int M, int Kc, int Nc, int lda,
    long sA, long sB, long sC, const float* __restrict__ bias, int act,
    int ktrim, int swz,
    const float* __restrict__ f_hin, const float* __restrict__ f_bmh,
    const float* __restrict__ f_mup, const float* __restrict__ f_lr,
    u16* __restrict__ f_hh, float* __restrict__ f_hout,
    const float* __restrict__ f_mrb, const float* __restrict__ f_mn2,
    float* __restrict__ f_out, int fmode)
{
    __shared__ u16 shA[2][64*64], shB[2][64*64];
    int bx = blockIdx.x, by = blockIdx.y;
    if (swz){
        int lin = bx + gridDim.x*by;
        int within = lin & 31, st = lin >> 5;
        int stm = gridDim.x >> 3;
        bx = (st % stm)*8 + (within & 7);
        by = (st / stm)*4 + (within >> 3);
    }
    const int m0 = bx*64, n0 = by*64;
    const int bz = blockIdx.z;
    const u16* gA = Ah + (long)bz*sA;
    const u16* gB = Bh + (long)bz*sB;
    const int tid = threadIdx.x;
    const int wave = tid >> 6, lane = tid & 63;
    const int quad = lane >> 4, r16 = lane & 15;
    const int wr = wave*16;
    const int kend = ktrim ? min(Kc, m0 + 64) : Kc;
    const int nsteps = kend >> 6;

    f32x4 acc[4];
    #pragma unroll
    for (int j=0;j<4;j++) acc[j] = (f32x4){0.f,0.f,0.f,0.f};

    auto stage = [&](int sel, int k0){
        #pragma unroll
        for (int rep=0; rep<2; ++rep){
            int c = rep*256 + tid;
            int row = c >> 3;
            int kg = ((c & 7) ^ (row & 7))*8;     // pre-swizzled global slot
            gload16(gA + (long)(m0+row)*lda + k0 + kg, &shA[sel][c*8]);
            gload16(gB + (long)(n0+row)*Kc + k0 + kg, &shB[sel][c*8]);
        }
    };

    stage(0, 0);
    __syncthreads();
    int cur = 0;
    for (int t = 0; t < nsteps; ++t){
        if (t+1 < nsteps) stage(cur^1, (t+1)<<6);
        #pragma unroll
        for (int kk=0; kk<2; ++kk){
            const int s = (((kk<<2)+quad) ^ (r16 & 7))*8;   // undo swizzle on read
            bf16x8 af = *(const bf16x8*)&shA[cur][(wr+r16)*64 + s];
            #pragma unroll
            for (int j=0;j<4;j++){
                bf16x8 bh = *(const bf16x8*)&shB[cur][(j*16+r16)*64 + s];
                acc[j] = __builtin_amdgcn_mfma_f32_16x16x32_bf16(af, bh, acc[j], 0,0,0);
            }
        }
        __syncthreads();
        cur ^= 1;
    }
    float lrv = 0.f;
    if (fmode) lrv = *f_lr;
    #pragma unroll
    for (int j=0;j<4;j++){
        int gc = n0 + j*16 + r16;
        float bv = bias ? bias[gc] : 0.f;
        #pragma unroll
        for (int r=0;r<4;r++){
            long gr = m0 + wr + quad*4 + r;
            float v = acc[j][r] + bv;
            if (act) v = gelu_tanh(v);
            long o = (long)bz*sC + gr*Nc + gc;
            if (fmode){
                float hv = f_hin[o];
                float val = hv + lrv*(v - (1e-3f*(hv - f_mup[o]) + (hv - f_bmh[o])));
                if (fmode == 1){ f_hout[o] = val; f_hh[o] = f2bf(val); }
                else           { f_out[o] = f_mrb[o] + val - f_mn2[o]; }
            } else {
                if (C) C[o] = v;
                if (Chi){ u16 t = f2bf(v); Chi[o] = t; if (Clo) Clo[o] = f2bf(v - bf2f(t)); }
            }
        }
    }
}

// ---------------------------------------------------------------- LayerNorm (+bf16 out, +sigma split, +output copies)
__global__ __launch_bounds__(256) void ln_k(
    const float* __restrict__ x, const float* __restrict__ g,
    const float* __restrict__ be, float* __restrict__ y,
    u16* __restrict__ yh16,
    const float* __restrict__ sg, u16* __restrict__ sgh, u16* __restrict__ sgl,
    float* __restrict__ osig, const float* __restrict__ phi, float* __restrict__ ophi)
{
    __shared__ float sh[8];
    const int r = blockIdx.x, tid = threadIdx.x;
    const float* xr = x + (long)r*KK;
    float2 v = *(const float2*)(xr + tid*2);
    float s = v.x+v.y, s2 = v.x*v.x+v.y*v.y;
    #pragma unroll
    for (int o=32;o>0;o>>=1){ s += __shfl_down(s,o); s2 += __shfl_down(s2,o); }
    if ((tid&63)==0){ sh[tid>>6]=s; sh[4+(tid>>6)]=s2; }
    __syncthreads();
    s  = sh[0]+sh[1]+sh[2]+sh[3];
    s2 = sh[4]+sh[5]+sh[6]+sh[7];
    const float mean = s*(1.f/KK);
    const float var  = s2*(1.f/KK) - mean*mean;
    const float rs = rsqrtf(var + 1e-5f);
    float2 gg = *(const float2*)(g + tid*2);
    float2 bb = *(const float2*)(be + tid*2);
    float ox = (v.x-mean)*rs*gg.x + bb.x;
    float oy = (v.y-mean)*rs*gg.y + bb.y;
    long o = (long)r*KK + tid*2;
    *(float2*)(y + o) = make_float2(ox, oy);
    if (yh16){ yh16[o] = f2bf(ox); yh16[o+1] = f2bf(oy); }
    if (sgh){
        float2 sv = *(const float2*)(sg + o);
        wsplit(sgh, sgl, o,   sv.x);
        wsplit(sgh, sgl, o+1, sv.y);
        if (osig) *(float2*)(osig + o) = sv;
    }
    if (ophi && tid < 3) ophi[(size_t)r*3 + tid] = phi[(size_t)r*3 + tid];
}

// ---------------------------------------------------------------- merged attention prep + V transpose
__global__ __launch_bounds__(512) void prepvt_k(
    const float* __restrict__ QKV, const float* __restrict__ SQSK,
    u16* __restrict__ CFh, u16* __restrict__ CFl,
    u16* __restrict__ KSh, u16* __restrict__ KSl, float* __restrict__ dvec,
    u16* __restrict__ VTh)
{
    __shared__ float t[64][65];
    const int bx = blockIdx.x;
    const int tid = threadIdx.x;
    if (bx < BN){
        const int bn = bx;
        const int b = bn / NN, n = bn % NN;
        const int h = tid >> 6, d = tid & 63;
        float q  = QKV[(size_t)bn*1536 + h*DHh + d];
        float k  = QKV[(size_t)bn*1536 + KK + h*DHh + d];
        float sq = SQSK[(size_t)bn*1024 + h*DHh + d] + 1e-8f;
        float sk = SQSK[(size_t)bn*1024 + KK + h*DHh + d] + 1e-8f;
        float inv = 1.f/sq;
        float nqi = -2.f*q*inv;
        float skk = sk + k*k;
        const size_t base = ((size_t)(h*BB + b)*NN + n)*128;
        wsplit(CFh, CFl, base+d,    inv);
        wsplit(CFh, CFl, base+64+d, nqi);
        wsplit(KSh, KSl, base+d,    skk);
        wsplit(KSh, KSl, base+64+d, k);
        float dv = __logf(sk);
        #pragma unroll
        for (int o=32;o>0;o>>=1) dv += __shfl_down(dv,o);
        if (d==0) dvec[((size_t)h*BB + b)*NN + n] = dv;
        return;
    }
    const int idx = bx - BN;
    const int n0 = (idx & 15)*64;
    const int h = (idx>>4)&7;
    const int b = idx>>7;
    const int c4 = (tid & 15) * 4;
    const int r0 = tid >> 4;     // 0..31
    for (int rr = r0; rr < 64; rr += 32){
        float4 v = *(const float4*)(QKV + (size_t)(b*NN + n0 + rr)*1536 + 1024 + h*DHh + c4);
        t[c4+0][rr] = v.x; t[c4+1][rr] = v.y; t[c4+2][rr] = v.z; t[c4+3][rr] = v.w;
    }
    __syncthreads();
    for (int dd = r0; dd < 64; dd += 32){
        size_t base = ((size_t)(h*BB + b)*64 + dd)*NN + n0 + c4;
        #pragma unroll
        for (int q=0;q<4;q++) VTh[base+q] = f2bf(t[dd][c4+q]);
    }
}

// ---------------------------------------------------------------- softmax, all 8 heads, register-resident
__global__ __launch_bounds__(256) void softmax_all_k(
    float* __restrict__ S, const float* __restrict__ dvec, u16* __restrict__ BMh)
{
    __shared__ float s_redA[2][4], s_redB[2][4];
    const int tid = threadIdx.x;
    const int b = blockIdx.x >> 10, i = blockIdx.x & (NN-1);
    const int L = i + 1;
    const int JEND = ((i >> 6) + 1) << 6;
    const int j4 = tid*4;
    const bool act = (j4 < JEND);
    const int wv = tid >> 6;
    const bool lane0 = ((tid & 63) == 0);

    float bm[4] = {0.f,0.f,0.f,0.f};
    float4 rv = make_float4(0,0,0,0), dpv = make_float4(0,0,0,0);
    if (act){
        rv  = *(const float4*)(S + ((long)(0*BB + b)*NN + i)*NN + j4);
        dpv = *(const float4*)(dvec + (size_t)(0*BB + b)*NN + j4);
    }
    for (int h = 0; h < 8; ++h){
        const int z = h*BB + b;
        float4 rvn = make_float4(0,0,0,0), dpn = make_float4(0,0,0,0);
        if (h < 7 && act){
            const int zn = (h+1)*BB + b;
            rvn = *(const float4*)(S + ((long)zn*NN + i)*NN + j4);
            dpn = *(const float4*)(dvec + (size_t)zn*NN + j4);
        }
        float sc[4];
        const float* rp = (const float*)&rv;
        const float* dp = (const float*)&dpv;
        #pragma unroll
        for (int e=0;e<4;e++){
            float s = -0.5f*rp[e] + 0.5f*dp[e];
            sc[e] = (act && (j4 + e < L)) ? s : -3.0e38f;
        }
        float lm = fmaxf(fmaxf(sc[0],sc[1]), fmaxf(sc[2],sc[3]));
        #pragma unroll
        for (int o=32;o>0;o>>=1) lm = fmaxf(lm, __shfl_xor(lm, o));
        if (lane0) s_redA[h&1][wv] = lm;
        __syncthreads();
        const float mx = fmaxf(fmaxf(s_redA[h&1][0],s_redA[h&1][1]),
                               fmaxf(s_redA[h&1][2],s_redA[h&1][3]));
        float w4[4], ps = 0.f;
        #pragma unroll
        for (int e=0;e<4;e++){
            float e1 = (act && (j4 + e < L)) ? __expf(sc[e]-mx) : 0.f;
            w4[e] = e1; ps += e1;
        }
        #pragma unroll
        for (int o=32;o>0;o>>=1) ps += __shfl_xor(ps, o);
        if (lane0) s_redB[h&1][wv] = ps;
        __syncthreads();
        const float isum = 1.f/(s_redB[h&1][0]+s_redB[h&1][1]+s_redB[h&1][2]+s_redB[h&1][3]);
        if (act){
            u16* brow = (u16*)(S + ((long)z*NN + i)*NN);
            ushort4 st;
            float w0=w4[0]*isum, w1=w4[1]*isum, w2=w4[2]*isum, w3=w4[3]*isum;
            bm[0]+=0.125f*w0; bm[1]+=0.125f*w1; bm[2]+=0.125f*w2; bm[3]+=0.125f*w3;
            st.x=f2bf(w0); st.y=f2bf(w1); st.z=f2bf(w2); st.w=f2bf(w3);
            *(ushort4*)(brow + j4) = st;
        }
        rv = rvn; dpv = dpn;
    }
    if (act){
        const long bmrow = ((long)b*NN + i)*NN;
        ushort4 st;
        st.x=f2bf(bm[0]); st.y=f2bf(bm[1]); st.z=f2bf(bm[2]); st.w=f2bf(bm[3]);
        *(ushort4*)(BMh + bmrow + j4) = st;
    }
}

// ---------------------------------------------------------------- PV, all 32 (head,batch) slices, grid (NN/64, 32)
__global__ __launch_bounds__(256) void pv_k(
    const u16* __restrict__ Sbeta,
    const u16* __restrict__ VTh,
    u16* __restrict__ xh)
{
    __shared__ u16 shA[2][64*64], shB[2][64*64];
    const int m0 = blockIdx.x*64;
    const int z = blockIdx.y;              // z = head*BB + b
    const int b = z & 3, head = z >> 2;
    const int tid = threadIdx.x;
    const int wave = tid>>6, lane = tid&63;
    const int quad = lane>>4, r16 = lane&15;
    f32x4 acc[4];
    #pragma unroll
    for (int j=0;j<4;j++) acc[j]=(f32x4){0.f,0.f,0.f,0.f};
    const int nsteps = (m0 >> 6) + 1;

    auto stage = [&](int sel, int j0){
        #pragma unroll
        for (int rep=0; rep<2; ++rep){
            int c = rep*256 + tid;
            int row = c >> 3;
            int k8 = ((c & 7) ^ (row & 7))*8;
            gload16(Sbeta + ((size_t)(z*NN + m0 + row))*(2*NN) + j0 + k8, &shA[sel][c*8]);
            gload16(VTh + ((size_t)(z*64 + row))*NN + j0 + k8, &shB[sel][c*8]);
        }
    };

    stage(0, 0);
    __syncthreads();
    int cur = 0;
    for (int t = 0; t < nsteps; ++t){
        if (t+1 < nsteps) stage(cur^1, (t+1)<<6);
        #pragma unroll
        for (int kk=0; kk<2; ++kk){
            const int s = (((kk<<2)+quad) ^ (r16 & 7))*8;
            bf16x8 af = *(const bf16x8*)&shA[cur][(wave*16 + r16)*64 + s];
            #pragma unroll
            for (int nj=0; nj<4; ++nj){
                bf16x8 bh = *(const bf16x8*)&shB[cur][(nj*16 + r16)*64 + s];
                acc[nj] = __builtin_amdgcn_mfma_f32_16x16x32_bf16(af, bh, acc[nj], 0,0,0);
            }
        }
        __syncthreads();
        cur ^= 1;
    }
    #pragma unroll
    for (int nj=0;nj<4;nj++){
        #pragma unroll
        for (int r=0;r<4;r++){
            int i = m0 + wave*16 + quad*4 + r;
            int d = nj*16 + r16;
            size_t o = ((size_t)(b*NN)+i)*KK + head*64 + d;
            xh[o] = f2bf(acc[nj][r]);
        }
    }
}

// ---------------------------------------------------------------- launch
extern "C" void kernel_launch(void* const* d_in, const int* in_sizes, int n_in,
                              void* d_out, int out_size, void* d_ws, size_t ws_size,
                              hipStream_t stream) {
    const float* mu_q    = (const float*)d_in[0];
    const float* sigma_q = (const float*)d_in[1];
    const float* phi     = (const float*)d_in[2];
    const float* gen     = (const float*)d_in[3];
    const float* mu_prior= (const float*)d_in[5];
    const float* Wq = (const float*)d_in[6];
    const float* Wk = (const float*)d_in[7];
    const float* Wv = (const float*)d_in[8];
    const float* Wo = (const float*)d_in[9];
    const float* g1 = (const float*)d_in[10];
    const float* be1= (const float*)d_in[11];
    const float* g2 = (const float*)d_in[12];
    const float* be2= (const float*)d_in[13];
    const float* W1 = (const float*)d_in[14];
    const float* bh1= (const float*)d_in[15];
    const float* W2 = (const float*)d_in[16];
    const float* bh2= (const float*)d_in[17];
    const float* lr = (const float*)d_in[18];
    float* out = (float*)d_out;

    float* w = (float*)d_ws;
    size_t off = 0;
    auto alloc = [&](size_t n){ float* p = w + off; off += (n+3)&~(size_t)3; return p; };
    auto ualloc = [&](size_t n){ return (u16*)alloc((n+1)/2); };

    // Xb..REG is one contiguous 32*NN*NN-float region reused as Sbig in phase C.
    float* Xb   = alloc((size_t)BN*KK);        // mu_n; later mn2
    float* A1b  = alloc((size_t)BN*KK);        // a1 / bmh
    float* A2b  = alloc((size_t)BN*KK);        // (spacer; part of Sbig)
    float* QKVb = alloc((size_t)BN*3*KK);      // QKV; later WOb / Hb / MRb
    float* SQSKb= alloc((size_t)BN*2*KK);
    float* REG  = alloc((size_t)16*NN*NN);     // SGh/SGl/Xh/A1h/WOh | Sbig tail | ZH
    float* Sbig = Xb;                          // 32 * NN*NN floats
    u16*  SGh   = (u16*)REG;
    u16*  SGl   = SGh + (size_t)BN*KK;
    u16*  Xh    = SGl + (size_t)BN*KK;
    u16*  A1h   = Xh  + (size_t)BN*KK;
    u16*  WOh   = A1h + (size_t)BN*KK;
    u16*  ZH    = (u16*)REG;
    float* Db_  = alloc((size_t)HH*BB*NN);
    u16* AH  = ualloc((size_t)BN*HIDd); u16* AL  = ualloc((size_t)BN*HIDd);
    u16* CFh = AH;
    u16* CFl = AH + (size_t)HH*BB*NN*128;
    u16* KSh = AL;
    u16* KSl = AL + (size_t)HH*BB*NN*128;
    u16* VTh = ualloc((size_t)HH*BB*64*NN);
    u16* GFh = ualloc((size_t)3*KK*KK);
    u16* WQKVh= ualloc((size_t)3*KK*KK); u16* WQKVl= ualloc((size_t)3*KK*KK);
    u16* WSQKh= ualloc((size_t)2*KK*KK); u16* WSQKl= ualloc((size_t)2*KK*KK);
    u16* WoTh= ualloc((size_t)KK*KK);
    u16* W1Th= ualloc((size_t)KK*HIDd);
    u16* W2Th= ualloc((size_t)KK*HIDd);
    u16* BMh = ualloc((size_t)BB*NN*NN);
    u16* HTh = ualloc((size_t)BB*KK*NN);
    float* WOb = QKVb;
    float* Hb  = QKVb + (size_t)BN*KK;
    float* MRb = QKVb + 2*(size_t)BN*KK;
    float* MN2b= Xb;
    (void)A2b;

    // ---- weight prep: one dispatch ----
    {
        dim3 gw(64, 16, 9);
        wmega_k<<<gw, 256, 0, stream>>>(Wq, Wk, Wv, Wo, W1, W2, gen,
                                        WQKVh, WQKVl, WoTh, WSQKh, WSQKl,
                                        W1Th, W2Th, GFh);
    }

    // ---- phase A: LN1 (+bf16 out, +sigma split, +output copies) + forward transport ----
    ln_k<<<BN, 256, 0, stream>>>(mu_q, g1, be1, Xb, Xh, sigma_q, SGh, SGl,
                                 out + (size_t)BN*KK, phi, out + 2*(size_t)BN*KK);
    {
        dim3 tg(BN/64, KK/64, 1);
        tgemm_k<<<tg, 256, 0, stream>>>(Xh, GFh, phi, 1.f, A1b, A1h, 0, 0, 0, 0);
        tgemm_k<<<tg, 256, 0, stream>>>(A1h, GFh, phi, 1.f, 0, AH, AL, Xb, A1b, 0);
    }

    // ---- phase B: projections (virtual-K 3-product, supertile swizzle) + attention prep ----
    {
        dim3 gq(BN/128, (3*KK)/128, 1);   // (32,12)
        gemm_v3_k<<<gq, 256, 0, stream>>>(AH, AL, WQKVh, WQKVl, QKVb,
            BN, KK, 3*KK, KK, 0, 0, 0, 0, 1);
        dim3 gs(BN/128, (2*KK)/128, 1);   // (32,8)
        gemm_v3_k<<<gs, 256, 0, stream>>>(SGh, SGl, WSQKh, WSQKl, SQSKb,
            BN, KK, 2*KK, KK, 0, 0, 0, 0, 1);
    }
    prepvt_k<<<BN + 512, 512, 0, stream>>>(QKVb, SQSKb, CFh, CFl, KSh, KSl, Db_, VTh);

    // ---- phase C: attention, all 8 heads in 3 dispatches (Sbig = Xb..REG, 134 MB) ----
    {
        dim3 sg(NN/128, NN/128, 32);
        gemm_v3_k<<<sg, 256, 0, stream>>>(CFh, CFl, KSh, KSl, Sbig,
            NN, 128, NN, 128, (long)NN*128, (long)NN*128, (long)NN*NN, 1, 2);
        softmax_all_k<<<BB*NN, 256, 0, stream>>>(Sbig, Db_, BMh);
        dim3 pg(NN/64, 32, 1);
        pv_k<<<pg, 256, 0, stream>>>((const u16*)Sbig, VTh, AH);
    }

    // ---- phase D: output proj + back transport (fused mrb) + LN2 ----
    {
        dim3 wg(BN/64, KK/64, 1);
        gemm64_k<<<wg, 256, 0, stream>>>(AH, WoTh, WOb, WOh, 0,
            BN, KK, KK, KK, 0,0,0, nullptr, 0, 0, 0,
            0,0,0,0,0,0,0,0,0,0);
        dim3 tg(BN/64, KK/64, 1);
        tgemm_k<<<tg, 256, 0, stream>>>(WOh, GFh, phi, -1.f, A1b, A1h, 0, 0, 0, 0);
        tgemm_k<<<tg, 256, 0, stream>>>(A1h, GFh, phi, -1.f, MRb, 0, 0, WOb, A1b, mu_q);
    }
    ln_k<<<BN, 256, 0, stream>>>(MRb, g2, be2, MN2b, AH, 0, 0, 0, 0, 0, 0);

    // ---- phase E: 2 VFE iterations (bmh first, then W1, then W2 with fused update) ----
    for (int it=0; it<2; ++it){
        const float* hin = (it==0) ? MN2b : Hb;
        {
            dim3 tg(KK/32, NN/32, BB);
            split_t_k<<<tg, 256, 0, stream>>>(hin, HTh, 0, NN, KK,
                                              (long)NN*KK, (long)KK*NN, 0);
        }
        {
            dim3 bg(NN/64, KK/64, BB);
            gemm64_k<<<bg, 256, 0, stream>>>(BMh, HTh, A1b, 0,0,
                                             NN, NN, KK, NN,
                                             (long)NN*NN, (long)KK*NN, (long)NN*KK,
                                             nullptr, 0, 1, 0,
                                             0,0,0,0,0,0,0,0,0,0);
        }
        {
            dim3 wg1(BN/128, HIDd/128, 1);   // (32,16), supertile swizzle
            gemm_mfma_k<<<wg1, 256, 0, stream>>>(AH, W1Th, 0, ZH, 0,
                BN, KK, HIDd, KK, 0, 0, 0, bh1, 1, 1);
        }
        {   // W2 + fused FFN update, supertile swizzle
            dim3 wg(BN/64, KK/64, 1);
            gemm64_k<<<wg, 256, 0, stream>>>(ZH, W2Th, 0,0,0,
                                             BN, HIDd, KK, HIDd, 0,0,0, bh2, 0, 0, 1,
                                             hin, A1b, mu_prior, lr, AH, Hb, MRb, MN2b, out,
                                             (it==0) ? 1 : 2);
        }
    }

    (void)in_sizes; (void)n_in; (void)out_size; (void)ws_size;
}

// Round 9
// 577.065 us; speedup vs baseline: 1.1078x; 1.0034x over previous
//
#include <hip/hip_runtime.h>
#include <math.h>

#define BB 4
#define NN 1024
#define KK 512
#define HH 8
#define DHh 64
#define HIDd 2048
#define BN (BB*NN)

typedef unsigned short u16;
typedef __attribute__((ext_vector_type(8))) short bf16x8;
typedef __attribute__((ext_vector_type(4))) float f32x4;

// ---------------------------------------------------------------- helpers
__device__ __forceinline__ float gelu_tanh(float x){
    // tanh-gelu via fast exp: 0.5x(1+tanh(u)) = x*t/(t+1), t=e^{2u}
    float u = 0.7978845608028654f*(x + 0.044715f*x*x*x);
    u = fminf(fmaxf(u, -15.f), 15.f);
    float t = __expf(2.f*u);
    return x*t/(t+1.f);
}
__device__ __forceinline__ u16 f2bf(float x){
    unsigned int u = __float_as_uint(x);
    unsigned int r = (u + 0x7fffu + ((u>>16)&1u)) >> 16;
    return (u16)r;
}
__device__ __forceinline__ float bf2f(u16 b){
    return __uint_as_float(((unsigned int)b)<<16);
}
__device__ __forceinline__ void gload16(const void* g, void* l){
    __builtin_amdgcn_global_load_lds((__attribute__((address_space(1))) void*)g,
                                     (__attribute__((address_space(3))) void*)l, 16, 0, 0);
}
__device__ __forceinline__ void wsplit(u16* hi, u16* lo, size_t o, float v){
    u16 h = f2bf(v);
    hi[o] = h;
    if (lo) lo[o] = f2bf(v - bf2f(h));
}

// ---------------------------------------------------------------- generic transpose-split (used for h^T in phase E)
__global__ __launch_bounds__(256) void split_t_k(
    const float* __restrict__ src, u16* __restrict__ hi, u16* __restrict__ lo,
    int Kc, int Nc, long sS, long sD, int square)
{
    __shared__ float t[32][33];
    const int n0 = blockIdx.x*32, k0 = blockIdx.y*32, bz = blockIdx.z;
    const float* S = src + (long)bz*sS;
    const int tx = threadIdx.x & 31, ty = threadIdx.x >> 5;
    for (int r = ty; r < 32; r += 8){
        float v = S[(long)(k0+r)*Nc + n0+tx];
        if (square) v *= v;
        t[r][tx] = v;
    }
    __syncthreads();
    for (int r = ty; r < 32; r += 8){
        float v = t[tx][r];
        long o = (long)bz*sD + (long)(n0+r)*Kc + k0 + tx;
        wsplit(hi, lo, o, v);
    }
}

// ---------------------------------------------------------------- all weight prep in one dispatch, grid (64,16,9)
__global__ __launch_bounds__(256) void wmega_k(
    const float* __restrict__ Wq, const float* __restrict__ Wk,
    const float* __restrict__ Wv, const float* __restrict__ Wo,
    const float* __restrict__ W1, const float* __restrict__ W2,
    const float* __restrict__ gen,
    u16* __restrict__ WQKVh, u16* __restrict__ WQKVl, u16* __restrict__ WoTh,
    u16* __restrict__ WSQKh, u16* __restrict__ WSQKl,
    u16* __restrict__ W1Th, u16* __restrict__ W2Th, u16* __restrict__ GFh)
{
    const int z = blockIdx.z;
    const int tid = threadIdx.x;
    if (z == 8){   // gflat: copy gen(3,K,K) -> GFh[k][g*512+l]
        if (blockIdx.x >= 48) return;
        const int c0 = blockIdx.x*32, k0 = blockIdx.y*32;
        const int tx = tid&31, ty = tid>>5;
        const int g = c0/KK, l0 = c0%KK;
        for (int r=ty; r<32; r+=8)
            GFh[(size_t)(k0+r)*(3*KK) + c0+tx] =
                f2bf(gen[(size_t)g*KK*KK + (size_t)(k0+r)*KK + l0+tx]);
        return;
    }
    __shared__ float t[32][33];
    const float* src; u16* hi; u16* lo=0; int sq=0;
    int n0, k0, Kc, Nc;
    const size_t KK2 = (size_t)KK*KK;
    if (z < 6){
        if (blockIdx.x >= 16) return;
        n0 = blockIdx.x*32; k0 = blockIdx.y*32; Kc=KK; Nc=KK;
        if      (z==0){ src=Wq; hi=WQKVh;       lo=WQKVl; }
        else if (z==1){ src=Wk; hi=WQKVh+KK2;   lo=WQKVl+KK2; }
        else if (z==2){ src=Wv; hi=WQKVh+2*KK2; lo=WQKVl+2*KK2; }
        else if (z==3){ src=Wo; hi=WoTh; }
        else if (z==4){ src=Wq; hi=WSQKh;       lo=WSQKl; sq=1; }
        else          { src=Wk; hi=WSQKh+KK2;   lo=WSQKl+KK2; sq=1; }
    } else if (z == 6){  // W1 [512][2048] -> [2048][512]
        src=W1; hi=W1Th; Kc=KK; Nc=HIDd;
        n0 = blockIdx.x*32; k0 = blockIdx.y*32;
    } else {             // W2 [2048][512] -> [512][2048]
        src=W2; hi=W2Th; Kc=HIDd; Nc=KK;
        n0 = blockIdx.y*32; k0 = blockIdx.x*32;
    }
    const int tx=tid&31, ty=tid>>5;
    for (int r=ty;r<32;r+=8){
        float v = src[(long)(k0+r)*Nc + n0+tx];
        if (sq) v*=v;
        t[r][tx]=v;
    }
    __syncthreads();
    for (int r=ty;r<32;r+=8){
        float v = t[tx][r];
        long o = (long)(n0+r)*Kc + k0+tx;
        wsplit(hi, lo, o, v);
    }
}

// ---------------------------------------------------------------- MFMA GEMM 128x128, single product
// NBUF=3 counted-vmcnt single-barrier pipeline (T4): per step
//   {vmcnt(4) retire stage(t) | s_barrier | issue stage(t+2) | ds_read+MFMA}.
// Prefetch never drained to 0; used where occupancy is GRID-limited (W1: 2 blk/CU),
// so 48KB LDS costs nothing.
// swz=1: 8x4 supertile remap — consecutive 32 blocks cover 8 M-tiles x 4 N-tiles.
__global__ __launch_bounds__(256) void gemm_mfma_k(
    const u16* __restrict__ Ah, const u16* __restrict__ Bh,
    float* __restrict__ C, u16* __restrict__ Chi, u16* __restrict__ Clo,
    int M, int Kc, int Nc, int lda,
    long sA, long sB, long sC, const float* __restrict__ bias, int act,
    int swz)
{
    __shared__ u16 shA[3][128*32], shB[3][128*32];
    int bx = blockIdx.x, by = blockIdx.y;
    if (swz){
        int lin = bx + gridDim.x*by;
        int within = lin & 31, st = lin >> 5;
        int stm = gridDim.x >> 3;
        bx = (st % stm)*8 + (within & 7);
        by = (st / stm)*4 + (within >> 3);
    }
    const int m0 = bx*128, n0 = by*128;
    const int bz = blockIdx.z;
    const u16* gAh = Ah + (long)bz*sA;
    const u16* gBh = Bh + (long)bz*sB;
    const int tid = threadIdx.x;
    const int wave = tid >> 6, lane = tid & 63;
    const int quad = lane >> 4, r16 = lane & 15;
    const int wm = (wave>>1)*64, wn = (wave&1)*64;

    f32x4 acc[4][4];
    #pragma unroll
    for (int i=0;i<4;i++)
        #pragma unroll
        for (int j=0;j<4;j++) acc[i][j] = (f32x4){0.f,0.f,0.f,0.f};

    auto stage = [&](int sel, int k0){
        #pragma unroll
        for (int half=0; half<2; ++half){
            int c = half*256 + tid;
            int row = c >> 2;
            int kg = ((c & 3) ^ ((row >> 1) & 3))*8;   // pre-swizzled global slot
            gload16(gAh + (long)(m0+row)*lda + k0 + kg, &shA[sel][c*8]);
            gload16(gBh + (long)(n0+row)*Kc  + k0 + kg, &shB[sel][c*8]);
        }
    };

    const int nsteps = Kc >> 5;
    stage(0, 0);
    if (1 < nsteps) stage(1, 1<<5);
    const int swr = (quad ^ ((r16 >> 1) & 3))*8;       // undo swizzle on read
    for (int t = 0; t < nsteps; ++t){
        if (t+1 < nsteps) asm volatile("s_waitcnt vmcnt(4)" ::: "memory");
        else              asm volatile("s_waitcnt vmcnt(0)" ::: "memory");
        __builtin_amdgcn_s_barrier();
        if (t+2 < nsteps) stage((t+2)%3, (t+2)<<5);
        const int rd = t % 3;
        bf16x8 afh[4], bfh[4];
        #pragma unroll
        for (int i=0;i<4;i++){
            afh[i] = *(const bf16x8*)&shA[rd][(wm+i*16+r16)*32 + swr];
            bfh[i] = *(const bf16x8*)&shB[rd][(wn+i*16+r16)*32 + swr];
        }
        #pragma unroll
        for (int i=0;i<4;i++)
            #pragma unroll
            for (int j=0;j<4;j++)
                acc[i][j] = __builtin_amdgcn_mfma_f32_16x16x32_bf16(afh[i], bfh[j], acc[i][j], 0,0,0);
    }
    #pragma unroll
    for (int i=0;i<4;i++){
        #pragma unroll
        for (int j=0;j<4;j++){
            int gc = n0 + wn + j*16 + r16;
            if (gc >= Nc) continue;
            float bv = bias ? bias[gc] : 0.f;
            #pragma unroll
            for (int r=0;r<4;r++){
                long gr = m0 + wm + i*16 + quad*4 + r;
                float v = acc[i][j][r] + bv;
                if (act) v = gelu_tanh(v);
                long o = (long)bz*sC + gr*Nc + gc;
                if (C) C[o] = v;
                if (Chi){ u16 t = f2bf(v); Chi[o] = t; if (Clo) Clo[o] = f2bf(v - bf2f(t)); }
            }
        }
    }
}

// ---------------------------------------------------------------- MFMA GEMM 128x128, 3-product via VIRTUAL K
// K_virt = 3*Kc; segment 0: Ah*Bh, 1: Al*Bh, 2: Ah*Bl (pointer switch in staging).
// NBUF=3: counted-vmcnt single-barrier pipeline (for grid-limited QKV/SQSK).
// NBUF=2: proven depth-2 __syncthreads path (for the 4.5-blk/CU S-GEMM — keeps
//   32KB LDS so the 5-blocks/CU cap stays; round-2 lesson).
// swzmode 1: 8x4 supertile remap. swzmode 2: XCD-slice pinning.
// cskip=1 (causal): skip above-diagonal tiles AND stores.
template<int NBUF>
__global__ __launch_bounds__(256) void gemm_v3_k(
    const u16* __restrict__ Ah, const u16* __restrict__ Al,
    const u16* __restrict__ Bh, const u16* __restrict__ Bl,
    float* __restrict__ C,
    int M, int Kc, int Nc, int lda,
    long sA, long sB, long sC, int cskip, int swzmode)
{
    __shared__ u16 shA[NBUF][128*32], shB[NBUF][128*32];
    int bx = blockIdx.x, by = blockIdx.y, bz = blockIdx.z;
    if (swzmode == 1){
        int lin = bx + gridDim.x*by;
        int within = lin & 31, st = lin >> 5;
        int stm = gridDim.x >> 3;
        bx = (st % stm)*8 + (within & 7);
        by = (st / stm)*4 + (within >> 3);
    } else if (swzmode == 2){
        int lin = bx + gridDim.x*(by + gridDim.y*bz);
        int xcd = lin & 7, idx = lin >> 3;
        bz = xcd + 8*(idx >> 6);
        int tile = idx & 63;
        bx = tile & 7; by = tile >> 3;
    }
    const int m0 = bx*128, n0 = by*128;
    if (cskip == 1 && n0 > m0 + 127) return;
    const u16* gAh = Ah + (long)bz*sA;
    const u16* gAl = Al + (long)bz*sA;
    const u16* gBh = Bh + (long)bz*sB;
    const u16* gBl = Bl + (long)bz*sB;
    const int tid = threadIdx.x;
    const int wave = tid >> 6, lane = tid & 63;
    const int quad = lane >> 4, r16 = lane & 15;
    const int wm = (wave>>1)*64, wn = (wave&1)*64;

    f32x4 acc[4][4];
    #pragma unroll
    for (int i=0;i<4;i++)
        #pragma unroll
        for (int j=0;j<4;j++) acc[i][j] = (f32x4){0.f,0.f,0.f,0.f};

    const int segsteps = Kc >> 5;
    const int nsteps = 3*segsteps;
    auto stage = [&](int sel, int t){
        int seg = (t >= segsteps) + (t >= 2*segsteps);
        int k0 = (t - seg*segsteps) << 5;
        const u16* a = (seg==1) ? gAl : gAh;
        const u16* b = (seg==2) ? gBl : gBh;
        #pragma unroll
        for (int half=0; half<2; ++half){
            int c = half*256 + tid;
            int row = c >> 2;
            int kg = ((c & 3) ^ ((row >> 1) & 3))*8;
            gload16(a + (long)(m0+row)*lda + k0 + kg, &shA[sel][c*8]);
            gload16(b + (long)(n0+row)*Kc  + k0 + kg, &shB[sel][c*8]);
        }
    };

    const int swr = (quad ^ ((r16 >> 1) & 3))*8;
    if constexpr (NBUF == 2){
        stage(0, 0);
        __syncthreads();
        int cur = 0;
        for (int t = 0; t < nsteps; ++t){
            if (t+1 < nsteps) stage(cur^1, t+1);
            bf16x8 afh[4], bfh[4];
            #pragma unroll
            for (int i=0;i<4;i++){
                afh[i] = *(const bf16x8*)&shA[cur][(wm+i*16+r16)*32 + swr];
                bfh[i] = *(const bf16x8*)&shB[cur][(wn+i*16+r16)*32 + swr];
            }
            #pragma unroll
            for (int i=0;i<4;i++)
                #pragma unroll
                for (int j=0;j<4;j++)
                    acc[i][j] = __builtin_amdgcn_mfma_f32_16x16x32_bf16(afh[i], bfh[j], acc[i][j], 0,0,0);
            __syncthreads();
            cur ^= 1;
        }
    } else {
        stage(0, 0);
        if (1 < nsteps) stage(1, 1);
        for (int t = 0; t < nsteps; ++t){
            if (t+1 < nsteps) asm volatile("s_waitcnt vmcnt(4)" ::: "memory");
            else              asm volatile("s_waitcnt vmcnt(0)" ::: "memory");
            __builtin_amdgcn_s_barrier();
            if (t+2 < nsteps) stage((t+2)%3, t+2);
            const int rd = t % 3;
            bf16x8 afh[4], bfh[4];
            #pragma unroll
            for (int i=0;i<4;i++){
                afh[i] = *(const bf16x8*)&shA[rd][(wm+i*16+r16)*32 + swr];
                bfh[i] = *(const bf16x8*)&shB[rd][(wn+i*16+r16)*32 + swr];
            }
            #pragma unroll
            for (int i=0;i<4;i++)
                #pragma unroll
                for (int j=0;j<4;j++)
                    acc[i][j] = __builtin_amdgcn_mfma_f32_16x16x32_bf16(afh[i], bfh[j], acc[i][j], 0,0,0);
        }
    }
    #pragma unroll
    for (int i=0;i<4;i++){
        #pragma unroll
        for (int j=0;j<4;j++){
            int gc = n0 + wn + j*16 + r16;
            if (gc >= Nc) continue;
            #pragma unroll
            for (int r=0;r<4;r++){
                long gr = m0 + wm + i*16 + quad*4 + r;
                if (cskip == 1 && gc > gr) continue;   // above-diagonal: never read
                long o = (long)bz*sC + gr*Nc + gc;
                C[o] = acc[i][j][r];
            }
        }
    }
}

// ---------------------------------------------------------------- transport GEMM 64x64:
// out[r][n] = sum_g (esign*phi[r][g]) * sum_kd A[r][kd]*gen[g][n][kd]
// = virtual-K GEMM over GF[n*1536 + g*512 + kd] with per-segment register fold.
__global__ __launch_bounds__(256) void tgemm_k(
    const u16* __restrict__ Ahh,   // [M][512] bf16
    const u16* __restrict__ GFh,   // [n][g*512+kd]
    const float* __restrict__ phi, float esign,
    float* __restrict__ C, u16* __restrict__ Chi, u16* __restrict__ Clo,
    const float* __restrict__ t_x, const float* __restrict__ t_a1,
    const float* __restrict__ t_res)
{
    __shared__ u16 shA[2][64*64], shB[2][64*64];
    const int m0 = blockIdx.x*64, n0 = blockIdx.y*64;
    const int tid = threadIdx.x;
    const int wave = tid >> 6, lane = tid & 63;
    const int quad = lane >> 4, r16 = lane & 15;
    const int wr = wave*16;

    float ph[3][4];
    #pragma unroll
    for (int sgi=0; sgi<3; ++sgi)
        #pragma unroll
        for (int r=0; r<4; ++r)
            ph[sgi][r] = esign*phi[(size_t)(m0+wr+quad*4+r)*3 + sgi];

    f32x4 acc[4], tot[4];
    #pragma unroll
    for (int j=0;j<4;j++){ acc[j] = (f32x4){0.f,0.f,0.f,0.f}; tot[j] = acc[j]; }

    auto stage = [&](int sel, int t){
        int seg = t >> 3, k0 = (t & 7) << 6;
        #pragma unroll
        for (int rep=0; rep<2; ++rep){
            int c = rep*256 + tid;
            int row = c >> 3;
            int kg = ((c & 7) ^ (row & 7))*8;
            gload16(Ahh + (long)(m0+row)*KK + k0 + kg, &shA[sel][c*8]);
            gload16(GFh + (long)(n0+row)*(3*KK) + seg*KK + k0 + kg, &shB[sel][c*8]);
        }
    };

    stage(0, 0);
    __syncthreads();
    int cur = 0;
    for (int t = 0; t < 24; ++t){
        if (t+1 < 24) stage(cur^1, t+1);
        #pragma unroll
        for (int kk=0; kk<2; ++kk){
            const int s = (((kk<<2)+quad) ^ (r16 & 7))*8;
            bf16x8 af = *(const bf16x8*)&shA[cur][(wr+r16)*64 + s];
            #pragma unroll
            for (int j=0;j<4;j++){
                bf16x8 bh = *(const bf16x8*)&shB[cur][(j*16+r16)*64 + s];
                acc[j] = __builtin_amdgcn_mfma_f32_16x16x32_bf16(af, bh, acc[j], 0,0,0);
            }
        }
        if ((t & 7) == 7){
            int sgi = t >> 3;
            #pragma unroll
            for (int j=0;j<4;j++){
                #pragma unroll
                for (int r=0;r<4;r++) tot[j][r] += ph[sgi][r]*acc[j][r];
                acc[j] = (f32x4){0.f,0.f,0.f,0.f};
            }
        }
        __syncthreads();
        cur ^= 1;
    }
    #pragma unroll
    for (int j=0;j<4;j++){
        int gc = n0 + j*16 + r16;
        #pragma unroll
        for (int r=0;r<4;r++){
            long gr = m0 + wr + quad*4 + r;
            float v = tot[j][r];
            long o = gr*(long)KK + gc;
            if (t_x){
                v = t_x[o] + t_a1[o] + 0.5f*v;
                if (t_res) v += t_res[o];
            }
            if (C) C[o] = v;
            if (Chi){ u16 t2 = f2bf(v); Chi[o] = t2; if (Clo) Clo[o] = f2bf(v - bf2f(t2)); }
        }
    }
}

// ---------------------------------------------------------------- MFMA GEMM 64x64
// depth-2 / single-__syncthreads pipeline, 32KB LDS. K-step 64.
// swz=1: 8x4 supertile remap. epilogue: fused FFN update (fmode 1=mid, 2=final)
__global__ __launch_bounds__(256) void gemm64_k(
    const u16* __restrict__ Ah, const u16* __restrict__ Bh,
    float* __restrict__ C, u16* __restrict__ Chi, u16* __restrict__ Clo,
    int M, int Kc, int Nc, int lda,
    long sA, long sB, long sC, const float* __restrict__ bias, int act,
    int ktrim, int swz,
    const float* __restrict__ f_hin, const float* __restrict__ f_bmh,
    const float* __restrict__ f_mup, const float* __restrict__ f_lr,
    u16* __restrict__ f_hh, float* __restrict__ f_hout,
    const float* __restrict__ f_mrb, const float* __restrict__ f_mn2,
    float* __restrict__ f_out, int fmode)
{
    __shared__ u16 shA[2][64*64], shB[2][64*64];
    int bx = blockIdx.x, by = blockIdx.y;
    if (swz){
        int lin = bx + gridDim.x*by;
        int within = lin & 31, st = lin >> 5;
        int stm = gridDim.x >> 3;
        bx = (st % stm)*8 + (within & 7);
        by = (st / stm)*4 + (within >> 3);
    }
    const int m0 = bx*64, n0 = by*64;
    const int bz = blockIdx.z;
    const u16* gA = Ah + (long)bz*sA;
    const u16* gB = Bh + (long)bz*sB;
    const int tid = threadIdx.x;
    const int wave = tid >> 6, lane = tid & 63;
    const int quad = lane >> 4, r16 = lane & 15;
    const int wr = wave*16;
    const int kend = ktrim ? min(Kc, m0 + 64) : Kc;
    const int nsteps = kend >> 6;

    f32x4 acc[4];
    #pragma unroll
    for (int j=0;j<4;j++) acc[j] = (f32x4){0.f,0.f,0.f,0.f};

    auto stage = [&](int sel, int k0){
        #pragma unroll
        for (int rep=0; rep<2; ++rep){
            int c = rep*256 + tid;
            int row = c >> 3;
            int kg = ((c & 7) ^ (row & 7))*8;     // pre-swizzled global slot
            gload16(gA + (long)(m0+row)*lda + k0 + kg, &shA[sel][c*8]);
            gload16(gB + (long)(n0+row)*Kc + k0 + kg, &shB[sel][c*8]);
        }
    };

    stage(0, 0);
    __syncthreads();
    int cur = 0;
    for (int t = 0; t < nsteps; ++t){
        if (t+1 < nsteps) stage(cur^1, (t+1)<<6);
        #pragma unroll
        for (int kk=0; kk<2; ++kk){
            const int s = (((kk<<2)+quad) ^ (r16 & 7))*8;   // undo swizzle on read
            bf16x8 af = *(const bf16x8*)&shA[cur][(wr+r16)*64 + s];
            #pragma unroll
            for (int j=0;j<4;j++){
                bf16x8 bh = *(const bf16x8*)&shB[cur][(j*16+r16)*64 + s];
                acc[j] = __builtin_amdgcn_mfma_f32_16x16x32_bf16(af, bh, acc[j], 0,0,0);
            }
        }
        __syncthreads();
        cur ^= 1;
    }
    float lrv = 0.f;
    if (fmode) lrv = *f_lr;
    #pragma unroll
    for (int j=0;j<4;j++){
        int gc = n0 + j*16 + r16;
        float bv = bias ? bias[gc] : 0.f;
        #pragma unroll
        for (int r=0;r<4;r++){
            long gr = m0 + wr + quad*4 + r;
            float v = acc[j][r] + bv;
            if (act) v = gelu_tanh(v);
            long o = (long)bz*sC + gr*Nc + gc;
            if (fmode){
                float hv = f_hin[o];
                float val = hv + lrv*(v - (1e-3f*(hv - f_mup[o]) + (hv - f_bmh[o])));
                if (fmode == 1){ f_hout[o] = val; f_hh[o] = f2bf(val); }
                else           { f_out[o] = f_mrb[o] + val - f_mn2[o]; }
            } else {
                if (C) C[o] = v;
                if (Chi){ u16 t = f2bf(v); Chi[o] = t; if (Clo) Clo[o] = f2bf(v - bf2f(t)); }
            }
        }
    }
}

// ---------------------------------------------------------------- LayerNorm (+bf16 out, +sigma split, +output copies)
__global__ __launch_bounds__(256) void ln_k(
    const float* __restrict__ x, const float* __restrict__ g,
    const float* __restrict__ be, float* __restrict__ y,
    u16* __restrict__ yh16,
    const float* __restrict__ sg, u16* __restrict__ sgh, u16* __restrict__ sgl,
    float* __restrict__ osig, const float* __restrict__ phi, float* __restrict__ ophi)
{
    __shared__ float sh[8];
    const int r = blockIdx.x, tid = threadIdx.x;
    const float* xr = x + (long)r*KK;
    float2 v = *(const float2*)(xr + tid*2);
    float s = v.x+v.y, s2 = v.x*v.x+v.y*v.y;
    #pragma unroll
    for (int o=32;o>0;o>>=1){ s += __shfl_down(s,o); s2 += __shfl_down(s2,o); }
    if ((tid&63)==0){ sh[tid>>6]=s; sh[4+(tid>>6)]=s2; }
    __syncthreads();
    s  = sh[0]+sh[1]+sh[2]+sh[3];
    s2 = sh[4]+sh[5]+sh[6]+sh[7];
    const float mean = s*(1.f/KK);
    const float var  = s2*(1.f/KK) - mean*mean;
    const float rs = rsqrtf(var + 1e-5f);
    float2 gg = *(const float2*)(g + tid*2);
    float2 bb = *(const float2*)(be + tid*2);
    float ox = (v.x-mean)*rs*gg.x + bb.x;
    float oy = (v.y-mean)*rs*gg.y + bb.y;
    long o = (long)r*KK + tid*2;
    *(float2*)(y + o) = make_float2(ox, oy);
    if (yh16){ yh16[o] = f2bf(ox); yh16[o+1] = f2bf(oy); }
    if (sgh){
        float2 sv = *(const float2*)(sg + o);
        wsplit(sgh, sgl, o,   sv.x);
        wsplit(sgh, sgl, o+1, sv.y);
        if (osig) *(float2*)(osig + o) = sv;
    }
    if (ophi && tid < 3) ophi[(size_t)r*3 + tid] = phi[(size_t)r*3 + tid];
}

// ---------------------------------------------------------------- merged attention prep + V transpose
__global__ __launch_bounds__(512) void prepvt_k(
    const float* __restrict__ QKV, const float* __restrict__ SQSK,
    u16* __restrict__ CFh, u16* __restrict__ CFl,
    u16* __restrict__ KSh, u16* __restrict__ KSl, float* __restrict__ dvec,
    u16* __restrict__ VTh)
{
    __shared__ float t[64][65];
    const int bx = blockIdx.x;
    const int tid = threadIdx.x;
    if (bx < BN){
        const int bn = bx;
        const int b = bn / NN, n = bn % NN;
        const int h = tid >> 6, d = tid & 63;
        float q  = QKV[(size_t)bn*1536 + h*DHh + d];
        float k  = QKV[(size_t)bn*1536 + KK + h*DHh + d];
        float sq = SQSK[(size_t)bn*1024 + h*DHh + d] + 1e-8f;
        float sk = SQSK[(size_t)bn*1024 + KK + h*DHh + d] + 1e-8f;
        float inv = 1.f/sq;
        float nqi = -2.f*q*inv;
        float skk = sk + k*k;
        const size_t base = ((size_t)(h*BB + b)*NN + n)*128;
        wsplit(CFh, CFl, base+d,    inv);
        wsplit(CFh, CFl, base+64+d, nqi);
        wsplit(KSh, KSl, base+d,    skk);
        wsplit(KSh, KSl, base+64+d, k);
        float dv = __logf(sk);
        #pragma unroll
        for (int o=32;o>0;o>>=1) dv += __shfl_down(dv,o);
        if (d==0) dvec[((size_t)h*BB + b)*NN + n] = dv;
        return;
    }
    const int idx = bx - BN;
    const int n0 = (idx & 15)*64;
    const int h = (idx>>4)&7;
    const int b = idx>>7;
    const int c4 = (tid & 15) * 4;
    const int r0 = tid >> 4;     // 0..31
    for (int rr = r0; rr < 64; rr += 32){
        float4 v = *(const float4*)(QKV + (size_t)(b*NN + n0 + rr)*1536 + 1024 + h*DHh + c4);
        t[c4+0][rr] = v.x; t[c4+1][rr] = v.y; t[c4+2][rr] = v.z; t[c4+3][rr] = v.w;
    }
    __syncthreads();
    for (int dd = r0; dd < 64; dd += 32){
        size_t base = ((size_t)(h*BB + b)*64 + dd)*NN + n0 + c4;
        #pragma unroll
        for (int q=0;q<4;q++) VTh[base+q] = f2bf(t[dd][c4+q]);
    }
}

// ---------------------------------------------------------------- softmax, all 8 heads, register-resident
__global__ __launch_bounds__(256) void softmax_all_k(
    float* __restrict__ S, const float* __restrict__ dvec, u16* __restrict__ BMh)
{
    __shared__ float s_redA[2][4], s_redB[2][4];
    const int tid = threadIdx.x;
    const int b = blockIdx.x >> 10, i = blockIdx.x & (NN-1);
    const int L = i + 1;
    const int JEND = ((i >> 6) + 1) << 6;
    const int j4 = tid*4;
    const bool act = (j4 < JEND);
    const int wv = tid >> 6;
    const bool lane0 = ((tid & 63) == 0);

    float bm[4] = {0.f,0.f,0.f,0.f};
    float4 rv = make_float4(0,0,0,0), dpv = make_float4(0,0,0,0);
    if (act){
        rv  = *(const float4*)(S + ((long)(0*BB + b)*NN + i)*NN + j4);
        dpv = *(const float4*)(dvec + (size_t)(0*BB + b)*NN + j4);
    }
    for (int h = 0; h < 8; ++h){
        const int z = h*BB + b;
        float4 rvn = make_float4(0,0,0,0), dpn = make_float4(0,0,0,0);
        if (h < 7 && act){
            const int zn = (h+1)*BB + b;
            rvn = *(const float4*)(S + ((long)zn*NN + i)*NN + j4);
            dpn = *(const float4*)(dvec + (size_t)zn*NN + j4);
        }
        float sc[4];
        const float* rp = (const float*)&rv;
        const float* dp = (const float*)&dpv;
        #pragma unroll
        for (int e=0;e<4;e++){
            float s = -0.5f*rp[e] + 0.5f*dp[e];
            sc[e] = (act && (j4 + e < L)) ? s : -3.0e38f;
        }
        float lm = fmaxf(fmaxf(sc[0],sc[1]), fmaxf(sc[2],sc[3]));
        #pragma unroll
        for (int o=32;o>0;o>>=1) lm = fmaxf(lm, __shfl_xor(lm, o));
        if (lane0) s_redA[h&1][wv] = lm;
        __syncthreads();
        const float mx = fmaxf(fmaxf(s_redA[h&1][0],s_redA[h&1][1]),
                               fmaxf(s_redA[h&1][2],s_redA[h&1][3]));
        float w4[4], ps = 0.f;
        #pragma unroll
        for (int e=0;e<4;e++){
            float e1 = (act && (j4 + e < L)) ? __expf(sc[e]-mx) : 0.f;
            w4[e] = e1; ps += e1;
        }
        #pragma unroll
        for (int o=32;o>0;o>>=1) ps += __shfl_xor(ps, o);
        if (lane0) s_redB[h&1][wv] = ps;
        __syncthreads();
        const float isum = 1.f/(s_redB[h&1][0]+s_redB[h&1][1]+s_redB[h&1][2]+s_redB[h&1][3]);
        if (act){
            u16* brow = (u16*)(S + ((long)z*NN + i)*NN);
            ushort4 st;
            float w0=w4[0]*isum, w1=w4[1]*isum, w2=w4[2]*isum, w3=w4[3]*isum;
            bm[0]+=0.125f*w0; bm[1]+=0.125f*w1; bm[2]+=0.125f*w2; bm[3]+=0.125f*w3;
            st.x=f2bf(w0); st.y=f2bf(w1); st.z=f2bf(w2); st.w=f2bf(w3);
            *(ushort4*)(brow + j4) = st;
        }
        rv = rvn; dpv = dpn;
    }
    if (act){
        const long bmrow = ((long)b*NN + i)*NN;
        ushort4 st;
        st.x=f2bf(bm[0]); st.y=f2bf(bm[1]); st.z=f2bf(bm[2]); st.w=f2bf(bm[3]);
        *(ushort4*)(BMh + bmrow + j4) = st;
    }
}

// ---------------------------------------------------------------- PV, all 32 (head,batch) slices, grid (NN/64, 32)
__global__ __launch_bounds__(256) void pv_k(
    const u16* __restrict__ Sbeta,
    const u16* __restrict__ VTh,
    u16* __restrict__ xh)
{
    __shared__ u16 shA[2][64*64], shB[2][64*64];
    const int m0 = blockIdx.x*64;
    const int z = blockIdx.y;              // z = head*BB + b
    const int b = z & 3, head = z >> 2;
    const int tid = threadIdx.x;
    const int wave = tid>>6, lane = tid&63;
    const int quad = lane>>4, r16 = lane&15;
    f32x4 acc[4];
    #pragma unroll
    for (int j=0;j<4;j++) acc[j]=(f32x4){0.f,0.f,0.f,0.f};
    const int nsteps = (m0 >> 6) + 1;

    auto stage = [&](int sel, int j0){
        #pragma unroll
        for (int rep=0; rep<2; ++rep){
            int c = rep*256 + tid;
            int row = c >> 3;
            int k8 = ((c & 7) ^ (row & 7))*8;
            gload16(Sbeta + ((size_t)(z*NN + m0 + row))*(2*NN) + j0 + k8, &shA[sel][c*8]);
            gload16(VTh + ((size_t)(z*64 + row))*NN + j0 + k8, &shB[sel][c*8]);
        }
    };

    stage(0, 0);
    __syncthreads();
    int cur = 0;
    for (int t = 0; t < nsteps; ++t){
        if (t+1 < nsteps) stage(cur^1, (t+1)<<6);
        #pragma unroll
        for (int kk=0; kk<2; ++kk){
            const int s = (((kk<<2)+quad) ^ (r16 & 7))*8;
            bf16x8 af = *(const bf16x8*)&shA[cur][(wave*16 + r16)*64 + s];
            #pragma unroll
            for (int nj=0; nj<4; ++nj){
                bf16x8 bh = *(const bf16x8*)&shB[cur][(nj*16 + r16)*64 + s];
                acc[nj] = __builtin_amdgcn_mfma_f32_16x16x32_bf16(af, bh, acc[nj], 0,0,0);
            }
        }
        __syncthreads();
        cur ^= 1;
    }
    #pragma unroll
    for (int nj=0;nj<4;nj++){
        #pragma unroll
        for (int r=0;r<4;r++){
            int i = m0 + wave*16 + quad*4 + r;
            int d = nj*16 + r16;
            size_t o = ((size_t)(b*NN)+i)*KK + head*64 + d;
            xh[o] = f2bf(acc[nj][r]);
        }
    }
}

// ---------------------------------------------------------------- launch
extern "C" void kernel_launch(void* const* d_in, const int* in_sizes, int n_in,
                              void* d_out, int out_size, void* d_ws, size_t ws_size,
                              hipStream_t stream) {
    const float* mu_q    = (const float*)d_in[0];
    const float* sigma_q = (const float*)d_in[1];
    const float* phi     = (const float*)d_in[2];
    const float* gen     = (const float*)d_in[3];
    const float* mu_prior= (const float*)d_in[5];
    const float* Wq = (const float*)d_in[6];
    const float* Wk = (const float*)d_in[7];
    const float* Wv = (const float*)d_in[8];
    const float* Wo = (const float*)d_in[9];
    const float* g1 = (const float*)d_in[10];
    const float* be1= (const float*)d_in[11];
    const float* g2 = (const float*)d_in[12];
    const float* be2= (const float*)d_in[13];
    const float* W1 = (const float*)d_in[14];
    const float* bh1= (const float*)d_in[15];
    const float* W2 = (const float*)d_in[16];
    const float* bh2= (const float*)d_in[17];
    const float* lr = (const float*)d_in[18];
    float* out = (float*)d_out;

    float* w = (float*)d_ws;
    size_t off = 0;
    auto alloc = [&](size_t n){ float* p = w + off; off += (n+3)&~(size_t)3; return p; };
    auto ualloc = [&](size_t n){ return (u16*)alloc((n+1)/2); };

    // Xb..REG is one contiguous 32*NN*NN-float region reused as Sbig in phase C.
    float* Xb   = alloc((size_t)BN*KK);        // mu_n; later mn2
    float* A1b  = alloc((size_t)BN*KK);        // a1 / bmh
    float* A2b  = alloc((size_t)BN*KK);        // (spacer; part of Sbig)
    float* QKVb = alloc((size_t)BN*3*KK);      // QKV; later WOb / Hb / MRb
    float* SQSKb= alloc((size_t)BN*2*KK);
    float* REG  = alloc((size_t)16*NN*NN);     // SGh/SGl/Xh/A1h/WOh | Sbig tail | ZH
    float* Sbig = Xb;                          // 32 * NN*NN floats
    u16*  SGh   = (u16*)REG;
    u16*  SGl   = SGh + (size_t)BN*KK;
    u16*  Xh    = SGl + (size_t)BN*KK;
    u16*  A1h   = Xh  + (size_t)BN*KK;
    u16*  WOh   = A1h + (size_t)BN*KK;
    u16*  ZH    = (u16*)REG;
    float* Db_  = alloc((size_t)HH*BB*NN);
    u16* AH  = ualloc((size_t)BN*HIDd); u16* AL  = ualloc((size_t)BN*HIDd);
    u16* CFh = AH;
    u16* CFl = AH + (size_t)HH*BB*NN*128;
    u16* KSh = AL;
    u16* KSl = AL + (size_t)HH*BB*NN*128;
    u16* VTh = ualloc((size_t)HH*BB*64*NN);
    u16* GFh = ualloc((size_t)3*KK*KK);
    u16* WQKVh= ualloc((size_t)3*KK*KK); u16* WQKVl= ualloc((size_t)3*KK*KK);
    u16* WSQKh= ualloc((size_t)2*KK*KK); u16* WSQKl= ualloc((size_t)2*KK*KK);
    u16* WoTh= ualloc((size_t)KK*KK);
    u16* W1Th= ualloc((size_t)KK*HIDd);
    u16* W2Th= ualloc((size_t)KK*HIDd);
    u16* BMh = ualloc((size_t)BB*NN*NN);
    u16* HTh = ualloc((size_t)BB*KK*NN);
    float* WOb = QKVb;
    float* Hb  = QKVb + (size_t)BN*KK;
    float* MRb = QKVb + 2*(size_t)BN*KK;
    float* MN2b= Xb;
    (void)A2b;

    // ---- weight prep: one dispatch ----
    {
        dim3 gw(64, 16, 9);
        wmega_k<<<gw, 256, 0, stream>>>(Wq, Wk, Wv, Wo, W1, W2, gen,
                                        WQKVh, WQKVl, WoTh, WSQKh, WSQKl,
                                        W1Th, W2Th, GFh);
    }

    // ---- phase A: LN1 (+bf16 out, +sigma split, +output copies) + forward transport ----
    ln_k<<<BN, 256, 0, stream>>>(mu_q, g1, be1, Xb, Xh, sigma_q, SGh, SGl,
                                 out + (size_t)BN*KK, phi, out + 2*(size_t)BN*KK);
    {
        dim3 tg(BN/64, KK/64, 1);
        tgemm_k<<<tg, 256, 0, stream>>>(Xh, GFh, phi, 1.f, A1b, A1h, 0, 0, 0, 0);
        tgemm_k<<<tg, 256, 0, stream>>>(A1h, GFh, phi, 1.f, 0, AH, AL, Xb, A1b, 0);
    }

    // ---- phase B: projections (virtual-K 3-product, counted pipeline) + attention prep ----
    {
        dim3 gq(BN/128, (3*KK)/128, 1);   // (32,12)
        gemm_v3_k<3><<<gq, 256, 0, stream>>>(AH, AL, WQKVh, WQKVl, QKVb,
            BN, KK, 3*KK, KK, 0, 0, 0, 0, 1);
        dim3 gs(BN/128, (2*KK)/128, 1);   // (32,8)
        gemm_v3_k<3><<<gs, 256, 0, stream>>>(SGh, SGl, WSQKh, WSQKl, SQSKb,
            BN, KK, 2*KK, KK, 0, 0, 0, 0, 1);
    }
    prepvt_k<<<BN + 512, 512, 0, stream>>>(QKVb, SQSKb, CFh, CFl, KSh, KSl, Db_, VTh);

    // ---- phase C: attention, all 8 heads in 3 dispatches (Sbig = Xb..REG, 134 MB) ----
    {
        dim3 sg(NN/128, NN/128, 32);
        gemm_v3_k<2><<<sg, 256, 0, stream>>>(CFh, CFl, KSh, KSl, Sbig,
            NN, 128, NN, 128, (long)NN*128, (long)NN*128, (long)NN*NN, 1, 2);
        softmax_all_k<<<BB*NN, 256, 0, stream>>>(Sbig, Db_, BMh);
        dim3 pg(NN/64, 32, 1);
        pv_k<<<pg, 256, 0, stream>>>((const u16*)Sbig, VTh, AH);
    }

    // ---- phase D: output proj + back transport (fused mrb) + LN2 ----
    {
        dim3 wg(BN/64, KK/64, 1);
        gemm64_k<<<wg, 256, 0, stream>>>(AH, WoTh, WOb, WOh, 0,
            BN, KK, KK, KK, 0,0,0, nullptr, 0, 0, 0,
            0,0,0,0,0,0,0,0,0,0);
        dim3 tg(BN/64, KK/64, 1);
        tgemm_k<<<tg, 256, 0, stream>>>(WOh, GFh, phi, -1.f, A1b, A1h, 0, 0, 0, 0);
        tgemm_k<<<tg, 256, 0, stream>>>(A1h, GFh, phi, -1.f, MRb, 0, 0, WOb, A1b, mu_q);
    }
    ln_k<<<BN, 256, 0, stream>>>(MRb, g2, be2, MN2b, AH, 0, 0, 0, 0, 0, 0);

    // ---- phase E: 2 VFE iterations (bmh first, then W1, then W2 with fused update) ----
    for (int it=0; it<2; ++it){
        const float* hin = (it==0) ? MN2b : Hb;
        {
            dim3 tg(KK/32, NN/32, BB);
            split_t_k<<<tg, 256, 0, stream>>>(hin, HTh, 0, NN, KK,
                                              (long)NN*KK, (long)KK*NN, 0);
        }
        {
            dim3 bg(NN/64, KK/64, BB);
            gemm64_k<<<bg, 256, 0, stream>>>(BMh, HTh, A1b, 0,0,
                                             NN, NN, KK, NN,
                                             (long)NN*NN, (long)KK*NN, (long)NN*KK,
                                             nullptr, 0, 1, 0,
                                             0,0,0,0,0,0,0,0,0,0);
        }
        {
            dim3 wg1(BN/128, HIDd/128, 1);   // (32,16), supertile swizzle
            gemm_mfma_k<<<wg1, 256, 0, stream>>>(AH, W1Th, 0, ZH, 0,
                BN, KK, HIDd, KK, 0, 0, 0, bh1, 1, 1);
        }
        {   // W2 + fused FFN update, supertile swizzle
            dim3 wg(BN/64, KK/64, 1);
            gemm64_k<<<wg, 256, 0, stream>>>(ZH, W2Th, 0,0,0,
                                             BN, HIDd, KK, HIDd, 0,0,0, bh2, 0, 0, 1,
                                             hin, A1b, mu_prior, lr, AH, Hb, MRb, MN2b, out,
                                             (it==0) ? 1 : 2);
        }
    }

    (void)in_sizes; (void)n_in; (void)out_size; (void)ws_size;
}

// Round 10
// 554.493 us; speedup vs baseline: 1.1529x; 1.0407x over previous
//
#include <hip/hip_runtime.h>
#include <math.h>

#define BB 4
#define NN 1024
#define KK 512
#define HH 8
#define DHh 64
#define HIDd 2048
#define BN (BB*NN)

typedef unsigned short u16;
typedef __attribute__((ext_vector_type(8))) short bf16x8;
typedef __attribute__((ext_vector_type(4))) float f32x4;

// ---------------------------------------------------------------- helpers
__device__ __forceinline__ float gelu_tanh(float x){
    // tanh-gelu via fast exp: 0.5x(1+tanh(u)) = x*t/(t+1), t=e^{2u}
    float u = 0.7978845608028654f*(x + 0.044715f*x*x*x);
    u = fminf(fmaxf(u, -15.f), 15.f);
    float t = __expf(2.f*u);
    return x*t/(t+1.f);
}
__device__ __forceinline__ u16 f2bf(float x){
    unsigned int u = __float_as_uint(x);
    unsigned int r = (u + 0x7fffu + ((u>>16)&1u)) >> 16;
    return (u16)r;
}
__device__ __forceinline__ float bf2f(u16 b){
    return __uint_as_float(((unsigned int)b)<<16);
}
__device__ __forceinline__ void gload16(const void* g, void* l){
    __builtin_amdgcn_global_load_lds((__attribute__((address_space(1))) void*)g,
                                     (__attribute__((address_space(3))) void*)l, 16, 0, 0);
}
__device__ __forceinline__ void wsplit(u16* hi, u16* lo, size_t o, float v){
    u16 h = f2bf(v);
    hi[o] = h;
    if (lo) lo[o] = f2bf(v - bf2f(h));
}

// ---------------------------------------------------------------- generic transpose-split (used for h^T in phase E)
__global__ __launch_bounds__(256) void split_t_k(
    const float* __restrict__ src, u16* __restrict__ hi, u16* __restrict__ lo,
    int Kc, int Nc, long sS, long sD, int square)
{
    __shared__ float t[32][33];
    const int n0 = blockIdx.x*32, k0 = blockIdx.y*32, bz = blockIdx.z;
    const float* S = src + (long)bz*sS;
    const int tx = threadIdx.x & 31, ty = threadIdx.x >> 5;
    for (int r = ty; r < 32; r += 8){
        float v = S[(long)(k0+r)*Nc + n0+tx];
        if (square) v *= v;
        t[r][tx] = v;
    }
    __syncthreads();
    for (int r = ty; r < 32; r += 8){
        float v = t[tx][r];
        long o = (long)bz*sD + (long)(n0+r)*Kc + k0 + tx;
        wsplit(hi, lo, o, v);
    }
}

// ---------------------------------------------------------------- all weight prep in one dispatch, grid (64,16,9)
__global__ __launch_bounds__(256) void wmega_k(
    const float* __restrict__ Wq, const float* __restrict__ Wk,
    const float* __restrict__ Wv, const float* __restrict__ Wo,
    const float* __restrict__ W1, const float* __restrict__ W2,
    const float* __restrict__ gen,
    u16* __restrict__ WQKVh, u16* __restrict__ WQKVl, u16* __restrict__ WoTh,
    u16* __restrict__ WSQKh, u16* __restrict__ WSQKl,
    u16* __restrict__ W1Th, u16* __restrict__ W2Th, u16* __restrict__ GFh)
{
    const int z = blockIdx.z;
    const int tid = threadIdx.x;
    if (z == 8){   // gflat: copy gen(3,K,K) -> GFh[k][g*512+l]
        if (blockIdx.x >= 48) return;
        const int c0 = blockIdx.x*32, k0 = blockIdx.y*32;
        const int tx = tid&31, ty = tid>>5;
        const int g = c0/KK, l0 = c0%KK;
        for (int r=ty; r<32; r+=8)
            GFh[(size_t)(k0+r)*(3*KK) + c0+tx] =
                f2bf(gen[(size_t)g*KK*KK + (size_t)(k0+r)*KK + l0+tx]);
        return;
    }
    __shared__ float t[32][33];
    const float* src; u16* hi; u16* lo=0; int sq=0;
    int n0, k0, Kc, Nc;
    const size_t KK2 = (size_t)KK*KK;
    if (z < 6){
        if (blockIdx.x >= 16) return;
        n0 = blockIdx.x*32; k0 = blockIdx.y*32; Kc=KK; Nc=KK;
        if      (z==0){ src=Wq; hi=WQKVh;       lo=WQKVl; }
        else if (z==1){ src=Wk; hi=WQKVh+KK2;   lo=WQKVl+KK2; }
        else if (z==2){ src=Wv; hi=WQKVh+2*KK2; lo=WQKVl+2*KK2; }
        else if (z==3){ src=Wo; hi=WoTh; }
        else if (z==4){ src=Wq; hi=WSQKh;       lo=WSQKl; sq=1; }
        else          { src=Wk; hi=WSQKh+KK2;   lo=WSQKl+KK2; sq=1; }
    } else if (z == 6){  // W1 [512][2048] -> [2048][512]
        src=W1; hi=W1Th; Kc=KK; Nc=HIDd;
        n0 = blockIdx.x*32; k0 = blockIdx.y*32;
    } else {             // W2 [2048][512] -> [512][2048]
        src=W2; hi=W2Th; Kc=HIDd; Nc=KK;
        n0 = blockIdx.y*32; k0 = blockIdx.x*32;
    }
    const int tx=tid&31, ty=tid>>5;
    for (int r=ty;r<32;r+=8){
        float v = src[(long)(k0+r)*Nc + n0+tx];
        if (sq) v*=v;
        t[r][tx]=v;
    }
    __syncthreads();
    for (int r=ty;r<32;r+=8){
        float v = t[tx][r];
        long o = (long)(n0+r)*Kc + k0+tx;
        wsplit(hi, lo, o, v);
    }
}

// ---------------------------------------------------------------- MFMA GEMM 128x128, single product
// NBUF=3 counted-vmcnt single-barrier pipeline.
// swz=1: 8x4 supertile remap — consecutive 32 blocks cover 8 M-tiles x 4 N-tiles.
__global__ __launch_bounds__(256) void gemm_mfma_k(
    const u16* __restrict__ Ah, const u16* __restrict__ Bh,
    float* __restrict__ C, u16* __restrict__ Chi, u16* __restrict__ Clo,
    int M, int Kc, int Nc, int lda,
    long sA, long sB, long sC, const float* __restrict__ bias, int act,
    int swz)
{
    __shared__ u16 shA[3][128*32], shB[3][128*32];
    int bx = blockIdx.x, by = blockIdx.y;
    if (swz){
        int lin = bx + gridDim.x*by;
        int within = lin & 31, st = lin >> 5;
        int stm = gridDim.x >> 3;
        bx = (st % stm)*8 + (within & 7);
        by = (st / stm)*4 + (within >> 3);
    }
    const int m0 = bx*128, n0 = by*128;
    const int bz = blockIdx.z;
    const u16* gAh = Ah + (long)bz*sA;
    const u16* gBh = Bh + (long)bz*sB;
    const int tid = threadIdx.x;
    const int wave = tid >> 6, lane = tid & 63;
    const int quad = lane >> 4, r16 = lane & 15;
    const int wm = (wave>>1)*64, wn = (wave&1)*64;

    f32x4 acc[4][4];
    #pragma unroll
    for (int i=0;i<4;i++)
        #pragma unroll
        for (int j=0;j<4;j++) acc[i][j] = (f32x4){0.f,0.f,0.f,0.f};

    auto stage = [&](int sel, int k0){
        #pragma unroll
        for (int half=0; half<2; ++half){
            int c = half*256 + tid;
            int row = c >> 2;
            int kg = ((c & 3) ^ ((row >> 1) & 3))*8;   // pre-swizzled global slot
            gload16(gAh + (long)(m0+row)*lda + k0 + kg, &shA[sel][c*8]);
            gload16(gBh + (long)(n0+row)*Kc  + k0 + kg, &shB[sel][c*8]);
        }
    };

    const int nsteps = Kc >> 5;
    stage(0, 0);
    if (1 < nsteps) stage(1, 1<<5);
    const int swr = (quad ^ ((r16 >> 1) & 3))*8;       // undo swizzle on read
    for (int t = 0; t < nsteps; ++t){
        if (t+1 < nsteps) asm volatile("s_waitcnt vmcnt(4)" ::: "memory");
        else              asm volatile("s_waitcnt vmcnt(0)" ::: "memory");
        __builtin_amdgcn_s_barrier();
        if (t+2 < nsteps) stage((t+2)%3, (t+2)<<5);
        const int rd = t % 3;
        bf16x8 afh[4], bfh[4];
        #pragma unroll
        for (int i=0;i<4;i++){
            afh[i] = *(const bf16x8*)&shA[rd][(wm+i*16+r16)*32 + swr];
            bfh[i] = *(const bf16x8*)&shB[rd][(wn+i*16+r16)*32 + swr];
        }
        #pragma unroll
        for (int i=0;i<4;i++)
            #pragma unroll
            for (int j=0;j<4;j++)
                acc[i][j] = __builtin_amdgcn_mfma_f32_16x16x32_bf16(afh[i], bfh[j], acc[i][j], 0,0,0);
    }
    #pragma unroll
    for (int i=0;i<4;i++){
        #pragma unroll
        for (int j=0;j<4;j++){
            int gc = n0 + wn + j*16 + r16;
            if (gc >= Nc) continue;
            float bv = bias ? bias[gc] : 0.f;
            #pragma unroll
            for (int r=0;r<4;r++){
                long gr = m0 + wm + i*16 + quad*4 + r;
                float v = acc[i][j][r] + bv;
                if (act) v = gelu_tanh(v);
                long o = (long)bz*sC + gr*Nc + gc;
                if (C) C[o] = v;
                if (Chi){ u16 t = f2bf(v); Chi[o] = t; if (Clo) Clo[o] = f2bf(v - bf2f(t)); }
            }
        }
    }
}

// ---------------------------------------------------------------- MFMA GEMM 128x128, 3-product via VIRTUAL K
// K_virt = 3*Kc; segment 0: Ah*Bh, 1: Al*Bh, 2: Ah*Bl (pointer switch in staging).
// NBUF=3: counted-vmcnt single-barrier pipeline (grid-limited projections).
// NBUF=2: proven depth-2 __syncthreads path (4.5-blk/CU S-GEMM; 32KB LDS).
// swzmode 1: 8x4 supertile remap. swzmode 2: XCD-slice pinning.
// cskip=1 (causal): skip above-diagonal tiles AND stores.
// Optional 2nd problem (QKV+SQSK concurrency): blocks with by >= ycut switch
// to {Ah2..Bl2, C2, Nc2}, by -= ycut. Supertile y-bands (height 4) lie entirely
// within one problem when ycut%4==0 — no working-set interleaving per band.
template<int NBUF>
__global__ __launch_bounds__(256) void gemm_v3_k(
    const u16* __restrict__ Ah, const u16* __restrict__ Al,
    const u16* __restrict__ Bh, const u16* __restrict__ Bl,
    float* __restrict__ C,
    int M, int Kc, int Nc, int lda,
    long sA, long sB, long sC, int cskip, int swzmode,
    const u16* __restrict__ Ah2, const u16* __restrict__ Al2,
    const u16* __restrict__ Bh2, const u16* __restrict__ Bl2,
    float* __restrict__ C2, int ycut, int Nc2)
{
    __shared__ u16 shA[NBUF][128*32], shB[NBUF][128*32];
    int bx = blockIdx.x, by = blockIdx.y, bz = blockIdx.z;
    if (swzmode == 1){
        int lin = bx + gridDim.x*by;
        int within = lin & 31, st = lin >> 5;
        int stm = gridDim.x >> 3;
        bx = (st % stm)*8 + (within & 7);
        by = (st / stm)*4 + (within >> 3);
    } else if (swzmode == 2){
        int lin = bx + gridDim.x*(by + gridDim.y*bz);
        int xcd = lin & 7, idx = lin >> 3;
        bz = xcd + 8*(idx >> 6);
        int tile = idx & 63;
        bx = tile & 7; by = tile >> 3;
    }
    if (ycut && by >= ycut){
        Ah = Ah2; Al = Al2; Bh = Bh2; Bl = Bl2; C = C2;
        by -= ycut; Nc = Nc2;
    }
    const int m0 = bx*128, n0 = by*128;
    if (cskip == 1 && n0 > m0 + 127) return;
    const u16* gAh = Ah + (long)bz*sA;
    const u16* gAl = Al + (long)bz*sA;
    const u16* gBh = Bh + (long)bz*sB;
    const u16* gBl = Bl + (long)bz*sB;
    const int tid = threadIdx.x;
    const int wave = tid >> 6, lane = tid & 63;
    const int quad = lane >> 4, r16 = lane & 15;
    const int wm = (wave>>1)*64, wn = (wave&1)*64;

    f32x4 acc[4][4];
    #pragma unroll
    for (int i=0;i<4;i++)
        #pragma unroll
        for (int j=0;j<4;j++) acc[i][j] = (f32x4){0.f,0.f,0.f,0.f};

    const int segsteps = Kc >> 5;
    const int nsteps = 3*segsteps;
    auto stage = [&](int sel, int t){
        int seg = (t >= segsteps) + (t >= 2*segsteps);
        int k0 = (t - seg*segsteps) << 5;
        const u16* a = (seg==1) ? gAl : gAh;
        const u16* b = (seg==2) ? gBl : gBh;
        #pragma unroll
        for (int half=0; half<2; ++half){
            int c = half*256 + tid;
            int row = c >> 2;
            int kg = ((c & 3) ^ ((row >> 1) & 3))*8;
            gload16(a + (long)(m0+row)*lda + k0 + kg, &shA[sel][c*8]);
            gload16(b + (long)(n0+row)*Kc  + k0 + kg, &shB[sel][c*8]);
        }
    };

    const int swr = (quad ^ ((r16 >> 1) & 3))*8;
    if constexpr (NBUF == 2){
        stage(0, 0);
        __syncthreads();
        int cur = 0;
        for (int t = 0; t < nsteps; ++t){
            if (t+1 < nsteps) stage(cur^1, t+1);
            bf16x8 afh[4], bfh[4];
            #pragma unroll
            for (int i=0;i<4;i++){
                afh[i] = *(const bf16x8*)&shA[cur][(wm+i*16+r16)*32 + swr];
                bfh[i] = *(const bf16x8*)&shB[cur][(wn+i*16+r16)*32 + swr];
            }
            #pragma unroll
            for (int i=0;i<4;i++)
                #pragma unroll
                for (int j=0;j<4;j++)
                    acc[i][j] = __builtin_amdgcn_mfma_f32_16x16x32_bf16(afh[i], bfh[j], acc[i][j], 0,0,0);
            __syncthreads();
            cur ^= 1;
        }
    } else {
        stage(0, 0);
        if (1 < nsteps) stage(1, 1);
        for (int t = 0; t < nsteps; ++t){
            if (t+1 < nsteps) asm volatile("s_waitcnt vmcnt(4)" ::: "memory");
            else              asm volatile("s_waitcnt vmcnt(0)" ::: "memory");
            __builtin_amdgcn_s_barrier();
            if (t+2 < nsteps) stage((t+2)%3, t+2);
            const int rd = t % 3;
            bf16x8 afh[4], bfh[4];
            #pragma unroll
            for (int i=0;i<4;i++){
                afh[i] = *(const bf16x8*)&shA[rd][(wm+i*16+r16)*32 + swr];
                bfh[i] = *(const bf16x8*)&shB[rd][(wn+i*16+r16)*32 + swr];
            }
            #pragma unroll
            for (int i=0;i<4;i++)
                #pragma unroll
                for (int j=0;j<4;j++)
                    acc[i][j] = __builtin_amdgcn_mfma_f32_16x16x32_bf16(afh[i], bfh[j], acc[i][j], 0,0,0);
        }
    }
    #pragma unroll
    for (int i=0;i<4;i++){
        #pragma unroll
        for (int j=0;j<4;j++){
            int gc = n0 + wn + j*16 + r16;
            if (gc >= Nc) continue;
            #pragma unroll
            for (int r=0;r<4;r++){
                long gr = m0 + wm + i*16 + quad*4 + r;
                if (cskip == 1 && gc > gr) continue;   // above-diagonal: never read
                long o = (long)bz*sC + gr*Nc + gc;
                C[o] = acc[i][j][r];
            }
        }
    }
}

// ---------------------------------------------------------------- transport GEMM 64x64:
// out[r][n] = sum_g (esign*phi[r][g]) * sum_kd A[r][kd]*gen[g][n][kd]
// = virtual-K GEMM over GF[n*1536 + g*512 + kd] with per-segment register fold.
__global__ __launch_bounds__(256) void tgemm_k(
    const u16* __restrict__ Ahh,   // [M][512] bf16
    const u16* __restrict__ GFh,   // [n][g*512+kd]
    const float* __restrict__ phi, float esign,
    float* __restrict__ C, u16* __restrict__ Chi, u16* __restrict__ Clo,
    const float* __restrict__ t_x, const float* __restrict__ t_a1,
    const float* __restrict__ t_res)
{
    __shared__ u16 shA[2][64*64], shB[2][64*64];
    const int m0 = blockIdx.x*64, n0 = blockIdx.y*64;
    const int tid = threadIdx.x;
    const int wave = tid >> 6, lane = tid & 63;
    const int quad = lane >> 4, r16 = lane & 15;
    const int wr = wave*16;

    float ph[3][4];
    #pragma unroll
    for (int sgi=0; sgi<3; ++sgi)
        #pragma unroll
        for (int r=0; r<4; ++r)
            ph[sgi][r] = esign*phi[(size_t)(m0+wr+quad*4+r)*3 + sgi];

    f32x4 acc[4], tot[4];
    #pragma unroll
    for (int j=0;j<4;j++){ acc[j] = (f32x4){0.f,0.f,0.f,0.f}; tot[j] = acc[j]; }

    auto stage = [&](int sel, int t){
        int seg = t >> 3, k0 = (t & 7) << 6;
        #pragma unroll
        for (int rep=0; rep<2; ++rep){
            int c = rep*256 + tid;
            int row = c >> 3;
            int kg = ((c & 7) ^ (row & 7))*8;
            gload16(Ahh + (long)(m0+row)*KK + k0 + kg, &shA[sel][c*8]);
            gload16(GFh + (long)(n0+row)*(3*KK) + seg*KK + k0 + kg, &shB[sel][c*8]);
        }
    };

    stage(0, 0);
    __syncthreads();
    int cur = 0;
    for (int t = 0; t < 24; ++t){
        if (t+1 < 24) stage(cur^1, t+1);
        #pragma unroll
        for (int kk=0; kk<2; ++kk){
            const int s = (((kk<<2)+quad) ^ (r16 & 7))*8;
            bf16x8 af = *(const bf16x8*)&shA[cur][(wr+r16)*64 + s];
            #pragma unroll
            for (int j=0;j<4;j++){
                bf16x8 bh = *(const bf16x8*)&shB[cur][(j*16+r16)*64 + s];
                acc[j] = __builtin_amdgcn_mfma_f32_16x16x32_bf16(af, bh, acc[j], 0,0,0);
            }
        }
        if ((t & 7) == 7){
            int sgi = t >> 3;
            #pragma unroll
            for (int j=0;j<4;j++){
                #pragma unroll
                for (int r=0;r<4;r++) tot[j][r] += ph[sgi][r]*acc[j][r];
                acc[j] = (f32x4){0.f,0.f,0.f,0.f};
            }
        }
        __syncthreads();
        cur ^= 1;
    }
    #pragma unroll
    for (int j=0;j<4;j++){
        int gc = n0 + j*16 + r16;
        #pragma unroll
        for (int r=0;r<4;r++){
            long gr = m0 + wr + quad*4 + r;
            float v = tot[j][r];
            long o = gr*(long)KK + gc;
            if (t_x){
                v = t_x[o] + t_a1[o] + 0.5f*v;
                if (t_res) v += t_res[o];
            }
            if (C) C[o] = v;
            if (Chi){ u16 t2 = f2bf(v); Chi[o] = t2; if (Clo) Clo[o] = f2bf(v - bf2f(t2)); }
        }
    }
}

// ---------------------------------------------------------------- MFMA GEMM 64x64
// depth-2 / single-__syncthreads pipeline, 32KB LDS. K-step 64.
// swz=1: 8x4 supertile remap. epilogue: fused FFN update (fmode 1=mid, 2=final)
__global__ __launch_bounds__(256) void gemm64_k(
    const u16* __restrict__ Ah, const u16* __restrict__ Bh,
    float* __restrict__ C, u16* __restrict__ Chi, u16* __restrict__ Clo,
    int M, int Kc, int Nc, int lda,
    long sA, long sB, long sC, const float* __restrict__ bias, int act,
    int ktrim, int swz,
    const float* __restrict__ f_hin, const float* __restrict__ f_bmh,
    const float* __restrict__ f_mup, const float* __restrict__ f_lr,
    u16* __restrict__ f_hh, float* __restrict__ f_hout,
    const float* __restrict__ f_mrb, const float* __restrict__ f_mn2,
    float* __restrict__ f_out, int fmode)
{
    __shared__ u16 shA[2][64*64], shB[2][64*64];
    int bx = blockIdx.x, by = blockIdx.y;
    if (swz){
        int lin = bx + gridDim.x*by;
        int within = lin & 31, st = lin >> 5;
        int stm = gridDim.x >> 3;
        bx = (st % stm)*8 + (within & 7);
        by = (st / stm)*4 + (within >> 3);
    }
    const int m0 = bx*64, n0 = by*64;
    const int bz = blockIdx.z;
    const u16* gA = Ah + (long)bz*sA;
    const u16* gB = Bh + (long)bz*sB;
    const int tid = threadIdx.x;
    const int wave = tid >> 6, lane = tid & 63;
    const int quad = lane >> 4, r16 = lane & 15;
    const int wr = wave*16;
    const int kend = ktrim ? min(Kc, m0 + 64) : Kc;
    const int nsteps = kend >> 6;

    f32x4 acc[4];
    #pragma unroll
    for (int j=0;j<4;j++) acc[j] = (f32x4){0.f,0.f,0.f,0.f};

    auto stage = [&](int sel, int k0){
        #pragma unroll
        for (int rep=0; rep<2; ++rep){
            int c = rep*256 + tid;
            int row = c >> 3;
            int kg = ((c & 7) ^ (row & 7))*8;     // pre-swizzled global slot
            gload16(gA + (long)(m0+row)*lda + k0 + kg, &shA[sel][c*8]);
            gload16(gB + (long)(n0+row)*Kc + k0 + kg, &shB[sel][c*8]);
        }
    };

    stage(0, 0);
    __syncthreads();
    int cur = 0;
    for (int t = 0; t < nsteps; ++t){
        if (t+1 < nsteps) stage(cur^1, (t+1)<<6);
        #pragma unroll
        for (int kk=0; kk<2; ++kk){
            const int s = (((kk<<2)+quad) ^ (r16 & 7))*8;   // undo swizzle on read
            bf16x8 af = *(const bf16x8*)&shA[cur][(wr+r16)*64 + s];
            #pragma unroll
            for (int j=0;j<4;j++){
                bf16x8 bh = *(const bf16x8*)&shB[cur][(j*16+r16)*64 + s];
                acc[j] = __builtin_amdgcn_mfma_f32_16x16x32_bf16(af, bh, acc[j], 0,0,0);
            }
        }
        __syncthreads();
        cur ^= 1;
    }
    float lrv = 0.f;
    if (fmode) lrv = *f_lr;
    #pragma unroll
    for (int j=0;j<4;j++){
        int gc = n0 + j*16 + r16;
        float bv = bias ? bias[gc] : 0.f;
        #pragma unroll
        for (int r=0;r<4;r++){
            long gr = m0 + wr + quad*4 + r;
            float v = acc[j][r] + bv;
            if (act) v = gelu_tanh(v);
            long o = (long)bz*sC + gr*Nc + gc;
            if (fmode){
                float hv = f_hin[o];
                float val = hv + lrv*(v - (1e-3f*(hv - f_mup[o]) + (hv - f_bmh[o])));
                if (fmode == 1){ f_hout[o] = val; f_hh[o] = f2bf(val); }
                else           { f_out[o] = f_mrb[o] + val - f_mn2[o]; }
            } else {
                if (C) C[o] = v;
                if (Chi){ u16 t = f2bf(v); Chi[o] = t; if (Clo) Clo[o] = f2bf(v - bf2f(t)); }
            }
        }
    }
}

// ---------------------------------------------------------------- LayerNorm (+bf16 out, +sigma split, +output copies)
__global__ __launch_bounds__(256) void ln_k(
    const float* __restrict__ x, const float* __restrict__ g,
    const float* __restrict__ be, float* __restrict__ y,
    u16* __restrict__ yh16,
    const float* __restrict__ sg, u16* __restrict__ sgh, u16* __restrict__ sgl,
    float* __restrict__ osig, const float* __restrict__ phi, float* __restrict__ ophi)
{
    __shared__ float sh[8];
    const int r = blockIdx.x, tid = threadIdx.x;
    const float* xr = x + (long)r*KK;
    float2 v = *(const float2*)(xr + tid*2);
    float s = v.x+v.y, s2 = v.x*v.x+v.y*v.y;
    #pragma unroll
    for (int o=32;o>0;o>>=1){ s += __shfl_down(s,o); s2 += __shfl_down(s2,o); }
    if ((tid&63)==0){ sh[tid>>6]=s; sh[4+(tid>>6)]=s2; }
    __syncthreads();
    s  = sh[0]+sh[1]+sh[2]+sh[3];
    s2 = sh[4]+sh[5]+sh[6]+sh[7];
    const float mean = s*(1.f/KK);
    const float var  = s2*(1.f/KK) - mean*mean;
    const float rs = rsqrtf(var + 1e-5f);
    float2 gg = *(const float2*)(g + tid*2);
    float2 bb = *(const float2*)(be + tid*2);
    float ox = (v.x-mean)*rs*gg.x + bb.x;
    float oy = (v.y-mean)*rs*gg.y + bb.y;
    long o = (long)r*KK + tid*2;
    *(float2*)(y + o) = make_float2(ox, oy);
    if (yh16){ yh16[o] = f2bf(ox); yh16[o+1] = f2bf(oy); }
    if (sgh){
        float2 sv = *(const float2*)(sg + o);
        wsplit(sgh, sgl, o,   sv.x);
        wsplit(sgh, sgl, o+1, sv.y);
        if (osig) *(float2*)(osig + o) = sv;
    }
    if (ophi && tid < 3) ophi[(size_t)r*3 + tid] = phi[(size_t)r*3 + tid];
}

// ---------------------------------------------------------------- merged attention prep + V transpose
__global__ __launch_bounds__(512) void prepvt_k(
    const float* __restrict__ QKV, const float* __restrict__ SQSK,
    u16* __restrict__ CFh, u16* __restrict__ CFl,
    u16* __restrict__ KSh, u16* __restrict__ KSl, float* __restrict__ dvec,
    u16* __restrict__ VTh)
{
    __shared__ float t[64][65];
    const int bx = blockIdx.x;
    const int tid = threadIdx.x;
    if (bx < BN){
        const int bn = bx;
        const int b = bn / NN, n = bn % NN;
        const int h = tid >> 6, d = tid & 63;
        float q  = QKV[(size_t)bn*1536 + h*DHh + d];
        float k  = QKV[(size_t)bn*1536 + KK + h*DHh + d];
        float sq = SQSK[(size_t)bn*1024 + h*DHh + d] + 1e-8f;
        float sk = SQSK[(size_t)bn*1024 + KK + h*DHh + d] + 1e-8f;
        float inv = 1.f/sq;
        float nqi = -2.f*q*inv;
        float skk = sk + k*k;
        const size_t base = ((size_t)(h*BB + b)*NN + n)*128;
        wsplit(CFh, CFl, base+d,    inv);
        wsplit(CFh, CFl, base+64+d, nqi);
        wsplit(KSh, KSl, base+d,    skk);
        wsplit(KSh, KSl, base+64+d, k);
        float dv = __logf(sk);
        #pragma unroll
        for (int o=32;o>0;o>>=1) dv += __shfl_down(dv,o);
        if (d==0) dvec[((size_t)h*BB + b)*NN + n] = dv;
        return;
    }
    const int idx = bx - BN;
    const int n0 = (idx & 15)*64;
    const int h = (idx>>4)&7;
    const int b = idx>>7;
    const int c4 = (tid & 15) * 4;
    const int r0 = tid >> 4;     // 0..31
    for (int rr = r0; rr < 64; rr += 32){
        float4 v = *(const float4*)(QKV + (size_t)(b*NN + n0 + rr)*1536 + 1024 + h*DHh + c4);
        t[c4+0][rr] = v.x; t[c4+1][rr] = v.y; t[c4+2][rr] = v.z; t[c4+3][rr] = v.w;
    }
    __syncthreads();
    for (int dd = r0; dd < 64; dd += 32){
        size_t base = ((size_t)(h*BB + b)*64 + dd)*NN + n0 + c4;
        #pragma unroll
        for (int q=0;q<4;q++) VTh[base+q] = f2bf(t[dd][c4+q]);
    }
}

// ---------------------------------------------------------------- softmax, all 8 heads, register-resident
__global__ __launch_bounds__(256) void softmax_all_k(
    float* __restrict__ S, const float* __restrict__ dvec, u16* __restrict__ BMh)
{
    __shared__ float s_redA[2][4], s_redB[2][4];
    const int tid = threadIdx.x;
    const int b = blockIdx.x >> 10, i = blockIdx.x & (NN-1);
    const int L = i + 1;
    const int JEND = ((i >> 6) + 1) << 6;
    const int j4 = tid*4;
    const bool act = (j4 < JEND);
    const int wv = tid >> 6;
    const bool lane0 = ((tid & 63) == 0);

    float bm[4] = {0.f,0.f,0.f,0.f};
    float4 rv = make_float4(0,0,0,0), dpv = make_float4(0,0,0,0);
    if (act){
        rv  = *(const float4*)(S + ((long)(0*BB + b)*NN + i)*NN + j4);
        dpv = *(const float4*)(dvec + (size_t)(0*BB + b)*NN + j4);
    }
    for (int h = 0; h < 8; ++h){
        const int z = h*BB + b;
        float4 rvn = make_float4(0,0,0,0), dpn = make_float4(0,0,0,0);
        if (h < 7 && act){
            const int zn = (h+1)*BB + b;
            rvn = *(const float4*)(S + ((long)zn*NN + i)*NN + j4);
            dpn = *(const float4*)(dvec + (size_t)zn*NN + j4);
        }
        float sc[4];
        const float* rp = (const float*)&rv;
        const float* dp = (const float*)&dpv;
        #pragma unroll
        for (int e=0;e<4;e++){
            float s = -0.5f*rp[e] + 0.5f*dp[e];
            sc[e] = (act && (j4 + e < L)) ? s : -3.0e38f;
        }
        float lm = fmaxf(fmaxf(sc[0],sc[1]), fmaxf(sc[2],sc[3]));
        #pragma unroll
        for (int o=32;o>0;o>>=1) lm = fmaxf(lm, __shfl_xor(lm, o));
        if (lane0) s_redA[h&1][wv] = lm;
        __syncthreads();
        const float mx = fmaxf(fmaxf(s_redA[h&1][0],s_redA[h&1][1]),
                               fmaxf(s_redA[h&1][2],s_redA[h&1][3]));
        float w4[4], ps = 0.f;
        #pragma unroll
        for (int e=0;e<4;e++){
            float e1 = (act && (j4 + e < L)) ? __expf(sc[e]-mx) : 0.f;
            w4[e] = e1; ps += e1;
        }
        #pragma unroll
        for (int o=32;o>0;o>>=1) ps += __shfl_xor(ps, o);
        if (lane0) s_redB[h&1][wv] = ps;
        __syncthreads();
        const float isum = 1.f/(s_redB[h&1][0]+s_redB[h&1][1]+s_redB[h&1][2]+s_redB[h&1][3]);
        if (act){
            u16* brow = (u16*)(S + ((long)z*NN + i)*NN);
            ushort4 st;
            float w0=w4[0]*isum, w1=w4[1]*isum, w2=w4[2]*isum, w3=w4[3]*isum;
            bm[0]+=0.125f*w0; bm[1]+=0.125f*w1; bm[2]+=0.125f*w2; bm[3]+=0.125f*w3;
            st.x=f2bf(w0); st.y=f2bf(w1); st.z=f2bf(w2); st.w=f2bf(w3);
            *(ushort4*)(brow + j4) = st;
        }
        rv = rvn; dpv = dpn;
    }
    if (act){
        const long bmrow = ((long)b*NN + i)*NN;
        ushort4 st;
        st.x=f2bf(bm[0]); st.y=f2bf(bm[1]); st.z=f2bf(bm[2]); st.w=f2bf(bm[3]);
        *(ushort4*)(BMh + bmrow + j4) = st;
    }
}

// ---------------------------------------------------------------- PV, all 32 (head,batch) slices, grid (NN/64, 32)
__global__ __launch_bounds__(256) void pv_k(
    const u16* __restrict__ Sbeta,
    const u16* __restrict__ VTh,
    u16* __restrict__ xh)
{
    __shared__ u16 shA[2][64*64], shB[2][64*64];
    const int m0 = blockIdx.x*64;
    const int z = blockIdx.y;              // z = head*BB + b
    const int b = z & 3, head = z >> 2;
    const int tid = threadIdx.x;
    const int wave = tid>>6, lane = tid&63;
    const int quad = lane>>4, r16 = lane&15;
    f32x4 acc[4];
    #pragma unroll
    for (int j=0;j<4;j++) acc[j]=(f32x4){0.f,0.f,0.f,0.f};
    const int nsteps = (m0 >> 6) + 1;

    auto stage = [&](int sel, int j0){
        #pragma unroll
        for (int rep=0; rep<2; ++rep){
            int c = rep*256 + tid;
            int row = c >> 3;
            int k8 = ((c & 7) ^ (row & 7))*8;
            gload16(Sbeta + ((size_t)(z*NN + m0 + row))*(2*NN) + j0 + k8, &shA[sel][c*8]);
            gload16(VTh + ((size_t)(z*64 + row))*NN + j0 + k8, &shB[sel][c*8]);
        }
    };

    stage(0, 0);
    __syncthreads();
    int cur = 0;
    for (int t = 0; t < nsteps; ++t){
        if (t+1 < nsteps) stage(cur^1, (t+1)<<6);
        #pragma unroll
        for (int kk=0; kk<2; ++kk){
            const int s = (((kk<<2)+quad) ^ (r16 & 7))*8;
            bf16x8 af = *(const bf16x8*)&shA[cur][(wave*16 + r16)*64 + s];
            #pragma unroll
            for (int nj=0; nj<4; ++nj){
                bf16x8 bh = *(const bf16x8*)&shB[cur][(nj*16 + r16)*64 + s];
                acc[nj] = __builtin_amdgcn_mfma_f32_16x16x32_bf16(af, bh, acc[nj], 0,0,0);
            }
        }
        __syncthreads();
        cur ^= 1;
    }
    #pragma unroll
    for (int nj=0;nj<4;nj++){
        #pragma unroll
        for (int r=0;r<4;r++){
            int i = m0 + wave*16 + quad*4 + r;
            int d = nj*16 + r16;
            size_t o = ((size_t)(b*NN)+i)*KK + head*64 + d;
            xh[o] = f2bf(acc[nj][r]);
        }
    }
}

// ---------------------------------------------------------------- launch
extern "C" void kernel_launch(void* const* d_in, const int* in_sizes, int n_in,
                              void* d_out, int out_size, void* d_ws, size_t ws_size,
                              hipStream_t stream) {
    const float* mu_q    = (const float*)d_in[0];
    const float* sigma_q = (const float*)d_in[1];
    const float* phi     = (const float*)d_in[2];
    const float* gen     = (const float*)d_in[3];
    const float* mu_prior= (const float*)d_in[5];
    const float* Wq = (const float*)d_in[6];
    const float* Wk = (const float*)d_in[7];
    const float* Wv = (const float*)d_in[8];
    const float* Wo = (const float*)d_in[9];
    const float* g1 = (const float*)d_in[10];
    const float* be1= (const float*)d_in[11];
    const float* g2 = (const float*)d_in[12];
    const float* be2= (const float*)d_in[13];
    const float* W1 = (const float*)d_in[14];
    const float* bh1= (const float*)d_in[15];
    const float* W2 = (const float*)d_in[16];
    const float* bh2= (const float*)d_in[17];
    const float* lr = (const float*)d_in[18];
    float* out = (float*)d_out;

    float* w = (float*)d_ws;
    size_t off = 0;
    auto alloc = [&](size_t n){ float* p = w + off; off += (n+3)&~(size_t)3; return p; };
    auto ualloc = [&](size_t n){ return (u16*)alloc((n+1)/2); };

    // Xb..REG is one contiguous 32*NN*NN-float region reused as Sbig in phase C.
    float* Xb   = alloc((size_t)BN*KK);        // mu_n; later mn2
    float* A1b  = alloc((size_t)BN*KK);        // a1 / bmh
    float* A2b  = alloc((size_t)BN*KK);        // (spacer; part of Sbig)
    float* QKVb = alloc((size_t)BN*3*KK);      // QKV; later WOb / Hb / MRb
    float* SQSKb= alloc((size_t)BN*2*KK);
    float* REG  = alloc((size_t)16*NN*NN);     // SGh/SGl/Xh/A1h/WOh | Sbig tail | ZH
    float* Sbig = Xb;                          // 32 * NN*NN floats
    u16*  SGh   = (u16*)REG;
    u16*  SGl   = SGh + (size_t)BN*KK;
    u16*  Xh    = SGl + (size_t)BN*KK;
    u16*  A1h   = Xh  + (size_t)BN*KK;
    u16*  WOh   = A1h + (size_t)BN*KK;
    u16*  ZH    = (u16*)REG;
    float* Db_  = alloc((size_t)HH*BB*NN);
    u16* AH  = ualloc((size_t)BN*HIDd); u16* AL  = ualloc((size_t)BN*HIDd);
    u16* CFh = AH;
    u16* CFl = AH + (size_t)HH*BB*NN*128;
    u16* KSh = AL;
    u16* KSl = AL + (size_t)HH*BB*NN*128;
    u16* VTh = ualloc((size_t)HH*BB*64*NN);
    u16* GFh = ualloc((size_t)3*KK*KK);
    u16* WQKVh= ualloc((size_t)3*KK*KK); u16* WQKVl= ualloc((size_t)3*KK*KK);
    u16* WSQKh= ualloc((size_t)2*KK*KK); u16* WSQKl= ualloc((size_t)2*KK*KK);
    u16* WoTh= ualloc((size_t)KK*KK);
    u16* W1Th= ualloc((size_t)KK*HIDd);
    u16* W2Th= ualloc((size_t)KK*HIDd);
    u16* BMh = ualloc((size_t)BB*NN*NN);
    u16* HTh = ualloc((size_t)BB*KK*NN);
    float* WOb = QKVb;
    float* Hb  = QKVb + (size_t)BN*KK;
    float* MRb = QKVb + 2*(size_t)BN*KK;
    float* MN2b= Xb;
    (void)A2b;

    // ---- weight prep: one dispatch ----
    {
        dim3 gw(64, 16, 9);
        wmega_k<<<gw, 256, 0, stream>>>(Wq, Wk, Wv, Wo, W1, W2, gen,
                                        WQKVh, WQKVl, WoTh, WSQKh, WSQKl,
                                        W1Th, W2Th, GFh);
    }

    // ---- phase A: LN1 (+bf16 out, +sigma split, +output copies) + forward transport ----
    ln_k<<<BN, 256, 0, stream>>>(mu_q, g1, be1, Xb, Xh, sigma_q, SGh, SGl,
                                 out + (size_t)BN*KK, phi, out + 2*(size_t)BN*KK);
    {
        dim3 tg(BN/64, KK/64, 1);
        tgemm_k<<<tg, 256, 0, stream>>>(Xh, GFh, phi, 1.f, A1b, A1h, 0, 0, 0, 0);
        tgemm_k<<<tg, 256, 0, stream>>>(A1h, GFh, phi, 1.f, 0, AH, AL, Xb, A1b, 0);
    }

    // ---- phase B: QKV (by 0..11) + SQSK (by 12..19) in ONE dispatch, 640 blocks
    //      (2.5 blocks/CU concurrent vs 1.5 then 1.0 serialized) ----
    {
        dim3 g(BN/128, 20, 1);
        gemm_v3_k<3><<<g, 256, 0, stream>>>(AH, AL, WQKVh, WQKVl, QKVb,
            BN, KK, 3*KK, KK, 0, 0, 0, 0, 1,
            SGh, SGl, WSQKh, WSQKl, SQSKb, 12, 2*KK);
    }
    prepvt_k<<<BN + 512, 512, 0, stream>>>(QKVb, SQSKb, CFh, CFl, KSh, KSl, Db_, VTh);

    // ---- phase C: attention, all 8 heads in 3 dispatches (Sbig = Xb..REG, 134 MB) ----
    {
        dim3 sg(NN/128, NN/128, 32);
        gemm_v3_k<2><<<sg, 256, 0, stream>>>(CFh, CFl, KSh, KSl, Sbig,
            NN, 128, NN, 128, (long)NN*128, (long)NN*128, (long)NN*NN, 1, 2,
            0, 0, 0, 0, 0, 0, 0);
        softmax_all_k<<<BB*NN, 256, 0, stream>>>(Sbig, Db_, BMh);
        dim3 pg(NN/64, 32, 1);
        pv_k<<<pg, 256, 0, stream>>>((const u16*)Sbig, VTh, AH);
    }

    // ---- phase D: output proj + back transport (fused mrb) + LN2 ----
    {
        dim3 wg(BN/64, KK/64, 1);
        gemm64_k<<<wg, 256, 0, stream>>>(AH, WoTh, WOb, WOh, 0,
            BN, KK, KK, KK, 0,0,0, nullptr, 0, 0, 0,
            0,0,0,0,0,0,0,0,0,0);
        dim3 tg(BN/64, KK/64, 1);
        tgemm_k<<<tg, 256, 0, stream>>>(WOh, GFh, phi, -1.f, A1b, A1h, 0, 0, 0, 0);
        tgemm_k<<<tg, 256, 0, stream>>>(A1h, GFh, phi, -1.f, MRb, 0, 0, WOb, A1b, mu_q);
    }
    ln_k<<<BN, 256, 0, stream>>>(MRb, g2, be2, MN2b, AH, 0, 0, 0, 0, 0, 0);

    // ---- phase E: 2 VFE iterations (bmh first, then W1, then W2 with fused update) ----
    for (int it=0; it<2; ++it){
        const float* hin = (it==0) ? MN2b : Hb;
        {
            dim3 tg(KK/32, NN/32, BB);
            split_t_k<<<tg, 256, 0, stream>>>(hin, HTh, 0, NN, KK,
                                              (long)NN*KK, (long)KK*NN, 0);
        }
        {
            dim3 bg(NN/64, KK/64, BB);
            gemm64_k<<<bg, 256, 0, stream>>>(BMh, HTh, A1b, 0,0,
                                             NN, NN, KK, NN,
                                             (long)NN*NN, (long)KK*NN, (long)NN*KK,
                                             nullptr, 0, 1, 0,
                                             0,0,0,0,0,0,0,0,0,0);
        }
        {
            dim3 wg1(BN/128, HIDd/128, 1);   // (32,16), supertile swizzle
            gemm_mfma_k<<<wg1, 256, 0, stream>>>(AH, W1Th, 0, ZH, 0,
                BN, KK, HIDd, KK, 0, 0, 0, bh1, 1, 1);
        }
        {   // W2 + fused FFN update, supertile swizzle
            dim3 wg(BN/64, KK/64, 1);
            gemm64_k<<<wg, 256, 0, stream>>>(ZH, W2Th, 0,0,0,
                                             BN, HIDd, KK, HIDd, 0,0,0, bh2, 0, 0, 1,
                                             hin, A1b, mu_prior, lr, AH, Hb, MRb, MN2b, out,
                                             (it==0) ? 1 : 2);
        }
    }

    (void)in_sizes; (void)n_in; (void)out_size; (void)ws_size;
}

// Round 11
// 540.810 us; speedup vs baseline: 1.1821x; 1.0253x over previous
//
#include <hip/hip_runtime.h>
#include <math.h>

#define BB 4
#define NN 1024
#define KK 512
#define HH 8
#define DHh 64
#define HIDd 2048
#define BN (BB*NN)

typedef unsigned short u16;
typedef __attribute__((ext_vector_type(8))) short bf16x8;
typedef __attribute__((ext_vector_type(4))) float f32x4;

// ---------------------------------------------------------------- helpers
__device__ __forceinline__ float gelu_tanh(float x){
    // tanh-gelu via fast exp: 0.5x(1+tanh(u)) = x*t/(t+1), t=e^{2u}
    float u = 0.7978845608028654f*(x + 0.044715f*x*x*x);
    u = fminf(fmaxf(u, -15.f), 15.f);
    float t = __expf(2.f*u);
    return x*t/(t+1.f);
}
__device__ __forceinline__ u16 f2bf(float x){
    unsigned int u = __float_as_uint(x);
    unsigned int r = (u + 0x7fffu + ((u>>16)&1u)) >> 16;
    return (u16)r;
}
__device__ __forceinline__ float bf2f(u16 b){
    return __uint_as_float(((unsigned int)b)<<16);
}
__device__ __forceinline__ void gload16(const void* g, void* l){
    __builtin_amdgcn_global_load_lds((__attribute__((address_space(1))) void*)g,
                                     (__attribute__((address_space(3))) void*)l, 16, 0, 0);
}
__device__ __forceinline__ void wsplit(u16* hi, u16* lo, size_t o, float v){
    u16 h = f2bf(v);
    hi[o] = h;
    if (lo) lo[o] = f2bf(v - bf2f(h));
}

// ---------------------------------------------------------------- generic transpose-split (used for h^T in phase E)
__global__ __launch_bounds__(256) void split_t_k(
    const float* __restrict__ src, u16* __restrict__ hi, u16* __restrict__ lo,
    int Kc, int Nc, long sS, long sD, int square)
{
    __shared__ float t[32][33];
    const int n0 = blockIdx.x*32, k0 = blockIdx.y*32, bz = blockIdx.z;
    const float* S = src + (long)bz*sS;
    const int tx = threadIdx.x & 31, ty = threadIdx.x >> 5;
    for (int r = ty; r < 32; r += 8){
        float v = S[(long)(k0+r)*Nc + n0+tx];
        if (square) v *= v;
        t[r][tx] = v;
    }
    __syncthreads();
    for (int r = ty; r < 32; r += 8){
        float v = t[tx][r];
        long o = (long)bz*sD + (long)(n0+r)*Kc + k0 + tx;
        wsplit(hi, lo, o, v);
    }
}

// ---------------------------------------------------------------- all weight prep in one dispatch, grid (64,16,9)
__global__ __launch_bounds__(256) void wmega_k(
    const float* __restrict__ Wq, const float* __restrict__ Wk,
    const float* __restrict__ Wv, const float* __restrict__ Wo,
    const float* __restrict__ W1, const float* __restrict__ W2,
    const float* __restrict__ gen,
    u16* __restrict__ WQKVh, u16* __restrict__ WQKVl, u16* __restrict__ WoTh,
    u16* __restrict__ WSQKh, u16* __restrict__ WSQKl,
    u16* __restrict__ W1Th, u16* __restrict__ W2Th, u16* __restrict__ GFh)
{
    const int z = blockIdx.z;
    const int tid = threadIdx.x;
    if (z == 8){   // gflat: copy gen(3,K,K) -> GFh[k][g*512+l]
        if (blockIdx.x >= 48) return;
        const int c0 = blockIdx.x*32, k0 = blockIdx.y*32;
        const int tx = tid&31, ty = tid>>5;
        const int g = c0/KK, l0 = c0%KK;
        for (int r=ty; r<32; r+=8)
            GFh[(size_t)(k0+r)*(3*KK) + c0+tx] =
                f2bf(gen[(size_t)g*KK*KK + (size_t)(k0+r)*KK + l0+tx]);
        return;
    }
    __shared__ float t[32][33];
    const float* src; u16* hi; u16* lo=0; int sq=0;
    int n0, k0, Kc, Nc;
    const size_t KK2 = (size_t)KK*KK;
    if (z < 6){
        if (blockIdx.x >= 16) return;
        n0 = blockIdx.x*32; k0 = blockIdx.y*32; Kc=KK; Nc=KK;
        if      (z==0){ src=Wq; hi=WQKVh;       lo=WQKVl; }
        else if (z==1){ src=Wk; hi=WQKVh+KK2;   lo=WQKVl+KK2; }
        else if (z==2){ src=Wv; hi=WQKVh+2*KK2; lo=WQKVl+2*KK2; }
        else if (z==3){ src=Wo; hi=WoTh; }
        else if (z==4){ src=Wq; hi=WSQKh;       lo=WSQKl; sq=1; }
        else          { src=Wk; hi=WSQKh+KK2;   lo=WSQKl+KK2; sq=1; }
    } else if (z == 6){  // W1 [512][2048] -> [2048][512]
        src=W1; hi=W1Th; Kc=KK; Nc=HIDd;
        n0 = blockIdx.x*32; k0 = blockIdx.y*32;
    } else {             // W2 [2048][512] -> [512][2048]
        src=W2; hi=W2Th; Kc=HIDd; Nc=KK;
        n0 = blockIdx.y*32; k0 = blockIdx.x*32;
    }
    const int tx=tid&31, ty=tid>>5;
    for (int r=ty;r<32;r+=8){
        float v = src[(long)(k0+r)*Nc + n0+tx];
        if (sq) v*=v;
        t[r][tx]=v;
    }
    __syncthreads();
    for (int r=ty;r<32;r+=8){
        float v = t[tx][r];
        long o = (long)(n0+r)*Kc + k0+tx;
        wsplit(hi, lo, o, v);
    }
}

// ---------------------------------------------------------------- MFMA GEMM 128x128, single product
// NBUF=3 counted-vmcnt single-barrier pipeline.
// swz=1: 8x4 supertile remap.
// Optional 2nd problem (bmh || W1 concurrency): blocks with by < ycut run the
// bmh GEMM  A1b[b] = BMh[b] (NNxNN, causal-trimmed K) x HTh[b] (KKxNN rows),
// reshaped to 128x128 tiles: m-tile = bx&7, batch = bx>>3, n-tile = by.
// kend = m0+128 is exact because softmax zero-extends BMh to the 128 boundary.
__global__ __launch_bounds__(256) void gemm_mfma_k(
    const u16* __restrict__ Ah, const u16* __restrict__ Bh,
    float* __restrict__ C, u16* __restrict__ Chi, u16* __restrict__ Clo,
    int M, int Kc, int Nc, int lda,
    long sA, long sB, long sC, const float* __restrict__ bias, int act,
    int swz,
    const u16* __restrict__ A2, const u16* __restrict__ B2,
    float* __restrict__ C2, int ycut)
{
    __shared__ u16 shA[3][128*32], shB[3][128*32];
    int bx = blockIdx.x, by = blockIdx.y;
    if (swz){
        int lin = bx + gridDim.x*by;
        int within = lin & 31, st = lin >> 5;
        int stm = gridDim.x >> 3;
        bx = (st % stm)*8 + (within & 7);
        by = (st / stm)*4 + (within >> 3);
    }
    int bz = blockIdx.z;
    int m0, n0, kend;
    const u16 *gAh, *gBh;
    if (ycut && by < ycut){          // problem 2: bmh
        m0 = (bx & 7)*128; n0 = by*128; bz = bx >> 3;
        gAh = A2 + (long)bz*NN*NN;
        gBh = B2 + (long)bz*KK*NN;
        Kc = NN; lda = NN; Nc = KK;
        C = C2 + (long)bz*NN*KK; Chi = 0; Clo = 0; bias = 0; act = 0; sC = 0;
        kend = m0 + 128;             // causal trim (BMh zero-extended to 128)
        bz = 0;
    } else {
        if (ycut) by -= ycut;
        m0 = bx*128; n0 = by*128;
        gAh = Ah + (long)bz*sA;
        gBh = Bh + (long)bz*sB;
        kend = Kc;
    }
    const int tid = threadIdx.x;
    const int wave = tid >> 6, lane = tid & 63;
    const int quad = lane >> 4, r16 = lane & 15;
    const int wm = (wave>>1)*64, wn = (wave&1)*64;

    f32x4 acc[4][4];
    #pragma unroll
    for (int i=0;i<4;i++)
        #pragma unroll
        for (int j=0;j<4;j++) acc[i][j] = (f32x4){0.f,0.f,0.f,0.f};

    auto stage = [&](int sel, int k0){
        #pragma unroll
        for (int half=0; half<2; ++half){
            int c = half*256 + tid;
            int row = c >> 2;
            int kg = ((c & 3) ^ ((row >> 1) & 3))*8;   // pre-swizzled global slot
            gload16(gAh + (long)(m0+row)*lda + k0 + kg, &shA[sel][c*8]);
            gload16(gBh + (long)(n0+row)*Kc  + k0 + kg, &shB[sel][c*8]);
        }
    };

    const int nsteps = kend >> 5;
    stage(0, 0);
    if (1 < nsteps) stage(1, 1<<5);
    const int swr = (quad ^ ((r16 >> 1) & 3))*8;       // undo swizzle on read
    for (int t = 0; t < nsteps; ++t){
        if (t+1 < nsteps) asm volatile("s_waitcnt vmcnt(4)" ::: "memory");
        else              asm volatile("s_waitcnt vmcnt(0)" ::: "memory");
        __builtin_amdgcn_s_barrier();
        if (t+2 < nsteps) stage((t+2)%3, (t+2)<<5);
        const int rd = t % 3;
        bf16x8 afh[4], bfh[4];
        #pragma unroll
        for (int i=0;i<4;i++){
            afh[i] = *(const bf16x8*)&shA[rd][(wm+i*16+r16)*32 + swr];
            bfh[i] = *(const bf16x8*)&shB[rd][(wn+i*16+r16)*32 + swr];
        }
        #pragma unroll
        for (int i=0;i<4;i++)
            #pragma unroll
            for (int j=0;j<4;j++)
                acc[i][j] = __builtin_amdgcn_mfma_f32_16x16x32_bf16(afh[i], bfh[j], acc[i][j], 0,0,0);
    }
    #pragma unroll
    for (int i=0;i<4;i++){
        #pragma unroll
        for (int j=0;j<4;j++){
            int gc = n0 + wn + j*16 + r16;
            if (gc >= Nc) continue;
            float bv = bias ? bias[gc] : 0.f;
            #pragma unroll
            for (int r=0;r<4;r++){
                long gr = m0 + wm + i*16 + quad*4 + r;
                float v = acc[i][j][r] + bv;
                if (act) v = gelu_tanh(v);
                long o = (long)bz*sC + gr*Nc + gc;
                if (C) C[o] = v;
                if (Chi){ u16 t = f2bf(v); Chi[o] = t; if (Clo) Clo[o] = f2bf(v - bf2f(t)); }
            }
        }
    }
}

// ---------------------------------------------------------------- MFMA GEMM 128x128, 3-product via VIRTUAL K
// K_virt = 3*Kc; segment 0: Ah*Bh, 1: Al*Bh, 2: Ah*Bl (pointer switch in staging).
// NBUF=3: counted-vmcnt single-barrier pipeline (grid-limited projections).
// NBUF=2: proven depth-2 __syncthreads path (4.5-blk/CU S-GEMM; 32KB LDS).
// swzmode 1: 8x4 supertile remap. swzmode 2: XCD-slice pinning.
// cskip=1 (causal): skip above-diagonal tiles AND stores.
// Optional 2nd problem (QKV+SQSK concurrency): by >= ycut switches operand set.
// dvec != 0: epilogue stores the final attention score -0.5*acc + 0.5*dvec[col]
// (bit-identical to the FMA softmax used to do).
template<int NBUF>
__global__ __launch_bounds__(256) void gemm_v3_k(
    const u16* __restrict__ Ah, const u16* __restrict__ Al,
    const u16* __restrict__ Bh, const u16* __restrict__ Bl,
    float* __restrict__ C,
    int M, int Kc, int Nc, int lda,
    long sA, long sB, long sC, int cskip, int swzmode,
    const u16* __restrict__ Ah2, const u16* __restrict__ Al2,
    const u16* __restrict__ Bh2, const u16* __restrict__ Bl2,
    float* __restrict__ C2, int ycut, int Nc2,
    const float* __restrict__ dvec)
{
    __shared__ u16 shA[NBUF][128*32], shB[NBUF][128*32];
    int bx = blockIdx.x, by = blockIdx.y, bz = blockIdx.z;
    if (swzmode == 1){
        int lin = bx + gridDim.x*by;
        int within = lin & 31, st = lin >> 5;
        int stm = gridDim.x >> 3;
        bx = (st % stm)*8 + (within & 7);
        by = (st / stm)*4 + (within >> 3);
    } else if (swzmode == 2){
        int lin = bx + gridDim.x*(by + gridDim.y*bz);
        int xcd = lin & 7, idx = lin >> 3;
        bz = xcd + 8*(idx >> 6);
        int tile = idx & 63;
        bx = tile & 7; by = tile >> 3;
    }
    if (ycut && by >= ycut){
        Ah = Ah2; Al = Al2; Bh = Bh2; Bl = Bl2; C = C2;
        by -= ycut; Nc = Nc2;
    }
    const int m0 = bx*128, n0 = by*128;
    if (cskip == 1 && n0 > m0 + 127) return;
    const u16* gAh = Ah + (long)bz*sA;
    const u16* gAl = Al + (long)bz*sA;
    const u16* gBh = Bh + (long)bz*sB;
    const u16* gBl = Bl + (long)bz*sB;
    const int tid = threadIdx.x;
    const int wave = tid >> 6, lane = tid & 63;
    const int quad = lane >> 4, r16 = lane & 15;
    const int wm = (wave>>1)*64, wn = (wave&1)*64;

    f32x4 acc[4][4];
    #pragma unroll
    for (int i=0;i<4;i++)
        #pragma unroll
        for (int j=0;j<4;j++) acc[i][j] = (f32x4){0.f,0.f,0.f,0.f};

    const int segsteps = Kc >> 5;
    const int nsteps = 3*segsteps;
    auto stage = [&](int sel, int t){
        int seg = (t >= segsteps) + (t >= 2*segsteps);
        int k0 = (t - seg*segsteps) << 5;
        const u16* a = (seg==1) ? gAl : gAh;
        const u16* b = (seg==2) ? gBl : gBh;
        #pragma unroll
        for (int half=0; half<2; ++half){
            int c = half*256 + tid;
            int row = c >> 2;
            int kg = ((c & 3) ^ ((row >> 1) & 3))*8;
            gload16(a + (long)(m0+row)*lda + k0 + kg, &shA[sel][c*8]);
            gload16(b + (long)(n0+row)*Kc  + k0 + kg, &shB[sel][c*8]);
        }
    };

    const int swr = (quad ^ ((r16 >> 1) & 3))*8;
    if constexpr (NBUF == 2){
        stage(0, 0);
        __syncthreads();
        int cur = 0;
        for (int t = 0; t < nsteps; ++t){
            if (t+1 < nsteps) stage(cur^1, t+1);
            bf16x8 afh[4], bfh[4];
            #pragma unroll
            for (int i=0;i<4;i++){
                afh[i] = *(const bf16x8*)&shA[cur][(wm+i*16+r16)*32 + swr];
                bfh[i] = *(const bf16x8*)&shB[cur][(wn+i*16+r16)*32 + swr];
            }
            #pragma unroll
            for (int i=0;i<4;i++)
                #pragma unroll
                for (int j=0;j<4;j++)
                    acc[i][j] = __builtin_amdgcn_mfma_f32_16x16x32_bf16(afh[i], bfh[j], acc[i][j], 0,0,0);
            __syncthreads();
            cur ^= 1;
        }
    } else {
        stage(0, 0);
        if (1 < nsteps) stage(1, 1);
        for (int t = 0; t < nsteps; ++t){
            if (t+1 < nsteps) asm volatile("s_waitcnt vmcnt(4)" ::: "memory");
            else              asm volatile("s_waitcnt vmcnt(0)" ::: "memory");
            __builtin_amdgcn_s_barrier();
            if (t+2 < nsteps) stage((t+2)%3, t+2);
            const int rd = t % 3;
            bf16x8 afh[4], bfh[4];
            #pragma unroll
            for (int i=0;i<4;i++){
                afh[i] = *(const bf16x8*)&shA[rd][(wm+i*16+r16)*32 + swr];
                bfh[i] = *(const bf16x8*)&shB[rd][(wn+i*16+r16)*32 + swr];
            }
            #pragma unroll
            for (int i=0;i<4;i++)
                #pragma unroll
                for (int j=0;j<4;j++)
                    acc[i][j] = __builtin_amdgcn_mfma_f32_16x16x32_bf16(afh[i], bfh[j], acc[i][j], 0,0,0);
        }
    }
    float dv4[4];
    if (dvec){
        #pragma unroll
        for (int j=0;j<4;j++)
            dv4[j] = 0.5f*dvec[(size_t)bz*NN + n0 + wn + j*16 + r16];
    }
    #pragma unroll
    for (int i=0;i<4;i++){
        #pragma unroll
        for (int j=0;j<4;j++){
            int gc = n0 + wn + j*16 + r16;
            if (gc >= Nc) continue;
            #pragma unroll
            for (int r=0;r<4;r++){
                long gr = m0 + wm + i*16 + quad*4 + r;
                if (cskip == 1 && gc > gr) continue;   // above-diagonal: never read
                long o = (long)bz*sC + gr*Nc + gc;
                float v = acc[i][j][r];
                if (dvec) v = -0.5f*v + dv4[j];
                C[o] = v;
            }
        }
    }
}

// ---------------------------------------------------------------- transport GEMM 64x64:
// out[r][n] = sum_g (esign*phi[r][g]) * sum_kd A[r][kd]*gen[g][n][kd]
// = virtual-K GEMM over GF[n*1536 + g*512 + kd] with per-segment register fold.
__global__ __launch_bounds__(256) void tgemm_k(
    const u16* __restrict__ Ahh,   // [M][512] bf16
    const u16* __restrict__ GFh,   // [n][g*512+kd]
    const float* __restrict__ phi, float esign,
    float* __restrict__ C, u16* __restrict__ Chi, u16* __restrict__ Clo,
    const float* __restrict__ t_x, const float* __restrict__ t_a1,
    const float* __restrict__ t_res)
{
    __shared__ u16 shA[2][64*64], shB[2][64*64];
    const int m0 = blockIdx.x*64, n0 = blockIdx.y*64;
    const int tid = threadIdx.x;
    const int wave = tid >> 6, lane = tid & 63;
    const int quad = lane >> 4, r16 = lane & 15;
    const int wr = wave*16;

    float ph[3][4];
    #pragma unroll
    for (int sgi=0; sgi<3; ++sgi)
        #pragma unroll
        for (int r=0; r<4; ++r)
            ph[sgi][r] = esign*phi[(size_t)(m0+wr+quad*4+r)*3 + sgi];

    f32x4 acc[4], tot[4];
    #pragma unroll
    for (int j=0;j<4;j++){ acc[j] = (f32x4){0.f,0.f,0.f,0.f}; tot[j] = acc[j]; }

    auto stage = [&](int sel, int t){
        int seg = t >> 3, k0 = (t & 7) << 6;
        #pragma unroll
        for (int rep=0; rep<2; ++rep){
            int c = rep*256 + tid;
            int row = c >> 3;
            int kg = ((c & 7) ^ (row & 7))*8;
            gload16(Ahh + (long)(m0+row)*KK + k0 + kg, &shA[sel][c*8]);
            gload16(GFh + (long)(n0+row)*(3*KK) + seg*KK + k0 + kg, &shB[sel][c*8]);
        }
    };

    stage(0, 0);
    __syncthreads();
    int cur = 0;
    for (int t = 0; t < 24; ++t){
        if (t+1 < 24) stage(cur^1, t+1);
        #pragma unroll
        for (int kk=0; kk<2; ++kk){
            const int s = (((kk<<2)+quad) ^ (r16 & 7))*8;
            bf16x8 af = *(const bf16x8*)&shA[cur][(wr+r16)*64 + s];
            #pragma unroll
            for (int j=0;j<4;j++){
                bf16x8 bh = *(const bf16x8*)&shB[cur][(j*16+r16)*64 + s];
                acc[j] = __builtin_amdgcn_mfma_f32_16x16x32_bf16(af, bh, acc[j], 0,0,0);
            }
        }
        if ((t & 7) == 7){
            int sgi = t >> 3;
            #pragma unroll
            for (int j=0;j<4;j++){
                #pragma unroll
                for (int r=0;r<4;r++) tot[j][r] += ph[sgi][r]*acc[j][r];
                acc[j] = (f32x4){0.f,0.f,0.f,0.f};
            }
        }
        __syncthreads();
        cur ^= 1;
    }
    #pragma unroll
    for (int j=0;j<4;j++){
        int gc = n0 + j*16 + r16;
        #pragma unroll
        for (int r=0;r<4;r++){
            long gr = m0 + wr + quad*4 + r;
            float v = tot[j][r];
            long o = gr*(long)KK + gc;
            if (t_x){
                v = t_x[o] + t_a1[o] + 0.5f*v;
                if (t_res) v += t_res[o];
            }
            if (C) C[o] = v;
            if (Chi){ u16 t2 = f2bf(v); Chi[o] = t2; if (Clo) Clo[o] = f2bf(v - bf2f(t2)); }
        }
    }
}

// ---------------------------------------------------------------- MFMA GEMM 64x64
// depth-2 / single-__syncthreads pipeline, 32KB LDS. K-step 64.
// swz=1: 8x4 supertile remap. epilogue: fused FFN update (fmode 1=mid, 2=final)
__global__ __launch_bounds__(256) void gemm64_k(
    const u16* __restrict__ Ah, const u16* __restrict__ Bh,
    float* __restrict__ C, u16* __restrict__ Chi, u16* __restrict__ Clo,
    int M, int Kc, int Nc, int lda,
    long sA, long sB, long sC, const float* __restrict__ bias, int act,
    int ktrim, int swz,
    const float* __restrict__ f_hin, const float* __restrict__ f_bmh,
    const float* __restrict__ f_mup, const float* __restrict__ f_lr,
    u16* __restrict__ f_hh, float* __restrict__ f_hout,
    const float* __restrict__ f_mrb, const float* __restrict__ f_mn2,
    float* __restrict__ f_out, int fmode)
{
    __shared__ u16 shA[2][64*64], shB[2][64*64];
    int bx = blockIdx.x, by = blockIdx.y;
    if (swz){
        int lin = bx + gridDim.x*by;
        int within = lin & 31, st = lin >> 5;
        int stm = gridDim.x >> 3;
        bx = (st % stm)*8 + (within & 7);
        by = (st / stm)*4 + (within >> 3);
    }
    const int m0 = bx*64, n0 = by*64;
    const int bz = blockIdx.z;
    const u16* gA = Ah + (long)bz*sA;
    const u16* gB = Bh + (long)bz*sB;
    const int tid = threadIdx.x;
    const int wave = tid >> 6, lane = tid & 63;
    const int quad = lane >> 4, r16 = lane & 15;
    const int wr = wave*16;
    const int kend = ktrim ? min(Kc, m0 + 64) : Kc;
    const int nsteps = kend >> 6;

    f32x4 acc[4];
    #pragma unroll
    for (int j=0;j<4;j++) acc[j] = (f32x4){0.f,0.f,0.f,0.f};

    auto stage = [&](int sel, int k0){
        #pragma unroll
        for (int rep=0; rep<2; ++rep){
            int c = rep*256 + tid;
            int row = c >> 3;
            int kg = ((c & 7) ^ (row & 7))*8;     // pre-swizzled global slot
            gload16(gA + (long)(m0+row)*lda + k0 + kg, &shA[sel][c*8]);
            gload16(gB + (long)(n0+row)*Kc + k0 + kg, &shB[sel][c*8]);
        }
    };

    stage(0, 0);
    __syncthreads();
    int cur = 0;
    for (int t = 0; t < nsteps; ++t){
        if (t+1 < nsteps) stage(cur^1, (t+1)<<6);
        #pragma unroll
        for (int kk=0; kk<2; ++kk){
            const int s = (((kk<<2)+quad) ^ (r16 & 7))*8;   // undo swizzle on read
            bf16x8 af = *(const bf16x8*)&shA[cur][(wr+r16)*64 + s];
            #pragma unroll
            for (int j=0;j<4;j++){
                bf16x8 bh = *(const bf16x8*)&shB[cur][(j*16+r16)*64 + s];
                acc[j] = __builtin_amdgcn_mfma_f32_16x16x32_bf16(af, bh, acc[j], 0,0,0);
            }
        }
        __syncthreads();
        cur ^= 1;
    }
    float lrv = 0.f;
    if (fmode) lrv = *f_lr;
    #pragma unroll
    for (int j=0;j<4;j++){
        int gc = n0 + j*16 + r16;
        float bv = bias ? bias[gc] : 0.f;
        #pragma unroll
        for (int r=0;r<4;r++){
            long gr = m0 + wr + quad*4 + r;
            float v = acc[j][r] + bv;
            if (act) v = gelu_tanh(v);
            long o = (long)bz*sC + gr*Nc + gc;
            if (fmode){
                float hv = f_hin[o];
                float val = hv + lrv*(v - (1e-3f*(hv - f_mup[o]) + (hv - f_bmh[o])));
                if (fmode == 1){ f_hout[o] = val; f_hh[o] = f2bf(val); }
                else           { f_out[o] = f_mrb[o] + val - f_mn2[o]; }
            } else {
                if (C) C[o] = v;
                if (Chi){ u16 t = f2bf(v); Chi[o] = t; if (Clo) Clo[o] = f2bf(v - bf2f(t)); }
            }
        }
    }
}

// ---------------------------------------------------------------- LayerNorm (+bf16 out, +sigma split, +output copies)
__global__ __launch_bounds__(256) void ln_k(
    const float* __restrict__ x, const float* __restrict__ g,
    const float* __restrict__ be, float* __restrict__ y,
    u16* __restrict__ yh16,
    const float* __restrict__ sg, u16* __restrict__ sgh, u16* __restrict__ sgl,
    float* __restrict__ osig, const float* __restrict__ phi, float* __restrict__ ophi)
{
    __shared__ float sh[8];
    const int r = blockIdx.x, tid = threadIdx.x;
    const float* xr = x + (long)r*KK;
    float2 v = *(const float2*)(xr + tid*2);
    float s = v.x+v.y, s2 = v.x*v.x+v.y*v.y;
    #pragma unroll
    for (int o=32;o>0;o>>=1){ s += __shfl_down(s,o); s2 += __shfl_down(s2,o); }
    if ((tid&63)==0){ sh[tid>>6]=s; sh[4+(tid>>6)]=s2; }
    __syncthreads();
    s  = sh[0]+sh[1]+sh[2]+sh[3];
    s2 = sh[4]+sh[5]+sh[6]+sh[7];
    const float mean = s*(1.f/KK);
    const float var  = s2*(1.f/KK) - mean*mean;
    const float rs = rsqrtf(var + 1e-5f);
    float2 gg = *(const float2*)(g + tid*2);
    float2 bb = *(const float2*)(be + tid*2);
    float ox = (v.x-mean)*rs*gg.x + bb.x;
    float oy = (v.y-mean)*rs*gg.y + bb.y;
    long o = (long)r*KK + tid*2;
    *(float2*)(y + o) = make_float2(ox, oy);
    if (yh16){ yh16[o] = f2bf(ox); yh16[o+1] = f2bf(oy); }
    if (sgh){
        float2 sv = *(const float2*)(sg + o);
        wsplit(sgh, sgl, o,   sv.x);
        wsplit(sgh, sgl, o+1, sv.y);
        if (osig) *(float2*)(osig + o) = sv;
    }
    if (ophi && tid < 3) ophi[(size_t)r*3 + tid] = phi[(size_t)r*3 + tid];
}

// ---------------------------------------------------------------- merged attention prep + V transpose
__global__ __launch_bounds__(512) void prepvt_k(
    const float* __restrict__ QKV, const float* __restrict__ SQSK,
    u16* __restrict__ CFh, u16* __restrict__ CFl,
    u16* __restrict__ KSh, u16* __restrict__ KSl, float* __restrict__ dvec,
    u16* __restrict__ VTh)
{
    __shared__ float t[64][65];
    const int bx = blockIdx.x;
    const int tid = threadIdx.x;
    if (bx < BN){
        const int bn = bx;
        const int b = bn / NN, n = bn % NN;
        const int h = tid >> 6, d = tid & 63;
        float q  = QKV[(size_t)bn*1536 + h*DHh + d];
        float k  = QKV[(size_t)bn*1536 + KK + h*DHh + d];
        float sq = SQSK[(size_t)bn*1024 + h*DHh + d] + 1e-8f;
        float sk = SQSK[(size_t)bn*1024 + KK + h*DHh + d] + 1e-8f;
        float inv = 1.f/sq;
        float nqi = -2.f*q*inv;
        float skk = sk + k*k;
        const size_t base = ((size_t)(h*BB + b)*NN + n)*128;
        wsplit(CFh, CFl, base+d,    inv);
        wsplit(CFh, CFl, base+64+d, nqi);
        wsplit(KSh, KSl, base+d,    skk);
        wsplit(KSh, KSl, base+64+d, k);
        float dv = __logf(sk);
        #pragma unroll
        for (int o=32;o>0;o>>=1) dv += __shfl_down(dv,o);
        if (d==0) dvec[((size_t)h*BB + b)*NN + n] = dv;
        return;
    }
    const int idx = bx - BN;
    const int n0 = (idx & 15)*64;
    const int h = (idx>>4)&7;
    const int b = idx>>7;
    const int c4 = (tid & 15) * 4;
    const int r0 = tid >> 4;     // 0..31
    for (int rr = r0; rr < 64; rr += 32){
        float4 v = *(const float4*)(QKV + (size_t)(b*NN + n0 + rr)*1536 + 1024 + h*DHh + c4);
        t[c4+0][rr] = v.x; t[c4+1][rr] = v.y; t[c4+2][rr] = v.z; t[c4+3][rr] = v.w;
    }
    __syncthreads();
    for (int dd = r0; dd < 64; dd += 32){
        size_t base = ((size_t)(h*BB + b)*64 + dd)*NN + n0 + c4;
        #pragma unroll
        for (int q=0;q<4;q++) VTh[base+q] = f2bf(t[dd][c4+q]);
    }
}

// ---------------------------------------------------------------- softmax, all 8 heads, register-resident
// S already holds the final score (-0.5*qk + 0.5*dvec folded in the S-GEMM).
// BMh is zero-extended to the 128-aligned boundary (JEND2) so the bmh GEMM can
// use 128-row tiles with kend = m0+128 (extra terms are exact zeros).
__global__ __launch_bounds__(256) void softmax_all_k(
    float* __restrict__ S, u16* __restrict__ BMh)
{
    __shared__ float s_redA[2][4], s_redB[2][4];
    const int tid = threadIdx.x;
    const int b = blockIdx.x >> 10, i = blockIdx.x & (NN-1);
    const int L = i + 1;
    const int JEND = ((i >> 6) + 1) << 6;
    const int JEND2 = ((i >> 7) + 1) << 7;
    const int j4 = tid*4;
    const bool act = (j4 < JEND);
    const int wv = tid >> 6;
    const bool lane0 = ((tid & 63) == 0);

    float bm[4] = {0.f,0.f,0.f,0.f};
    float4 rv = make_float4(0,0,0,0);
    if (act) rv = *(const float4*)(S + ((long)(0*BB + b)*NN + i)*NN + j4);
    for (int h = 0; h < 8; ++h){
        const int z = h*BB + b;
        float4 rvn = make_float4(0,0,0,0);
        if (h < 7 && act){
            const int zn = (h+1)*BB + b;
            rvn = *(const float4*)(S + ((long)zn*NN + i)*NN + j4);
        }
        float sc[4];
        const float* rp = (const float*)&rv;
        #pragma unroll
        for (int e=0;e<4;e++)
            sc[e] = (act && (j4 + e < L)) ? rp[e] : -3.0e38f;
        float lm = fmaxf(fmaxf(sc[0],sc[1]), fmaxf(sc[2],sc[3]));
        #pragma unroll
        for (int o=32;o>0;o>>=1) lm = fmaxf(lm, __shfl_xor(lm, o));
        if (lane0) s_redA[h&1][wv] = lm;
        __syncthreads();
        const float mx = fmaxf(fmaxf(s_redA[h&1][0],s_redA[h&1][1]),
                               fmaxf(s_redA[h&1][2],s_redA[h&1][3]));
        float w4[4], ps = 0.f;
        #pragma unroll
        for (int e=0;e<4;e++){
            float e1 = (act && (j4 + e < L)) ? __expf(sc[e]-mx) : 0.f;
            w4[e] = e1; ps += e1;
        }
        #pragma unroll
        for (int o=32;o>0;o>>=1) ps += __shfl_xor(ps, o);
        if (lane0) s_redB[h&1][wv] = ps;
        __syncthreads();
        const float isum = 1.f/(s_redB[h&1][0]+s_redB[h&1][1]+s_redB[h&1][2]+s_redB[h&1][3]);
        if (act){
            u16* brow = (u16*)(S + ((long)z*NN + i)*NN);
            ushort4 st;
            float w0=w4[0]*isum, w1=w4[1]*isum, w2=w4[2]*isum, w3=w4[3]*isum;
            bm[0]+=0.125f*w0; bm[1]+=0.125f*w1; bm[2]+=0.125f*w2; bm[3]+=0.125f*w3;
            st.x=f2bf(w0); st.y=f2bf(w1); st.z=f2bf(w2); st.w=f2bf(w3);
            *(ushort4*)(brow + j4) = st;
        }
        rv = rvn;
    }
    if (j4 < JEND2){
        const long bmrow = ((long)b*NN + i)*NN;
        ushort4 st;
        st.x=f2bf(bm[0]); st.y=f2bf(bm[1]); st.z=f2bf(bm[2]); st.w=f2bf(bm[3]);
        *(ushort4*)(BMh + bmrow + j4) = st;
    }
}

// ---------------------------------------------------------------- PV, all 32 (head,batch) slices, grid (NN/64, 32)
__global__ __launch_bounds__(256) void pv_k(
    const u16* __restrict__ Sbeta,
    const u16* __restrict__ VTh,
    u16* __restrict__ xh)
{
    __shared__ u16 shA[2][64*64], shB[2][64*64];
    const int m0 = blockIdx.x*64;
    const int z = blockIdx.y;              // z = head*BB + b
    const int b = z & 3, head = z >> 2;
    const int tid = threadIdx.x;
    const int wave = tid>>6, lane = tid&63;
    const int quad = lane>>4, r16 = lane&15;
    f32x4 acc[4];
    #pragma unroll
    for (int j=0;j<4;j++) acc[j]=(f32x4){0.f,0.f,0.f,0.f};
    const int nsteps = (m0 >> 6) + 1;

    auto stage = [&](int sel, int j0){
        #pragma unroll
        for (int rep=0; rep<2; ++rep){
            int c = rep*256 + tid;
            int row = c >> 3;
            int k8 = ((c & 7) ^ (row & 7))*8;
            gload16(Sbeta + ((size_t)(z*NN + m0 + row))*(2*NN) + j0 + k8, &shA[sel][c*8]);
            gload16(VTh + ((size_t)(z*64 + row))*NN + j0 + k8, &shB[sel][c*8]);
        }
    };

    stage(0, 0);
    __syncthreads();
    int cur = 0;
    for (int t = 0; t < nsteps; ++t){
        if (t+1 < nsteps) stage(cur^1, (t+1)<<6);
        #pragma unroll
        for (int kk=0; kk<2; ++kk){
            const int s = (((kk<<2)+quad) ^ (r16 & 7))*8;
            bf16x8 af = *(const bf16x8*)&shA[cur][(wave*16 + r16)*64 + s];
            #pragma unroll
            for (int nj=0; nj<4; ++nj){
                bf16x8 bh = *(const bf16x8*)&shB[cur][(nj*16 + r16)*64 + s];
                acc[nj] = __builtin_amdgcn_mfma_f32_16x16x32_bf16(af, bh, acc[nj], 0,0,0);
            }
        }
        __syncthreads();
        cur ^= 1;
    }
    #pragma unroll
    for (int nj=0;nj<4;nj++){
        #pragma unroll
        for (int r=0;r<4;r++){
            int i = m0 + wave*16 + quad*4 + r;
            int d = nj*16 + r16;
            size_t o = ((size_t)(b*NN)+i)*KK + head*64 + d;
            xh[o] = f2bf(acc[nj][r]);
        }
    }
}

// ---------------------------------------------------------------- launch
extern "C" void kernel_launch(void* const* d_in, const int* in_sizes, int n_in,
                              void* d_out, int out_size, void* d_ws, size_t ws_size,
                              hipStream_t stream) {
    const float* mu_q    = (const float*)d_in[0];
    const float* sigma_q = (const float*)d_in[1];
    const float* phi     = (const float*)d_in[2];
    const float* gen     = (const float*)d_in[3];
    const float* mu_prior= (const float*)d_in[5];
    const float* Wq = (const float*)d_in[6];
    const float* Wk = (const float*)d_in[7];
    const float* Wv = (const float*)d_in[8];
    const float* Wo = (const float*)d_in[9];
    const float* g1 = (const float*)d_in[10];
    const float* be1= (const float*)d_in[11];
    const float* g2 = (const float*)d_in[12];
    const float* be2= (const float*)d_in[13];
    const float* W1 = (const float*)d_in[14];
    const float* bh1= (const float*)d_in[15];
    const float* W2 = (const float*)d_in[16];
    const float* bh2= (const float*)d_in[17];
    const float* lr = (const float*)d_in[18];
    float* out = (float*)d_out;

    float* w = (float*)d_ws;
    size_t off = 0;
    auto alloc = [&](size_t n){ float* p = w + off; off += (n+3)&~(size_t)3; return p; };
    auto ualloc = [&](size_t n){ return (u16*)alloc((n+1)/2); };

    // Xb..REG is one contiguous 32*NN*NN-float region reused as Sbig in phase C.
    float* Xb   = alloc((size_t)BN*KK);        // mu_n; later mn2
    float* A1b  = alloc((size_t)BN*KK);        // a1 / bmh
    float* A2b  = alloc((size_t)BN*KK);        // (spacer; part of Sbig)
    float* QKVb = alloc((size_t)BN*3*KK);      // QKV; later WOb / Hb / MRb
    float* SQSKb= alloc((size_t)BN*2*KK);
    float* REG  = alloc((size_t)16*NN*NN);     // SGh/SGl/Xh/A1h/WOh | Sbig tail | ZH
    float* Sbig = Xb;                          // 32 * NN*NN floats
    u16*  SGh   = (u16*)REG;
    u16*  SGl   = SGh + (size_t)BN*KK;
    u16*  Xh    = SGl + (size_t)BN*KK;
    u16*  A1h   = Xh  + (size_t)BN*KK;
    u16*  WOh   = A1h + (size_t)BN*KK;
    u16*  ZH    = (u16*)REG;
    float* Db_  = alloc((size_t)HH*BB*NN);
    u16* AH  = ualloc((size_t)BN*HIDd); u16* AL  = ualloc((size_t)BN*HIDd);
    u16* CFh = AH;
    u16* CFl = AH + (size_t)HH*BB*NN*128;
    u16* KSh = AL;
    u16* KSl = AL + (size_t)HH*BB*NN*128;
    u16* VTh = ualloc((size_t)HH*BB*64*NN);
    u16* GFh = ualloc((size_t)3*KK*KK);
    u16* WQKVh= ualloc((size_t)3*KK*KK); u16* WQKVl= ualloc((size_t)3*KK*KK);
    u16* WSQKh= ualloc((size_t)2*KK*KK); u16* WSQKl= ualloc((size_t)2*KK*KK);
    u16* WoTh= ualloc((size_t)KK*KK);
    u16* W1Th= ualloc((size_t)KK*HIDd);
    u16* W2Th= ualloc((size_t)KK*HIDd);
    u16* BMh = ualloc((size_t)BB*NN*NN);
    u16* HTh = ualloc((size_t)BB*KK*NN);
    float* WOb = QKVb;
    float* Hb  = QKVb + (size_t)BN*KK;
    float* MRb = QKVb + 2*(size_t)BN*KK;
    float* MN2b= Xb;
    (void)A2b;

    // ---- weight prep: one dispatch ----
    {
        dim3 gw(64, 16, 9);
        wmega_k<<<gw, 256, 0, stream>>>(Wq, Wk, Wv, Wo, W1, W2, gen,
                                        WQKVh, WQKVl, WoTh, WSQKh, WSQKl,
                                        W1Th, W2Th, GFh);
    }

    // ---- phase A: LN1 (+bf16 out, +sigma split, +output copies) + forward transport ----
    ln_k<<<BN, 256, 0, stream>>>(mu_q, g1, be1, Xb, Xh, sigma_q, SGh, SGl,
                                 out + (size_t)BN*KK, phi, out + 2*(size_t)BN*KK);
    {
        dim3 tg(BN/64, KK/64, 1);
        tgemm_k<<<tg, 256, 0, stream>>>(Xh, GFh, phi, 1.f, A1b, A1h, 0, 0, 0, 0);
        tgemm_k<<<tg, 256, 0, stream>>>(A1h, GFh, phi, 1.f, 0, AH, AL, Xb, A1b, 0);
    }

    // ---- phase B: QKV (by 0..11) + SQSK (by 12..19) in ONE dispatch ----
    {
        dim3 g(BN/128, 20, 1);
        gemm_v3_k<3><<<g, 256, 0, stream>>>(AH, AL, WQKVh, WQKVl, QKVb,
            BN, KK, 3*KK, KK, 0, 0, 0, 0, 1,
            SGh, SGl, WSQKh, WSQKl, SQSKb, 12, 2*KK, 0);
    }
    prepvt_k<<<BN + 512, 512, 0, stream>>>(QKVb, SQSKb, CFh, CFl, KSh, KSl, Db_, VTh);

    // ---- phase C: attention, all 8 heads in 3 dispatches (Sbig = Xb..REG, 134 MB)
    //      S-GEMM stores the FINAL score (dvec folded); softmax skips dvec ----
    {
        dim3 sg(NN/128, NN/128, 32);
        gemm_v3_k<2><<<sg, 256, 0, stream>>>(CFh, CFl, KSh, KSl, Sbig,
            NN, 128, NN, 128, (long)NN*128, (long)NN*128, (long)NN*NN, 1, 2,
            0, 0, 0, 0, 0, 0, 0, Db_);
        softmax_all_k<<<BB*NN, 256, 0, stream>>>(Sbig, BMh);
        dim3 pg(NN/64, 32, 1);
        pv_k<<<pg, 256, 0, stream>>>((const u16*)Sbig, VTh, AH);
    }

    // ---- phase D: output proj + back transport (fused mrb) + LN2 ----
    {
        dim3 wg(BN/64, KK/64, 1);
        gemm64_k<<<wg, 256, 0, stream>>>(AH, WoTh, WOb, WOh, 0,
            BN, KK, KK, KK, 0,0,0, nullptr, 0, 0, 0,
            0,0,0,0,0,0,0,0,0,0);
        dim3 tg(BN/64, KK/64, 1);
        tgemm_k<<<tg, 256, 0, stream>>>(WOh, GFh, phi, -1.f, A1b, A1h, 0, 0, 0, 0);
        tgemm_k<<<tg, 256, 0, stream>>>(A1h, GFh, phi, -1.f, MRb, 0, 0, WOb, A1b, mu_q);
    }
    ln_k<<<BN, 256, 0, stream>>>(MRb, g2, be2, MN2b, AH, 0, 0, 0, 0, 0, 0);

    // ---- phase E: 2 VFE iterations: split_t, then [bmh || W1] in ONE dispatch,
    //      then W2 with fused update ----
    for (int it=0; it<2; ++it){
        const float* hin = (it==0) ? MN2b : Hb;
        {
            dim3 tg(KK/32, NN/32, BB);
            split_t_k<<<tg, 256, 0, stream>>>(hin, HTh, 0, NN, KK,
                                              (long)NN*KK, (long)KK*NN, 0);
        }
        {   // merged: by<4 -> bmh (128 blocks, launched first), by>=4 -> W1 (512)
            dim3 wg1(BN/128, 4 + HIDd/128, 1);
            gemm_mfma_k<<<wg1, 256, 0, stream>>>(AH, W1Th, 0, ZH, 0,
                BN, KK, HIDd, KK, 0, 0, 0, bh1, 1, 1,
                BMh, HTh, A1b, 4);
        }
        {   // W2 + fused FFN update, supertile swizzle
            dim3 wg(BN/64, KK/64, 1);
            gemm64_k<<<wg, 256, 0, stream>>>(ZH, W2Th, 0,0,0,
                                             BN, HIDd, KK, HIDd, 0,0,0, bh2, 0, 0, 1,
                                             hin, A1b, mu_prior, lr, AH, Hb, MRb, MN2b, out,
                                             (it==0) ? 1 : 2);
        }
    }

    (void)in_sizes; (void)n_in; (void)out_size; (void)ws_size;
}

// Round 12
// 523.864 us; speedup vs baseline: 1.2203x; 1.0323x over previous
//
#include <hip/hip_runtime.h>
#include <math.h>

#define BB 4
#define NN 1024
#define KK 512
#define HH 8
#define DHh 64
#define HIDd 2048
#define BN (BB*NN)

typedef unsigned short u16;
typedef __attribute__((ext_vector_type(8))) short bf16x8;
typedef __attribute__((ext_vector_type(4))) float f32x4;

// ---------------------------------------------------------------- helpers
__device__ __forceinline__ float gelu_tanh(float x){
    // tanh-gelu via fast exp: 0.5x(1+tanh(u)) = x*t/(t+1), t=e^{2u}
    float u = 0.7978845608028654f*(x + 0.044715f*x*x*x);
    u = fminf(fmaxf(u, -15.f), 15.f);
    float t = __expf(2.f*u);
    return x*t/(t+1.f);
}
__device__ __forceinline__ u16 f2bf(float x){
    unsigned int u = __float_as_uint(x);
    unsigned int r = (u + 0x7fffu + ((u>>16)&1u)) >> 16;
    return (u16)r;
}
__device__ __forceinline__ float bf2f(u16 b){
    return __uint_as_float(((unsigned int)b)<<16);
}
__device__ __forceinline__ void gload16(const void* g, void* l){
    __builtin_amdgcn_global_load_lds((__attribute__((address_space(1))) void*)g,
                                     (__attribute__((address_space(3))) void*)l, 16, 0, 0);
}
__device__ __forceinline__ void wsplit(u16* hi, u16* lo, size_t o, float v){
    u16 h = f2bf(v);
    hi[o] = h;
    if (lo) lo[o] = f2bf(v - bf2f(h));
}

// ---------------------------------------------------------------- generic transpose-split (used for h^T in phase E)
__global__ __launch_bounds__(256) void split_t_k(
    const float* __restrict__ src, u16* __restrict__ hi, u16* __restrict__ lo,
    int Kc, int Nc, long sS, long sD, int square)
{
    __shared__ float t[32][33];
    const int n0 = blockIdx.x*32, k0 = blockIdx.y*32, bz = blockIdx.z;
    const float* S = src + (long)bz*sS;
    const int tx = threadIdx.x & 31, ty = threadIdx.x >> 5;
    for (int r = ty; r < 32; r += 8){
        float v = S[(long)(k0+r)*Nc + n0+tx];
        if (square) v *= v;
        t[r][tx] = v;
    }
    __syncthreads();
    for (int r = ty; r < 32; r += 8){
        float v = t[tx][r];
        long o = (long)bz*sD + (long)(n0+r)*Kc + k0 + tx;
        wsplit(hi, lo, o, v);
    }
}

// ---------------------------------------------------------------- all weight prep in one dispatch, grid (64,16,9)
__global__ __launch_bounds__(256) void wmega_k(
    const float* __restrict__ Wq, const float* __restrict__ Wk,
    const float* __restrict__ Wv, const float* __restrict__ Wo,
    const float* __restrict__ W1, const float* __restrict__ W2,
    const float* __restrict__ gen,
    u16* __restrict__ WQKVh, u16* __restrict__ WQKVl, u16* __restrict__ WoTh,
    u16* __restrict__ WSQKh, u16* __restrict__ WSQKl,
    u16* __restrict__ W1Th, u16* __restrict__ W2Th, u16* __restrict__ GFh)
{
    const int z = blockIdx.z;
    const int tid = threadIdx.x;
    if (z == 8){   // gflat: copy gen(3,K,K) -> GFh[k][g*512+l]
        if (blockIdx.x >= 48) return;
        const int c0 = blockIdx.x*32, k0 = blockIdx.y*32;
        const int tx = tid&31, ty = tid>>5;
        const int g = c0/KK, l0 = c0%KK;
        for (int r=ty; r<32; r+=8)
            GFh[(size_t)(k0+r)*(3*KK) + c0+tx] =
                f2bf(gen[(size_t)g*KK*KK + (size_t)(k0+r)*KK + l0+tx]);
        return;
    }
    __shared__ float t[32][33];
    const float* src; u16* hi; u16* lo=0; int sq=0;
    int n0, k0, Kc, Nc;
    const size_t KK2 = (size_t)KK*KK;
    if (z < 6){
        if (blockIdx.x >= 16) return;
        n0 = blockIdx.x*32; k0 = blockIdx.y*32; Kc=KK; Nc=KK;
        if      (z==0){ src=Wq; hi=WQKVh;       lo=WQKVl; }
        else if (z==1){ src=Wk; hi=WQKVh+KK2;   lo=WQKVl+KK2; }
        else if (z==2){ src=Wv; hi=WQKVh+2*KK2; lo=WQKVl+2*KK2; }
        else if (z==3){ src=Wo; hi=WoTh; }
        else if (z==4){ src=Wq; hi=WSQKh;       lo=WSQKl; sq=1; }
        else          { src=Wk; hi=WSQKh+KK2;   lo=WSQKl+KK2; sq=1; }
    } else if (z == 6){  // W1 [512][2048] -> [2048][512]
        src=W1; hi=W1Th; Kc=KK; Nc=HIDd;
        n0 = blockIdx.x*32; k0 = blockIdx.y*32;
    } else {             // W2 [2048][512] -> [512][2048]
        src=W2; hi=W2Th; Kc=HIDd; Nc=KK;
        n0 = blockIdx.y*32; k0 = blockIdx.x*32;
    }
    const int tx=tid&31, ty=tid>>5;
    for (int r=ty;r<32;r+=8){
        float v = src[(long)(k0+r)*Nc + n0+tx];
        if (sq) v*=v;
        t[r][tx]=v;
    }
    __syncthreads();
    for (int r=ty;r<32;r+=8){
        float v = t[tx][r];
        long o = (long)(n0+r)*Kc + k0+tx;
        wsplit(hi, lo, o, v);
    }
}

// ---------------------------------------------------------------- MFMA GEMM 128x128, single product
// NBUF=3 counted-vmcnt single-barrier pipeline.
// swz=1: 8x4 supertile remap.
// Optional 2nd problem (bmh || W1 concurrency): blocks with by < ycut run the
// bmh GEMM  A1b[b] = BMh[b] (NNxNN, causal-trimmed K) x HTh[b] (KKxNN rows),
// reshaped to 128x128 tiles: m-tile = bx&7, batch = bx>>3, n-tile = by.
// kend = m0+128 is exact because softmax zero-extends BMh to the 128 boundary.
__global__ __launch_bounds__(256) void gemm_mfma_k(
    const u16* __restrict__ Ah, const u16* __restrict__ Bh,
    float* __restrict__ C, u16* __restrict__ Chi, u16* __restrict__ Clo,
    int M, int Kc, int Nc, int lda,
    long sA, long sB, long sC, const float* __restrict__ bias, int act,
    int swz,
    const u16* __restrict__ A2, const u16* __restrict__ B2,
    float* __restrict__ C2, int ycut)
{
    __shared__ u16 shA[3][128*32], shB[3][128*32];
    int bx = blockIdx.x, by = blockIdx.y;
    if (swz){
        int lin = bx + gridDim.x*by;
        int within = lin & 31, st = lin >> 5;
        int stm = gridDim.x >> 3;
        bx = (st % stm)*8 + (within & 7);
        by = (st / stm)*4 + (within >> 3);
    }
    int bz = blockIdx.z;
    int m0, n0, kend;
    const u16 *gAh, *gBh;
    if (ycut && by < ycut){          // problem 2: bmh
        m0 = (bx & 7)*128; n0 = by*128; bz = bx >> 3;
        gAh = A2 + (long)bz*NN*NN;
        gBh = B2 + (long)bz*KK*NN;
        Kc = NN; lda = NN; Nc = KK;
        C = C2 + (long)bz*NN*KK; Chi = 0; Clo = 0; bias = 0; act = 0; sC = 0;
        kend = m0 + 128;             // causal trim (BMh zero-extended to 128)
        bz = 0;
    } else {
        if (ycut) by -= ycut;
        m0 = bx*128; n0 = by*128;
        gAh = Ah + (long)bz*sA;
        gBh = Bh + (long)bz*sB;
        kend = Kc;
    }
    const int tid = threadIdx.x;
    const int wave = tid >> 6, lane = tid & 63;
    const int quad = lane >> 4, r16 = lane & 15;
    const int wm = (wave>>1)*64, wn = (wave&1)*64;

    f32x4 acc[4][4];
    #pragma unroll
    for (int i=0;i<4;i++)
        #pragma unroll
        for (int j=0;j<4;j++) acc[i][j] = (f32x4){0.f,0.f,0.f,0.f};

    auto stage = [&](int sel, int k0){
        #pragma unroll
        for (int half=0; half<2; ++half){
            int c = half*256 + tid;
            int row = c >> 2;
            int kg = ((c & 3) ^ ((row >> 1) & 3))*8;   // pre-swizzled global slot
            gload16(gAh + (long)(m0+row)*lda + k0 + kg, &shA[sel][c*8]);
            gload16(gBh + (long)(n0+row)*Kc  + k0 + kg, &shB[sel][c*8]);
        }
    };

    const int nsteps = kend >> 5;
    stage(0, 0);
    if (1 < nsteps) stage(1, 1<<5);
    const int swr = (quad ^ ((r16 >> 1) & 3))*8;       // undo swizzle on read
    for (int t = 0; t < nsteps; ++t){
        if (t+1 < nsteps) asm volatile("s_waitcnt vmcnt(4)" ::: "memory");
        else              asm volatile("s_waitcnt vmcnt(0)" ::: "memory");
        __builtin_amdgcn_s_barrier();
        if (t+2 < nsteps) stage((t+2)%3, (t+2)<<5);
        const int rd = t % 3;
        bf16x8 afh[4], bfh[4];
        #pragma unroll
        for (int i=0;i<4;i++){
            afh[i] = *(const bf16x8*)&shA[rd][(wm+i*16+r16)*32 + swr];
            bfh[i] = *(const bf16x8*)&shB[rd][(wn+i*16+r16)*32 + swr];
        }
        #pragma unroll
        for (int i=0;i<4;i++)
            #pragma unroll
            for (int j=0;j<4;j++)
                acc[i][j] = __builtin_amdgcn_mfma_f32_16x16x32_bf16(afh[i], bfh[j], acc[i][j], 0,0,0);
    }
    #pragma unroll
    for (int i=0;i<4;i++){
        #pragma unroll
        for (int j=0;j<4;j++){
            int gc = n0 + wn + j*16 + r16;
            if (gc >= Nc) continue;
            float bv = bias ? bias[gc] : 0.f;
            #pragma unroll
            for (int r=0;r<4;r++){
                long gr = m0 + wm + i*16 + quad*4 + r;
                float v = acc[i][j][r] + bv;
                if (act) v = gelu_tanh(v);
                long o = (long)bz*sC + gr*Nc + gc;
                if (C) C[o] = v;
                if (Chi){ u16 t = f2bf(v); Chi[o] = t; if (Clo) Clo[o] = f2bf(v - bf2f(t)); }
            }
        }
    }
}

// ---------------------------------------------------------------- MFMA GEMM 128x128, 3-product via VIRTUAL K
// K_virt = 3*Kc; segment 0: Ah*Bh, 1: Al*Bh, 2: Ah*Bl (pointer switch in staging).
// NBUF=3: counted-vmcnt single-barrier pipeline (grid-limited projections).
// NBUF=2: proven depth-2 __syncthreads path (4.5-blk/CU S-GEMM; 32KB LDS).
// swzmode 1: 8x4 supertile remap. swzmode 2: XCD-slice pinning.
// cskip=1 (causal): skip above-diagonal tiles AND stores.
// Optional 2nd problem (QKV+SQSK concurrency): by >= ycut switches operand set.
// dvec != 0: epilogue stores the final attention score -0.5*acc + 0.5*dvec[col].
template<int NBUF>
__global__ __launch_bounds__(256) void gemm_v3_k(
    const u16* __restrict__ Ah, const u16* __restrict__ Al,
    const u16* __restrict__ Bh, const u16* __restrict__ Bl,
    float* __restrict__ C,
    int M, int Kc, int Nc, int lda,
    long sA, long sB, long sC, int cskip, int swzmode,
    const u16* __restrict__ Ah2, const u16* __restrict__ Al2,
    const u16* __restrict__ Bh2, const u16* __restrict__ Bl2,
    float* __restrict__ C2, int ycut, int Nc2,
    const float* __restrict__ dvec)
{
    __shared__ u16 shA[NBUF][128*32], shB[NBUF][128*32];
    int bx = blockIdx.x, by = blockIdx.y, bz = blockIdx.z;
    if (swzmode == 1){
        int lin = bx + gridDim.x*by;
        int within = lin & 31, st = lin >> 5;
        int stm = gridDim.x >> 3;
        bx = (st % stm)*8 + (within & 7);
        by = (st / stm)*4 + (within >> 3);
    } else if (swzmode == 2){
        int lin = bx + gridDim.x*(by + gridDim.y*bz);
        int xcd = lin & 7, idx = lin >> 3;
        bz = xcd + 8*(idx >> 6);
        int tile = idx & 63;
        bx = tile & 7; by = tile >> 3;
    }
    if (ycut && by >= ycut){
        Ah = Ah2; Al = Al2; Bh = Bh2; Bl = Bl2; C = C2;
        by -= ycut; Nc = Nc2;
    }
    const int m0 = bx*128, n0 = by*128;
    if (cskip == 1 && n0 > m0 + 127) return;
    const u16* gAh = Ah + (long)bz*sA;
    const u16* gAl = Al + (long)bz*sA;
    const u16* gBh = Bh + (long)bz*sB;
    const u16* gBl = Bl + (long)bz*sB;
    const int tid = threadIdx.x;
    const int wave = tid >> 6, lane = tid & 63;
    const int quad = lane >> 4, r16 = lane & 15;
    const int wm = (wave>>1)*64, wn = (wave&1)*64;

    f32x4 acc[4][4];
    #pragma unroll
    for (int i=0;i<4;i++)
        #pragma unroll
        for (int j=0;j<4;j++) acc[i][j] = (f32x4){0.f,0.f,0.f,0.f};

    const int segsteps = Kc >> 5;
    const int nsteps = 3*segsteps;
    auto stage = [&](int sel, int t){
        int seg = (t >= segsteps) + (t >= 2*segsteps);
        int k0 = (t - seg*segsteps) << 5;
        const u16* a = (seg==1) ? gAl : gAh;
        const u16* b = (seg==2) ? gBl : gBh;
        #pragma unroll
        for (int half=0; half<2; ++half){
            int c = half*256 + tid;
            int row = c >> 2;
            int kg = ((c & 3) ^ ((row >> 1) & 3))*8;
            gload16(a + (long)(m0+row)*lda + k0 + kg, &shA[sel][c*8]);
            gload16(b + (long)(n0+row)*Kc  + k0 + kg, &shB[sel][c*8]);
        }
    };

    const int swr = (quad ^ ((r16 >> 1) & 3))*8;
    if constexpr (NBUF == 2){
        stage(0, 0);
        __syncthreads();
        int cur = 0;
        for (int t = 0; t < nsteps; ++t){
            if (t+1 < nsteps) stage(cur^1, t+1);
            bf16x8 afh[4], bfh[4];
            #pragma unroll
            for (int i=0;i<4;i++){
                afh[i] = *(const bf16x8*)&shA[cur][(wm+i*16+r16)*32 + swr];
                bfh[i] = *(const bf16x8*)&shB[cur][(wn+i*16+r16)*32 + swr];
            }
            #pragma unroll
            for (int i=0;i<4;i++)
                #pragma unroll
                for (int j=0;j<4;j++)
                    acc[i][j] = __builtin_amdgcn_mfma_f32_16x16x32_bf16(afh[i], bfh[j], acc[i][j], 0,0,0);
            __syncthreads();
            cur ^= 1;
        }
    } else {
        stage(0, 0);
        if (1 < nsteps) stage(1, 1);
        for (int t = 0; t < nsteps; ++t){
            if (t+1 < nsteps) asm volatile("s_waitcnt vmcnt(4)" ::: "memory");
            else              asm volatile("s_waitcnt vmcnt(0)" ::: "memory");
            __builtin_amdgcn_s_barrier();
            if (t+2 < nsteps) stage((t+2)%3, t+2);
            const int rd = t % 3;
            bf16x8 afh[4], bfh[4];
            #pragma unroll
            for (int i=0;i<4;i++){
                afh[i] = *(const bf16x8*)&shA[rd][(wm+i*16+r16)*32 + swr];
                bfh[i] = *(const bf16x8*)&shB[rd][(wn+i*16+r16)*32 + swr];
            }
            #pragma unroll
            for (int i=0;i<4;i++)
                #pragma unroll
                for (int j=0;j<4;j++)
                    acc[i][j] = __builtin_amdgcn_mfma_f32_16x16x32_bf16(afh[i], bfh[j], acc[i][j], 0,0,0);
        }
    }
    float dv4[4];
    if (dvec){
        #pragma unroll
        for (int j=0;j<4;j++)
            dv4[j] = 0.5f*dvec[(size_t)bz*NN + n0 + wn + j*16 + r16];
    }
    #pragma unroll
    for (int i=0;i<4;i++){
        #pragma unroll
        for (int j=0;j<4;j++){
            int gc = n0 + wn + j*16 + r16;
            if (gc >= Nc) continue;
            #pragma unroll
            for (int r=0;r<4;r++){
                long gr = m0 + wm + i*16 + quad*4 + r;
                if (cskip == 1 && gc > gr) continue;   // above-diagonal: never read
                long o = (long)bz*sC + gr*Nc + gc;
                float v = acc[i][j][r];
                if (dvec) v = -0.5f*v + dv4[j];
                C[o] = v;
            }
        }
    }
}

// ---------------------------------------------------------------- transport GEMM 64x64:
// out[r][n] = sum_g (esign*phi[r][g]) * sum_kd A[r][kd]*gen[g][n][kd]
// = virtual-K GEMM over GF[n*1536 + g*512 + kd] with per-segment register fold.
// NBUF=3 counted-vmcnt single-barrier pipeline (48KB LDS; grid-limited 2 blk/CU).
__global__ __launch_bounds__(256) void tgemm_k(
    const u16* __restrict__ Ahh,   // [M][512] bf16
    const u16* __restrict__ GFh,   // [n][g*512+kd]
    const float* __restrict__ phi, float esign,
    float* __restrict__ C, u16* __restrict__ Chi, u16* __restrict__ Clo,
    const float* __restrict__ t_x, const float* __restrict__ t_a1,
    const float* __restrict__ t_res)
{
    __shared__ u16 shA[3][64*64], shB[3][64*64];
    const int m0 = blockIdx.x*64, n0 = blockIdx.y*64;
    const int tid = threadIdx.x;
    const int wave = tid >> 6, lane = tid & 63;
    const int quad = lane >> 4, r16 = lane & 15;
    const int wr = wave*16;

    float ph[3][4];
    #pragma unroll
    for (int sgi=0; sgi<3; ++sgi)
        #pragma unroll
        for (int r=0; r<4; ++r)
            ph[sgi][r] = esign*phi[(size_t)(m0+wr+quad*4+r)*3 + sgi];

    f32x4 acc[4], tot[4];
    #pragma unroll
    for (int j=0;j<4;j++){ acc[j] = (f32x4){0.f,0.f,0.f,0.f}; tot[j] = acc[j]; }

    auto stage = [&](int sel, int t){
        int seg = t >> 3, k0 = (t & 7) << 6;
        #pragma unroll
        for (int rep=0; rep<2; ++rep){
            int c = rep*256 + tid;
            int row = c >> 3;
            int kg = ((c & 7) ^ (row & 7))*8;
            gload16(Ahh + (long)(m0+row)*KK + k0 + kg, &shA[sel][c*8]);
            gload16(GFh + (long)(n0+row)*(3*KK) + seg*KK + k0 + kg, &shB[sel][c*8]);
        }
    };

    stage(0, 0);
    stage(1, 1);
    for (int t = 0; t < 24; ++t){
        if (t+1 < 24) asm volatile("s_waitcnt vmcnt(4)" ::: "memory");
        else          asm volatile("s_waitcnt vmcnt(0)" ::: "memory");
        __builtin_amdgcn_s_barrier();
        if (t+2 < 24) stage((t+2)%3, t+2);
        const int rd = t % 3;
        #pragma unroll
        for (int kk=0; kk<2; ++kk){
            const int s = (((kk<<2)+quad) ^ (r16 & 7))*8;
            bf16x8 af = *(const bf16x8*)&shA[rd][(wr+r16)*64 + s];
            #pragma unroll
            for (int j=0;j<4;j++){
                bf16x8 bh = *(const bf16x8*)&shB[rd][(j*16+r16)*64 + s];
                acc[j] = __builtin_amdgcn_mfma_f32_16x16x32_bf16(af, bh, acc[j], 0,0,0);
            }
        }
        if ((t & 7) == 7){
            int sgi = t >> 3;
            #pragma unroll
            for (int j=0;j<4;j++){
                #pragma unroll
                for (int r=0;r<4;r++) tot[j][r] += ph[sgi][r]*acc[j][r];
                acc[j] = (f32x4){0.f,0.f,0.f,0.f};
            }
        }
    }
    #pragma unroll
    for (int j=0;j<4;j++){
        int gc = n0 + j*16 + r16;
        #pragma unroll
        for (int r=0;r<4;r++){
            long gr = m0 + wr + quad*4 + r;
            float v = tot[j][r];
            long o = gr*(long)KK + gc;
            if (t_x){
                v = t_x[o] + t_a1[o] + 0.5f*v;
                if (t_res) v += t_res[o];
            }
            if (C) C[o] = v;
            if (Chi){ u16 t2 = f2bf(v); Chi[o] = t2; if (Clo) Clo[o] = f2bf(v - bf2f(t2)); }
        }
    }
}

// ---------------------------------------------------------------- MFMA GEMM 64x64
// NBUF=3 counted-vmcnt single-barrier pipeline, 48KB LDS (grid-limited 2 blk/CU).
// swz=1: 8x4 supertile remap. epilogue: fused FFN update (fmode 1=mid, 2=final)
__global__ __launch_bounds__(256) void gemm64_k(
    const u16* __restrict__ Ah, const u16* __restrict__ Bh,
    float* __restrict__ C, u16* __restrict__ Chi, u16* __restrict__ Clo,
    int M, int Kc, int Nc, int lda,
    long sA, long sB, long sC, const float* __restrict__ bias, int act,
    int ktrim, int swz,
    const float* __restrict__ f_hin, const float* __restrict__ f_bmh,
    const float* __restrict__ f_mup, const float* __restrict__ f_lr,
    u16* __restrict__ f_hh, float* __restrict__ f_hout,
    const float* __restrict__ f_mrb, const float* __restrict__ f_mn2,
    float* __restrict__ f_out, int fmode)
{
    __shared__ u16 shA[3][64*64], shB[3][64*64];
    int bx = blockIdx.x, by = blockIdx.y;
    if (swz){
        int lin = bx + gridDim.x*by;
        int within = lin & 31, st = lin >> 5;
        int stm = gridDim.x >> 3;
        bx = (st % stm)*8 + (within & 7);
        by = (st / stm)*4 + (within >> 3);
    }
    const int m0 = bx*64, n0 = by*64;
    const int bz = blockIdx.z;
    const u16* gA = Ah + (long)bz*sA;
    const u16* gB = Bh + (long)bz*sB;
    const int tid = threadIdx.x;
    const int wave = tid >> 6, lane = tid & 63;
    const int quad = lane >> 4, r16 = lane & 15;
    const int wr = wave*16;
    const int kend = ktrim ? min(Kc, m0 + 64) : Kc;
    const int nsteps = kend >> 6;

    f32x4 acc[4];
    #pragma unroll
    for (int j=0;j<4;j++) acc[j] = (f32x4){0.f,0.f,0.f,0.f};

    auto stage = [&](int sel, int k0){
        #pragma unroll
        for (int rep=0; rep<2; ++rep){
            int c = rep*256 + tid;
            int row = c >> 3;
            int kg = ((c & 7) ^ (row & 7))*8;     // pre-swizzled global slot
            gload16(gA + (long)(m0+row)*lda + k0 + kg, &shA[sel][c*8]);
            gload16(gB + (long)(n0+row)*Kc + k0 + kg, &shB[sel][c*8]);
        }
    };

    stage(0, 0);
    if (1 < nsteps) stage(1, 1<<6);
    for (int t = 0; t < nsteps; ++t){
        if (t+1 < nsteps) asm volatile("s_waitcnt vmcnt(4)" ::: "memory");
        else              asm volatile("s_waitcnt vmcnt(0)" ::: "memory");
        __builtin_amdgcn_s_barrier();
        if (t+2 < nsteps) stage((t+2)%3, (t+2)<<6);
        const int rd = t % 3;
        #pragma unroll
        for (int kk=0; kk<2; ++kk){
            const int s = (((kk<<2)+quad) ^ (r16 & 7))*8;   // undo swizzle on read
            bf16x8 af = *(const bf16x8*)&shA[rd][(wr+r16)*64 + s];
            #pragma unroll
            for (int j=0;j<4;j++){
                bf16x8 bh = *(const bf16x8*)&shB[rd][(j*16+r16)*64 + s];
                acc[j] = __builtin_amdgcn_mfma_f32_16x16x32_bf16(af, bh, acc[j], 0,0,0);
            }
        }
    }
    float lrv = 0.f;
    if (fmode) lrv = *f_lr;
    #pragma unroll
    for (int j=0;j<4;j++){
        int gc = n0 + j*16 + r16;
        float bv = bias ? bias[gc] : 0.f;
        #pragma unroll
        for (int r=0;r<4;r++){
            long gr = m0 + wr + quad*4 + r;
            float v = acc[j][r] + bv;
            if (act) v = gelu_tanh(v);
            long o = (long)bz*sC + gr*Nc + gc;
            if (fmode){
                float hv = f_hin[o];
                float val = hv + lrv*(v - (1e-3f*(hv - f_mup[o]) + (hv - f_bmh[o])));
                if (fmode == 1){ f_hout[o] = val; f_hh[o] = f2bf(val); }
                else           { f_out[o] = f_mrb[o] + val - f_mn2[o]; }
            } else {
                if (C) C[o] = v;
                if (Chi){ u16 t = f2bf(v); Chi[o] = t; if (Clo) Clo[o] = f2bf(v - bf2f(t)); }
            }
        }
    }
}

// ---------------------------------------------------------------- LayerNorm (+bf16 out, +sigma split, +output copies)
__global__ __launch_bounds__(256) void ln_k(
    const float* __restrict__ x, const float* __restrict__ g,
    const float* __restrict__ be, float* __restrict__ y,
    u16* __restrict__ yh16,
    const float* __restrict__ sg, u16* __restrict__ sgh, u16* __restrict__ sgl,
    float* __restrict__ osig, const float* __restrict__ phi, float* __restrict__ ophi)
{
    __shared__ float sh[8];
    const int r = blockIdx.x, tid = threadIdx.x;
    const float* xr = x + (long)r*KK;
    float2 v = *(const float2*)(xr + tid*2);
    float s = v.x+v.y, s2 = v.x*v.x+v.y*v.y;
    #pragma unroll
    for (int o=32;o>0;o>>=1){ s += __shfl_down(s,o); s2 += __shfl_down(s2,o); }
    if ((tid&63)==0){ sh[tid>>6]=s; sh[4+(tid>>6)]=s2; }
    __syncthreads();
    s  = sh[0]+sh[1]+sh[2]+sh[3];
    s2 = sh[4]+sh[5]+sh[6]+sh[7];
    const float mean = s*(1.f/KK);
    const float var  = s2*(1.f/KK) - mean*mean;
    const float rs = rsqrtf(var + 1e-5f);
    float2 gg = *(const float2*)(g + tid*2);
    float2 bb = *(const float2*)(be + tid*2);
    float ox = (v.x-mean)*rs*gg.x + bb.x;
    float oy = (v.y-mean)*rs*gg.y + bb.y;
    long o = (long)r*KK + tid*2;
    *(float2*)(y + o) = make_float2(ox, oy);
    if (yh16){ yh16[o] = f2bf(ox); yh16[o+1] = f2bf(oy); }
    if (sgh){
        float2 sv = *(const float2*)(sg + o);
        wsplit(sgh, sgl, o,   sv.x);
        wsplit(sgh, sgl, o+1, sv.y);
        if (osig) *(float2*)(osig + o) = sv;
    }
    if (ophi && tid < 3) ophi[(size_t)r*3 + tid] = phi[(size_t)r*3 + tid];
}

// ---------------------------------------------------------------- merged attention prep + V transpose
__global__ __launch_bounds__(512) void prepvt_k(
    const float* __restrict__ QKV, const float* __restrict__ SQSK,
    u16* __restrict__ CFh, u16* __restrict__ CFl,
    u16* __restrict__ KSh, u16* __restrict__ KSl, float* __restrict__ dvec,
    u16* __restrict__ VTh)
{
    __shared__ float t[64][65];
    const int bx = blockIdx.x;
    const int tid = threadIdx.x;
    if (bx < BN){
        const int bn = bx;
        const int b = bn / NN, n = bn % NN;
        const int h = tid >> 6, d = tid & 63;
        float q  = QKV[(size_t)bn*1536 + h*DHh + d];
        float k  = QKV[(size_t)bn*1536 + KK + h*DHh + d];
        float sq = SQSK[(size_t)bn*1024 + h*DHh + d] + 1e-8f;
        float sk = SQSK[(size_t)bn*1024 + KK + h*DHh + d] + 1e-8f;
        float inv = 1.f/sq;
        float nqi = -2.f*q*inv;
        float skk = sk + k*k;
        const size_t base = ((size_t)(h*BB + b)*NN + n)*128;
        wsplit(CFh, CFl, base+d,    inv);
        wsplit(CFh, CFl, base+64+d, nqi);
        wsplit(KSh, KSl, base+d,    skk);
        wsplit(KSh, KSl, base+64+d, k);
        float dv = __logf(sk);
        #pragma unroll
        for (int o=32;o>0;o>>=1) dv += __shfl_down(dv,o);
        if (d==0) dvec[((size_t)h*BB + b)*NN + n] = dv;
        return;
    }
    const int idx = bx - BN;
    const int n0 = (idx & 15)*64;
    const int h = (idx>>4)&7;
    const int b = idx>>7;
    const int c4 = (tid & 15) * 4;
    const int r0 = tid >> 4;     // 0..31
    for (int rr = r0; rr < 64; rr += 32){
        float4 v = *(const float4*)(QKV + (size_t)(b*NN + n0 + rr)*1536 + 1024 + h*DHh + c4);
        t[c4+0][rr] = v.x; t[c4+1][rr] = v.y; t[c4+2][rr] = v.z; t[c4+3][rr] = v.w;
    }
    __syncthreads();
    for (int dd = r0; dd < 64; dd += 32){
        size_t base = ((size_t)(h*BB + b)*64 + dd)*NN + n0 + c4;
        #pragma unroll
        for (int q=0;q<4;q++) VTh[base+q] = f2bf(t[dd][c4+q]);
    }
}

// ---------------------------------------------------------------- softmax, all 8 heads, register-resident
// S already holds the final score (-0.5*qk + 0.5*dvec folded in the S-GEMM).
// BMh is zero-extended to the 128-aligned boundary (JEND2) so the bmh GEMM can
// use 128-row tiles with kend = m0+128 (extra terms are exact zeros).
__global__ __launch_bounds__(256) void softmax_all_k(
    float* __restrict__ S, u16* __restrict__ BMh)
{
    __shared__ float s_redA[2][4], s_redB[2][4];
    const int tid = threadIdx.x;
    const int b = blockIdx.x >> 10, i = blockIdx.x & (NN-1);
    const int L = i + 1;
    const int JEND = ((i >> 6) + 1) << 6;
    const int JEND2 = ((i >> 7) + 1) << 7;
    const int j4 = tid*4;
    const bool act = (j4 < JEND);
    const int wv = tid >> 6;
    const bool lane0 = ((tid & 63) == 0);

    float bm[4] = {0.f,0.f,0.f,0.f};
    float4 rv = make_float4(0,0,0,0);
    if (act) rv = *(const float4*)(S + ((long)(0*BB + b)*NN + i)*NN + j4);
    for (int h = 0; h < 8; ++h){
        const int z = h*BB + b;
        float4 rvn = make_float4(0,0,0,0);
        if (h < 7 && act){
            const int zn = (h+1)*BB + b;
            rvn = *(const float4*)(S + ((long)zn*NN + i)*NN + j4);
        }
        float sc[4];
        const float* rp = (const float*)&rv;
        #pragma unroll
        for (int e=0;e<4;e++)
            sc[e] = (act && (j4 + e < L)) ? rp[e] : -3.0e38f;
        float lm = fmaxf(fmaxf(sc[0],sc[1]), fmaxf(sc[2],sc[3]));
        #pragma unroll
        for (int o=32;o>0;o>>=1) lm = fmaxf(lm, __shfl_xor(lm, o));
        if (lane0) s_redA[h&1][wv] = lm;
        __syncthreads();
        const float mx = fmaxf(fmaxf(s_redA[h&1][0],s_redA[h&1][1]),
                               fmaxf(s_redA[h&1][2],s_redA[h&1][3]));
        float w4[4], ps = 0.f;
        #pragma unroll
        for (int e=0;e<4;e++){
            float e1 = (act && (j4 + e < L)) ? __expf(sc[e]-mx) : 0.f;
            w4[e] = e1; ps += e1;
        }
        #pragma unroll
        for (int o=32;o>0;o>>=1) ps += __shfl_xor(ps, o);
        if (lane0) s_redB[h&1][wv] = ps;
        __syncthreads();
        const float isum = 1.f/(s_redB[h&1][0]+s_redB[h&1][1]+s_redB[h&1][2]+s_redB[h&1][3]);
        if (act){
            u16* brow = (u16*)(S + ((long)z*NN + i)*NN);
            ushort4 st;
            float w0=w4[0]*isum, w1=w4[1]*isum, w2=w4[2]*isum, w3=w4[3]*isum;
            bm[0]+=0.125f*w0; bm[1]+=0.125f*w1; bm[2]+=0.125f*w2; bm[3]+=0.125f*w3;
            st.x=f2bf(w0); st.y=f2bf(w1); st.z=f2bf(w2); st.w=f2bf(w3);
            *(ushort4*)(brow + j4) = st;
        }
        rv = rvn;
    }
    if (j4 < JEND2){
        const long bmrow = ((long)b*NN + i)*NN;
        ushort4 st;
        st.x=f2bf(bm[0]); st.y=f2bf(bm[1]); st.z=f2bf(bm[2]); st.w=f2bf(bm[3]);
        *(ushort4*)(BMh + bmrow + j4) = st;
    }
}

// ---------------------------------------------------------------- PV, all 32 (head,batch) slices, grid (NN/64, 32)
__global__ __launch_bounds__(256) void pv_k(
    const u16* __restrict__ Sbeta,
    const u16* __restrict__ VTh,
    u16* __restrict__ xh)
{
    __shared__ u16 shA[2][64*64], shB[2][64*64];
    const int m0 = blockIdx.x*64;
    const int z = blockIdx.y;              // z = head*BB + b
    const int b = z & 3, head = z >> 2;
    const int tid = threadIdx.x;
    const int wave = tid>>6, lane = tid&63;
    const int quad = lane>>4, r16 = lane&15;
    f32x4 acc[4];
    #pragma unroll
    for (int j=0;j<4;j++) acc[j]=(f32x4){0.f,0.f,0.f,0.f};
    const int nsteps = (m0 >> 6) + 1;

    auto stage = [&](int sel, int j0){
        #pragma unroll
        for (int rep=0; rep<2; ++rep){
            int c = rep*256 + tid;
            int row = c >> 3;
            int k8 = ((c & 7) ^ (row & 7))*8;
            gload16(Sbeta + ((size_t)(z*NN + m0 + row))*(2*NN) + j0 + k8, &shA[sel][c*8]);
            gload16(VTh + ((size_t)(z*64 + row))*NN + j0 + k8, &shB[sel][c*8]);
        }
    };

    stage(0, 0);
    __syncthreads();
    int cur = 0;
    for (int t = 0; t < nsteps; ++t){
        if (t+1 < nsteps) stage(cur^1, (t+1)<<6);
        #pragma unroll
        for (int kk=0; kk<2; ++kk){
            const int s = (((kk<<2)+quad) ^ (r16 & 7))*8;
            bf16x8 af = *(const bf16x8*)&shA[cur][(wave*16 + r16)*64 + s];
            #pragma unroll
            for (int nj=0; nj<4; ++nj){
                bf16x8 bh = *(const bf16x8*)&shB[cur][(nj*16 + r16)*64 + s];
                acc[nj] = __builtin_amdgcn_mfma_f32_16x16x32_bf16(af, bh, acc[nj], 0,0,0);
            }
        }
        __syncthreads();
        cur ^= 1;
    }
    #pragma unroll
    for (int nj=0;nj<4;nj++){
        #pragma unroll
        for (int r=0;r<4;r++){
            int i = m0 + wave*16 + quad*4 + r;
            int d = nj*16 + r16;
            size_t o = ((size_t)(b*NN)+i)*KK + head*64 + d;
            xh[o] = f2bf(acc[nj][r]);
        }
    }
}

// ---------------------------------------------------------------- launch
extern "C" void kernel_launch(void* const* d_in, const int* in_sizes, int n_in,
                              void* d_out, int out_size, void* d_ws, size_t ws_size,
                              hipStream_t stream) {
    const float* mu_q    = (const float*)d_in[0];
    const float* sigma_q = (const float*)d_in[1];
    const float* phi     = (const float*)d_in[2];
    const float* gen     = (const float*)d_in[3];
    const float* mu_prior= (const float*)d_in[5];
    const float* Wq = (const float*)d_in[6];
    const float* Wk = (const float*)d_in[7];
    const float* Wv = (const float*)d_in[8];
    const float* Wo = (const float*)d_in[9];
    const float* g1 = (const float*)d_in[10];
    const float* be1= (const float*)d_in[11];
    const float* g2 = (const float*)d_in[12];
    const float* be2= (const float*)d_in[13];
    const float* W1 = (const float*)d_in[14];
    const float* bh1= (const float*)d_in[15];
    const float* W2 = (const float*)d_in[16];
    const float* bh2= (const float*)d_in[17];
    const float* lr = (const float*)d_in[18];
    float* out = (float*)d_out;

    float* w = (float*)d_ws;
    size_t off = 0;
    auto alloc = [&](size_t n){ float* p = w + off; off += (n+3)&~(size_t)3; return p; };
    auto ualloc = [&](size_t n){ return (u16*)alloc((n+1)/2); };

    // Xb..REG is one contiguous 32*NN*NN-float region reused as Sbig in phase C.
    float* Xb   = alloc((size_t)BN*KK);        // mu_n; later mn2
    float* A1b  = alloc((size_t)BN*KK);        // a1 / bmh
    float* A2b  = alloc((size_t)BN*KK);        // (spacer; part of Sbig)
    float* QKVb = alloc((size_t)BN*3*KK);      // QKV; later WOb / Hb / MRb
    float* SQSKb= alloc((size_t)BN*2*KK);
    float* REG  = alloc((size_t)16*NN*NN);     // SGh/SGl/Xh/A1h/WOh | Sbig tail | ZH
    float* Sbig = Xb;                          // 32 * NN*NN floats
    u16*  SGh   = (u16*)REG;
    u16*  SGl   = SGh + (size_t)BN*KK;
    u16*  Xh    = SGl + (size_t)BN*KK;
    u16*  A1h   = Xh  + (size_t)BN*KK;
    u16*  WOh   = A1h + (size_t)BN*KK;
    u16*  ZH    = (u16*)REG;
    float* Db_  = alloc((size_t)HH*BB*NN);
    u16* AH  = ualloc((size_t)BN*HIDd); u16* AL  = ualloc((size_t)BN*HIDd);
    u16* CFh = AH;
    u16* CFl = AH + (size_t)HH*BB*NN*128;
    u16* KSh = AL;
    u16* KSl = AL + (size_t)HH*BB*NN*128;
    u16* VTh = ualloc((size_t)HH*BB*64*NN);
    u16* GFh = ualloc((size_t)3*KK*KK);
    u16* WQKVh= ualloc((size_t)3*KK*KK); u16* WQKVl= ualloc((size_t)3*KK*KK);
    u16* WSQKh= ualloc((size_t)2*KK*KK); u16* WSQKl= ualloc((size_t)2*KK*KK);
    u16* WoTh= ualloc((size_t)KK*KK);
    u16* W1Th= ualloc((size_t)KK*HIDd);
    u16* W2Th= ualloc((size_t)KK*HIDd);
    u16* BMh = ualloc((size_t)BB*NN*NN);
    u16* HTh = ualloc((size_t)BB*KK*NN);
    float* WOb = QKVb;
    float* Hb  = QKVb + (size_t)BN*KK;
    float* MRb = QKVb + 2*(size_t)BN*KK;
    float* MN2b= Xb;
    (void)A2b;

    // ---- weight prep: one dispatch ----
    {
        dim3 gw(64, 16, 9);
        wmega_k<<<gw, 256, 0, stream>>>(Wq, Wk, Wv, Wo, W1, W2, gen,
                                        WQKVh, WQKVl, WoTh, WSQKh, WSQKl,
                                        W1Th, W2Th, GFh);
    }

    // ---- phase A: LN1 (+bf16 out, +sigma split, +output copies) + forward transport ----
    ln_k<<<BN, 256, 0, stream>>>(mu_q, g1, be1, Xb, Xh, sigma_q, SGh, SGl,
                                 out + (size_t)BN*KK, phi, out + 2*(size_t)BN*KK);
    {
        dim3 tg(BN/64, KK/64, 1);
        tgemm_k<<<tg, 256, 0, stream>>>(Xh, GFh, phi, 1.f, A1b, A1h, 0, 0, 0, 0);
        tgemm_k<<<tg, 256, 0, stream>>>(A1h, GFh, phi, 1.f, 0, AH, AL, Xb, A1b, 0);
    }

    // ---- phase B: QKV (by 0..11) + SQSK (by 12..19) in ONE dispatch ----
    {
        dim3 g(BN/128, 20, 1);
        gemm_v3_k<3><<<g, 256, 0, stream>>>(AH, AL, WQKVh, WQKVl, QKVb,
            BN, KK, 3*KK, KK, 0, 0, 0, 0, 1,
            SGh, SGl, WSQKh, WSQKl, SQSKb, 12, 2*KK, 0);
    }
    prepvt_k<<<BN + 512, 512, 0, stream>>>(QKVb, SQSKb, CFh, CFl, KSh, KSl, Db_, VTh);

    // ---- phase C: attention, all 8 heads in 3 dispatches (Sbig = Xb..REG, 134 MB)
    //      S-GEMM stores the FINAL score (dvec folded); softmax skips dvec ----
    {
        dim3 sg(NN/128, NN/128, 32);
        gemm_v3_k<2><<<sg, 256, 0, stream>>>(CFh, CFl, KSh, KSl, Sbig,
            NN, 128, NN, 128, (long)NN*128, (long)NN*128, (long)NN*NN, 1, 2,
            0, 0, 0, 0, 0, 0, 0, Db_);
        softmax_all_k<<<BB*NN, 256, 0, stream>>>(Sbig, BMh);
        dim3 pg(NN/64, 32, 1);
        pv_k<<<pg, 256, 0, stream>>>((const u16*)Sbig, VTh, AH);
    }

    // ---- phase D: output proj + back transport (fused mrb) + LN2 ----
    {
        dim3 wg(BN/64, KK/64, 1);
        gemm64_k<<<wg, 256, 0, stream>>>(AH, WoTh, WOb, WOh, 0,
            BN, KK, KK, KK, 0,0,0, nullptr, 0, 0, 0,
            0,0,0,0,0,0,0,0,0,0);
        dim3 tg(BN/64, KK/64, 1);
        tgemm_k<<<tg, 256, 0, stream>>>(WOh, GFh, phi, -1.f, A1b, A1h, 0, 0, 0, 0);
        tgemm_k<<<tg, 256, 0, stream>>>(A1h, GFh, phi, -1.f, MRb, 0, 0, WOb, A1b, mu_q);
    }
    ln_k<<<BN, 256, 0, stream>>>(MRb, g2, be2, MN2b, AH, 0, 0, 0, 0, 0, 0);

    // ---- phase E: 2 VFE iterations: split_t, then [bmh || W1] in ONE dispatch,
    //      then W2 with fused update ----
    for (int it=0; it<2; ++it){
        const float* hin = (it==0) ? MN2b : Hb;
        {
            dim3 tg(KK/32, NN/32, BB);
            split_t_k<<<tg, 256, 0, stream>>>(hin, HTh, 0, NN, KK,
                                              (long)NN*KK, (long)KK*NN, 0);
        }
        {   // merged: by<4 -> bmh (128 blocks, launched first), by>=4 -> W1 (512)
            dim3 wg1(BN/128, 4 + HIDd/128, 1);
            gemm_mfma_k<<<wg1, 256, 0, stream>>>(AH, W1Th, 0, ZH, 0,
                BN, KK, HIDd, KK, 0, 0, 0, bh1, 1, 1,
                BMh, HTh, A1b, 4);
        }
        {   // W2 + fused FFN update, supertile swizzle
            dim3 wg(BN/64, KK/64, 1);
            gemm64_k<<<wg, 256, 0, stream>>>(ZH, W2Th, 0,0,0,
                                             BN, HIDd, KK, HIDd, 0,0,0, bh2, 0, 0, 1,
                                             hin, A1b, mu_prior, lr, AH, Hb, MRb, MN2b, out,
                                             (it==0) ? 1 : 2);
        }
    }

    (void)in_sizes; (void)n_in; (void)out_size; (void)ws_size;
}

// Round 14
// 517.468 us; speedup vs baseline: 1.2354x; 1.0124x over previous
//
#include <hip/hip_runtime.h>
#include <math.h>

#define BB 4
#define NN 1024
#define KK 512
#define HH 8
#define DHh 64
#define HIDd 2048
#define BN (BB*NN)

typedef unsigned short u16;
typedef __attribute__((ext_vector_type(8))) short bf16x8;
typedef __attribute__((ext_vector_type(4))) float f32x4;

// ---------------------------------------------------------------- helpers
__device__ __forceinline__ float gelu_tanh(float x){
    // tanh-gelu via fast exp: 0.5x(1+tanh(u)) = x*t/(t+1), t=e^{2u}
    float u = 0.7978845608028654f*(x + 0.044715f*x*x*x);
    u = fminf(fmaxf(u, -15.f), 15.f);
    float t = __expf(2.f*u);
    return x*t/(t+1.f);
}
__device__ __forceinline__ u16 f2bf(float x){
    unsigned int u = __float_as_uint(x);
    unsigned int r = (u + 0x7fffu + ((u>>16)&1u)) >> 16;
    return (u16)r;
}
__device__ __forceinline__ float bf2f(u16 b){
    return __uint_as_float(((unsigned int)b)<<16);
}
__device__ __forceinline__ void gload16(const void* g, void* l){
    __builtin_amdgcn_global_load_lds((__attribute__((address_space(1))) void*)g,
                                     (__attribute__((address_space(3))) void*)l, 16, 0, 0);
}
__device__ __forceinline__ void wsplit(u16* hi, u16* lo, size_t o, float v){
    u16 h = f2bf(v);
    hi[o] = h;
    if (lo) lo[o] = f2bf(v - bf2f(h));
}

// ---------------------------------------------------------------- generic transpose-split (used for h^T in phase E)
__global__ __launch_bounds__(256) void split_t_k(
    const float* __restrict__ src, u16* __restrict__ hi, u16* __restrict__ lo,
    int Kc, int Nc, long sS, long sD, int square)
{
    __shared__ float t[32][33];
    const int n0 = blockIdx.x*32, k0 = blockIdx.y*32, bz = blockIdx.z;
    const float* S = src + (long)bz*sS;
    const int tx = threadIdx.x & 31, ty = threadIdx.x >> 5;
    for (int r = ty; r < 32; r += 8){
        float v = S[(long)(k0+r)*Nc + n0+tx];
        if (square) v *= v;
        t[r][tx] = v;
    }
    __syncthreads();
    for (int r = ty; r < 32; r += 8){
        float v = t[tx][r];
        long o = (long)bz*sD + (long)(n0+r)*Kc + k0 + tx;
        wsplit(hi, lo, o, v);
    }
}

// ---------------------------------------------------------------- all weight prep in one dispatch, grid (64,16,9)
__global__ __launch_bounds__(256) void wmega_k(
    const float* __restrict__ Wq, const float* __restrict__ Wk,
    const float* __restrict__ Wv, const float* __restrict__ Wo,
    const float* __restrict__ W1, const float* __restrict__ W2,
    const float* __restrict__ gen,
    u16* __restrict__ WQKVh, u16* __restrict__ WQKVl, u16* __restrict__ WoTh,
    u16* __restrict__ WSQKh, u16* __restrict__ WSQKl,
    u16* __restrict__ W1Th, u16* __restrict__ W2Th, u16* __restrict__ GFh)
{
    const int z = blockIdx.z;
    const int tid = threadIdx.x;
    if (z == 8){   // gflat: copy gen(3,K,K) -> GFh[k][g*512+l]
        if (blockIdx.x >= 48) return;
        const int c0 = blockIdx.x*32, k0 = blockIdx.y*32;
        const int tx = tid&31, ty = tid>>5;
        const int g = c0/KK, l0 = c0%KK;
        for (int r=ty; r<32; r+=8)
            GFh[(size_t)(k0+r)*(3*KK) + c0+tx] =
                f2bf(gen[(size_t)g*KK*KK + (size_t)(k0+r)*KK + l0+tx]);
        return;
    }
    __shared__ float t[32][33];
    const float* src; u16* hi; u16* lo=0; int sq=0;
    int n0, k0, Kc, Nc;
    const size_t KK2 = (size_t)KK*KK;
    if (z < 6){
        if (blockIdx.x >= 16) return;
        n0 = blockIdx.x*32; k0 = blockIdx.y*32; Kc=KK; Nc=KK;
        if      (z==0){ src=Wq; hi=WQKVh;       lo=WQKVl; }
        else if (z==1){ src=Wk; hi=WQKVh+KK2;   lo=WQKVl+KK2; }
        else if (z==2){ src=Wv; hi=WQKVh+2*KK2; lo=WQKVl+2*KK2; }
        else if (z==3){ src=Wo; hi=WoTh; }
        else if (z==4){ src=Wq; hi=WSQKh;       lo=WSQKl; sq=1; }
        else          { src=Wk; hi=WSQKh+KK2;   lo=WSQKl+KK2; sq=1; }
    } else if (z == 6){  // W1 [512][2048] -> [2048][512]
        src=W1; hi=W1Th; Kc=KK; Nc=HIDd;
        n0 = blockIdx.x*32; k0 = blockIdx.y*32;
    } else {             // W2 [2048][512] -> [512][2048]
        src=W2; hi=W2Th; Kc=HIDd; Nc=KK;
        n0 = blockIdx.y*32; k0 = blockIdx.x*32;
    }
    const int tx=tid&31, ty=tid>>5;
    for (int r=ty;r<32;r+=8){
        float v = src[(long)(k0+r)*Nc + n0+tx];
        if (sq) v*=v;
        t[r][tx]=v;
    }
    __syncthreads();
    for (int r=ty;r<32;r+=8){
        float v = t[tx][r];
        long o = (long)(n0+r)*Kc + k0+tx;
        wsplit(hi, lo, o, v);
    }
}

// ---------------------------------------------------------------- MFMA GEMM 128x128, single product
// NBUF=3 counted-vmcnt single-barrier pipeline.
// swz=1: 8x4 supertile remap.
// Optional 2nd problem (bmh || W1 concurrency): blocks with by < ycut run the
// bmh GEMM  A1b[b] = BMh[b] (NNxNN, causal-trimmed K) x HTh[b] (KKxNN rows),
// reshaped to 128x128 tiles: m-tile = bx&7, batch = bx>>3, n-tile = by.
// kend = m0+128 is exact because softmax zero-extends BMh to the 128 boundary.
__global__ __launch_bounds__(256) void gemm_mfma_k(
    const u16* __restrict__ Ah, const u16* __restrict__ Bh,
    float* __restrict__ C, u16* __restrict__ Chi, u16* __restrict__ Clo,
    int M, int Kc, int Nc, int lda,
    long sA, long sB, long sC, const float* __restrict__ bias, int act,
    int swz,
    const u16* __restrict__ A2, const u16* __restrict__ B2,
    float* __restrict__ C2, int ycut)
{
    __shared__ u16 shA[3][128*32], shB[3][128*32];
    int bx = blockIdx.x, by = blockIdx.y;
    if (swz){
        int lin = bx + gridDim.x*by;
        int within = lin & 31, st = lin >> 5;
        int stm = gridDim.x >> 3;
        bx = (st % stm)*8 + (within & 7);
        by = (st / stm)*4 + (within >> 3);
    }
    int bz = blockIdx.z;
    int m0, n0, kend;
    const u16 *gAh, *gBh;
    if (ycut && by < ycut){          // problem 2: bmh
        m0 = (bx & 7)*128; n0 = by*128; bz = bx >> 3;
        gAh = A2 + (long)bz*NN*NN;
        gBh = B2 + (long)bz*KK*NN;
        Kc = NN; lda = NN; Nc = KK;
        C = C2 + (long)bz*NN*KK; Chi = 0; Clo = 0; bias = 0; act = 0; sC = 0;
        kend = m0 + 128;             // causal trim (BMh zero-extended to 128)
        bz = 0;
    } else {
        if (ycut) by -= ycut;
        m0 = bx*128; n0 = by*128;
        gAh = Ah + (long)bz*sA;
        gBh = Bh + (long)bz*sB;
        kend = Kc;
    }
    const int tid = threadIdx.x;
    const int wave = tid >> 6, lane = tid & 63;
    const int quad = lane >> 4, r16 = lane & 15;
    const int wm = (wave>>1)*64, wn = (wave&1)*64;

    f32x4 acc[4][4];
    #pragma unroll
    for (int i=0;i<4;i++)
        #pragma unroll
        for (int j=0;j<4;j++) acc[i][j] = (f32x4){0.f,0.f,0.f,0.f};

    auto stage = [&](int sel, int k0){
        #pragma unroll
        for (int half=0; half<2; ++half){
            int c = half*256 + tid;
            int row = c >> 2;
            int kg = ((c & 3) ^ ((row >> 1) & 3))*8;   // pre-swizzled global slot
            gload16(gAh + (long)(m0+row)*lda + k0 + kg, &shA[sel][c*8]);
            gload16(gBh + (long)(n0+row)*Kc  + k0 + kg, &shB[sel][c*8]);
        }
    };

    const int nsteps = kend >> 5;
    stage(0, 0);
    if (1 < nsteps) stage(1, 1<<5);
    const int swr = (quad ^ ((r16 >> 1) & 3))*8;       // undo swizzle on read
    for (int t = 0; t < nsteps; ++t){
        if (t+1 < nsteps) asm volatile("s_waitcnt vmcnt(4)" ::: "memory");
        else              asm volatile("s_waitcnt vmcnt(0)" ::: "memory");
        __builtin_amdgcn_s_barrier();
        if (t+2 < nsteps) stage((t+2)%3, (t+2)<<5);
        const int rd = t % 3;
        bf16x8 afh[4], bfh[4];
        #pragma unroll
        for (int i=0;i<4;i++){
            afh[i] = *(const bf16x8*)&shA[rd][(wm+i*16+r16)*32 + swr];
            bfh[i] = *(const bf16x8*)&shB[rd][(wn+i*16+r16)*32 + swr];
        }
        #pragma unroll
        for (int i=0;i<4;i++)
            #pragma unroll
            for (int j=0;j<4;j++)
                acc[i][j] = __builtin_amdgcn_mfma_f32_16x16x32_bf16(afh[i], bfh[j], acc[i][j], 0,0,0);
    }
    #pragma unroll
    for (int i=0;i<4;i++){
        #pragma unroll
        for (int j=0;j<4;j++){
            int gc = n0 + wn + j*16 + r16;
            if (gc >= Nc) continue;
            float bv = bias ? bias[gc] : 0.f;
            #pragma unroll
            for (int r=0;r<4;r++){
                long gr = m0 + wm + i*16 + quad*4 + r;
                float v = acc[i][j][r] + bv;
                if (act) v = gelu_tanh(v);
                long o = (long)bz*sC + gr*Nc + gc;
                if (C) C[o] = v;
                if (Chi){ u16 t = f2bf(v); Chi[o] = t; if (Clo) Clo[o] = f2bf(v - bf2f(t)); }
            }
        }
    }
}

// ---------------------------------------------------------------- MFMA GEMM 128x128, 3-product via VIRTUAL K
// K_virt = 3*Kc; segment 0: Ah*Bh, 1: Al*Bh, 2: Ah*Bl (pointer switch in staging).
// NBUF=3: counted-vmcnt single-barrier pipeline (grid-limited projections).
// NBUF=2: proven depth-2 __syncthreads path (4.5-blk/CU S-GEMM; 32KB LDS).
// swzmode 1: 8x4 supertile remap. swzmode 2: XCD-slice pinning.
// cskip=1 (causal): skip above-diagonal tiles AND stores.
// Optional 2nd problem (QKV+SQSK concurrency): by >= ycut switches operand set.
// dvec != 0: epilogue stores the final attention score -0.5*acc + 0.5*dvec[col].
template<int NBUF>
__global__ __launch_bounds__(256) void gemm_v3_k(
    const u16* __restrict__ Ah, const u16* __restrict__ Al,
    const u16* __restrict__ Bh, const u16* __restrict__ Bl,
    float* __restrict__ C,
    int M, int Kc, int Nc, int lda,
    long sA, long sB, long sC, int cskip, int swzmode,
    const u16* __restrict__ Ah2, const u16* __restrict__ Al2,
    const u16* __restrict__ Bh2, const u16* __restrict__ Bl2,
    float* __restrict__ C2, int ycut, int Nc2,
    const float* __restrict__ dvec)
{
    __shared__ u16 shA[NBUF][128*32], shB[NBUF][128*32];
    int bx = blockIdx.x, by = blockIdx.y, bz = blockIdx.z;
    if (swzmode == 1){
        int lin = bx + gridDim.x*by;
        int within = lin & 31, st = lin >> 5;
        int stm = gridDim.x >> 3;
        bx = (st % stm)*8 + (within & 7);
        by = (st / stm)*4 + (within >> 3);
    } else if (swzmode == 2){
        int lin = bx + gridDim.x*(by + gridDim.y*bz);
        int xcd = lin & 7, idx = lin >> 3;
        bz = xcd + 8*(idx >> 6);
        int tile = idx & 63;
        bx = tile & 7; by = tile >> 3;
    }
    if (ycut && by >= ycut){
        Ah = Ah2; Al = Al2; Bh = Bh2; Bl = Bl2; C = C2;
        by -= ycut; Nc = Nc2;
    }
    const int m0 = bx*128, n0 = by*128;
    if (cskip == 1 && n0 > m0 + 127) return;
    const u16* gAh = Ah + (long)bz*sA;
    const u16* gAl = Al + (long)bz*sA;
    const u16* gBh = Bh + (long)bz*sB;
    const u16* gBl = Bl + (long)bz*sB;
    const int tid = threadIdx.x;
    const int wave = tid >> 6, lane = tid & 63;
    const int quad = lane >> 4, r16 = lane & 15;
    const int wm = (wave>>1)*64, wn = (wave&1)*64;

    f32x4 acc[4][4];
    #pragma unroll
    for (int i=0;i<4;i++)
        #pragma unroll
        for (int j=0;j<4;j++) acc[i][j] = (f32x4){0.f,0.f,0.f,0.f};

    const int segsteps = Kc >> 5;
    const int nsteps = 3*segsteps;
    auto stage = [&](int sel, int t){
        int seg = (t >= segsteps) + (t >= 2*segsteps);
        int k0 = (t - seg*segsteps) << 5;
        const u16* a = (seg==1) ? gAl : gAh;
        const u16* b = (seg==2) ? gBl : gBh;
        #pragma unroll
        for (int half=0; half<2; ++half){
            int c = half*256 + tid;
            int row = c >> 2;
            int kg = ((c & 3) ^ ((row >> 1) & 3))*8;
            gload16(a + (long)(m0+row)*lda + k0 + kg, &shA[sel][c*8]);
            gload16(b + (long)(n0+row)*Kc  + k0 + kg, &shB[sel][c*8]);
        }
    };

    const int swr = (quad ^ ((r16 >> 1) & 3))*8;
    if constexpr (NBUF == 2){
        stage(0, 0);
        __syncthreads();
        int cur = 0;
        for (int t = 0; t < nsteps; ++t){
            if (t+1 < nsteps) stage(cur^1, t+1);
            bf16x8 afh[4], bfh[4];
            #pragma unroll
            for (int i=0;i<4;i++){
                afh[i] = *(const bf16x8*)&shA[cur][(wm+i*16+r16)*32 + swr];
                bfh[i] = *(const bf16x8*)&shB[cur][(wn+i*16+r16)*32 + swr];
            }
            #pragma unroll
            for (int i=0;i<4;i++)
                #pragma unroll
                for (int j=0;j<4;j++)
                    acc[i][j] = __builtin_amdgcn_mfma_f32_16x16x32_bf16(afh[i], bfh[j], acc[i][j], 0,0,0);
            __syncthreads();
            cur ^= 1;
        }
    } else {
        stage(0, 0);
        if (1 < nsteps) stage(1, 1);
        for (int t = 0; t < nsteps; ++t){
            if (t+1 < nsteps) asm volatile("s_waitcnt vmcnt(4)" ::: "memory");
            else              asm volatile("s_waitcnt vmcnt(0)" ::: "memory");
            __builtin_amdgcn_s_barrier();
            if (t+2 < nsteps) stage((t+2)%3, t+2);
            const int rd = t % 3;
            bf16x8 afh[4], bfh[4];
            #pragma unroll
            for (int i=0;i<4;i++){
                afh[i] = *(const bf16x8*)&shA[rd][(wm+i*16+r16)*32 + swr];
                bfh[i] = *(const bf16x8*)&shB[rd][(wn+i*16+r16)*32 + swr];
            }
            #pragma unroll
            for (int i=0;i<4;i++)
                #pragma unroll
                for (int j=0;j<4;j++)
                    acc[i][j] = __builtin_amdgcn_mfma_f32_16x16x32_bf16(afh[i], bfh[j], acc[i][j], 0,0,0);
        }
    }
    float dv4[4];
    if (dvec){
        #pragma unroll
        for (int j=0;j<4;j++)
            dv4[j] = 0.5f*dvec[(size_t)bz*NN + n0 + wn + j*16 + r16];
    }
    #pragma unroll
    for (int i=0;i<4;i++){
        #pragma unroll
        for (int j=0;j<4;j++){
            int gc = n0 + wn + j*16 + r16;
            if (gc >= Nc) continue;
            #pragma unroll
            for (int r=0;r<4;r++){
                long gr = m0 + wm + i*16 + quad*4 + r;
                if (cskip == 1 && gc > gr) continue;   // above-diagonal: never read
                long o = (long)bz*sC + gr*Nc + gc;
                float v = acc[i][j][r];
                if (dvec) v = -0.5f*v + dv4[j];
                C[o] = v;
            }
        }
    }
}

// ---------------------------------------------------------------- transport GEMM 64x64:
// out[r][n] = sum_g (esign*phi[r][g]) * sum_kd A[r][kd]*gen[g][n][kd]
// = virtual-K GEMM over GF[n*1536 + g*512 + kd] with per-segment register fold.
// NBUF=3 counted-vmcnt single-barrier pipeline (48KB LDS; grid-limited 2 blk/CU).
__global__ __launch_bounds__(256) void tgemm_k(
    const u16* __restrict__ Ahh,   // [M][512] bf16
    const u16* __restrict__ GFh,   // [n][g*512+kd]
    const float* __restrict__ phi, float esign,
    float* __restrict__ C, u16* __restrict__ Chi, u16* __restrict__ Clo,
    const float* __restrict__ t_x, const float* __restrict__ t_a1,
    const float* __restrict__ t_res)
{
    __shared__ u16 shA[3][64*64], shB[3][64*64];
    const int m0 = blockIdx.x*64, n0 = blockIdx.y*64;
    const int tid = threadIdx.x;
    const int wave = tid >> 6, lane = tid & 63;
    const int quad = lane >> 4, r16 = lane & 15;
    const int wr = wave*16;

    float ph[3][4];
    #pragma unroll
    for (int sgi=0; sgi<3; ++sgi)
        #pragma unroll
        for (int r=0; r<4; ++r)
            ph[sgi][r] = esign*phi[(size_t)(m0+wr+quad*4+r)*3 + sgi];

    f32x4 acc[4], tot[4];
    #pragma unroll
    for (int j=0;j<4;j++){ acc[j] = (f32x4){0.f,0.f,0.f,0.f}; tot[j] = acc[j]; }

    auto stage = [&](int sel, int t){
        int seg = t >> 3, k0 = (t & 7) << 6;
        #pragma unroll
        for (int rep=0; rep<2; ++rep){
            int c = rep*256 + tid;
            int row = c >> 3;
            int kg = ((c & 7) ^ (row & 7))*8;
            gload16(Ahh + (long)(m0+row)*KK + k0 + kg, &shA[sel][c*8]);
            gload16(GFh + (long)(n0+row)*(3*KK) + seg*KK + k0 + kg, &shB[sel][c*8]);
        }
    };

    stage(0, 0);
    stage(1, 1);
    for (int t = 0; t < 24; ++t){
        if (t+1 < 24) asm volatile("s_waitcnt vmcnt(4)" ::: "memory");
        else          asm volatile("s_waitcnt vmcnt(0)" ::: "memory");
        __builtin_amdgcn_s_barrier();
        if (t+2 < 24) stage((t+2)%3, t+2);
        const int rd = t % 3;
        #pragma unroll
        for (int kk=0; kk<2; ++kk){
            const int s = (((kk<<2)+quad) ^ (r16 & 7))*8;
            bf16x8 af = *(const bf16x8*)&shA[rd][(wr+r16)*64 + s];
            #pragma unroll
            for (int j=0;j<4;j++){
                bf16x8 bh = *(const bf16x8*)&shB[rd][(j*16+r16)*64 + s];
                acc[j] = __builtin_amdgcn_mfma_f32_16x16x32_bf16(af, bh, acc[j], 0,0,0);
            }
        }
        if ((t & 7) == 7){
            int sgi = t >> 3;
            #pragma unroll
            for (int j=0;j<4;j++){
                #pragma unroll
                for (int r=0;r<4;r++) tot[j][r] += ph[sgi][r]*acc[j][r];
                acc[j] = (f32x4){0.f,0.f,0.f,0.f};
            }
        }
    }
    #pragma unroll
    for (int j=0;j<4;j++){
        int gc = n0 + j*16 + r16;
        #pragma unroll
        for (int r=0;r<4;r++){
            long gr = m0 + wr + quad*4 + r;
            float v = tot[j][r];
            long o = gr*(long)KK + gc;
            if (t_x){
                v = t_x[o] + t_a1[o] + 0.5f*v;
                if (t_res) v += t_res[o];
            }
            if (C) C[o] = v;
            if (Chi){ u16 t2 = f2bf(v); Chi[o] = t2; if (Clo) Clo[o] = f2bf(v - bf2f(t2)); }
        }
    }
}

// ---------------------------------------------------------------- MFMA GEMM 64x64
// NBUF=3 counted-vmcnt single-barrier pipeline, 48KB LDS (grid-limited 2 blk/CU).
// swz=1: 8x4 supertile remap. epilogue: fused FFN update (fmode 1=mid, 2=final)
__global__ __launch_bounds__(256) void gemm64_k(
    const u16* __restrict__ Ah, const u16* __restrict__ Bh,
    float* __restrict__ C, u16* __restrict__ Chi, u16* __restrict__ Clo,
    int M, int Kc, int Nc, int lda,
    long sA, long sB, long sC, const float* __restrict__ bias, int act,
    int ktrim, int swz,
    const float* __restrict__ f_hin, const float* __restrict__ f_bmh,
    const float* __restrict__ f_mup, const float* __restrict__ f_lr,
    u16* __restrict__ f_hh, float* __restrict__ f_hout,
    const float* __restrict__ f_mrb, const float* __restrict__ f_mn2,
    float* __restrict__ f_out, int fmode)
{
    __shared__ u16 shA[3][64*64], shB[3][64*64];
    int bx = blockIdx.x, by = blockIdx.y;
    if (swz){
        int lin = bx + gridDim.x*by;
        int within = lin & 31, st = lin >> 5;
        int stm = gridDim.x >> 3;
        bx = (st % stm)*8 + (within & 7);
        by = (st / stm)*4 + (within >> 3);
    }
    const int m0 = bx*64, n0 = by*64;
    const int bz = blockIdx.z;
    const u16* gA = Ah + (long)bz*sA;
    const u16* gB = Bh + (long)bz*sB;
    const int tid = threadIdx.x;
    const int wave = tid >> 6, lane = tid & 63;
    const int quad = lane >> 4, r16 = lane & 15;
    const int wr = wave*16;
    const int kend = ktrim ? min(Kc, m0 + 64) : Kc;
    const int nsteps = kend >> 6;

    f32x4 acc[4];
    #pragma unroll
    for (int j=0;j<4;j++) acc[j] = (f32x4){0.f,0.f,0.f,0.f};

    auto stage = [&](int sel, int k0){
        #pragma unroll
        for (int rep=0; rep<2; ++rep){
            int c = rep*256 + tid;
            int row = c >> 3;
            int kg = ((c & 7) ^ (row & 7))*8;     // pre-swizzled global slot
            gload16(gA + (long)(m0+row)*lda + k0 + kg, &shA[sel][c*8]);
            gload16(gB + (long)(n0+row)*Kc + k0 + kg, &shB[sel][c*8]);
        }
    };

    stage(0, 0);
    if (1 < nsteps) stage(1, 1<<6);
    for (int t = 0; t < nsteps; ++t){
        if (t+1 < nsteps) asm volatile("s_waitcnt vmcnt(4)" ::: "memory");
        else              asm volatile("s_waitcnt vmcnt(0)" ::: "memory");
        __builtin_amdgcn_s_barrier();
        if (t+2 < nsteps) stage((t+2)%3, (t+2)<<6);
        const int rd = t % 3;
        #pragma unroll
        for (int kk=0; kk<2; ++kk){
            const int s = (((kk<<2)+quad) ^ (r16 & 7))*8;   // undo swizzle on read
            bf16x8 af = *(const bf16x8*)&shA[rd][(wr+r16)*64 + s];
            #pragma unroll
            for (int j=0;j<4;j++){
                bf16x8 bh = *(const bf16x8*)&shB[rd][(j*16+r16)*64 + s];
                acc[j] = __builtin_amdgcn_mfma_f32_16x16x32_bf16(af, bh, acc[j], 0,0,0);
            }
        }
    }
    float lrv = 0.f;
    if (fmode) lrv = *f_lr;
    #pragma unroll
    for (int j=0;j<4;j++){
        int gc = n0 + j*16 + r16;
        float bv = bias ? bias[gc] : 0.f;
        #pragma unroll
        for (int r=0;r<4;r++){
            long gr = m0 + wr + quad*4 + r;
            float v = acc[j][r] + bv;
            if (act) v = gelu_tanh(v);
            long o = (long)bz*sC + gr*Nc + gc;
            if (fmode){
                float hv = f_hin[o];
                float val = hv + lrv*(v - (1e-3f*(hv - f_mup[o]) + (hv - f_bmh[o])));
                if (fmode == 1){ f_hout[o] = val; f_hh[o] = f2bf(val); }
                else           { f_out[o] = f_mrb[o] + val - f_mn2[o]; }
            } else {
                if (C) C[o] = v;
                if (Chi){ u16 t = f2bf(v); Chi[o] = t; if (Clo) Clo[o] = f2bf(v - bf2f(t)); }
            }
        }
    }
}

// ---------------------------------------------------------------- LayerNorm (+bf16 out, +sigma split, +output copies)
__global__ __launch_bounds__(256) void ln_k(
    const float* __restrict__ x, const float* __restrict__ g,
    const float* __restrict__ be, float* __restrict__ y,
    u16* __restrict__ yh16,
    const float* __restrict__ sg, u16* __restrict__ sgh, u16* __restrict__ sgl,
    float* __restrict__ osig, const float* __restrict__ phi, float* __restrict__ ophi)
{
    __shared__ float sh[8];
    const int r = blockIdx.x, tid = threadIdx.x;
    const float* xr = x + (long)r*KK;
    float2 v = *(const float2*)(xr + tid*2);
    float s = v.x+v.y, s2 = v.x*v.x+v.y*v.y;
    #pragma unroll
    for (int o=32;o>0;o>>=1){ s += __shfl_down(s,o); s2 += __shfl_down(s2,o); }
    if ((tid&63)==0){ sh[tid>>6]=s; sh[4+(tid>>6)]=s2; }
    __syncthreads();
    s  = sh[0]+sh[1]+sh[2]+sh[3];
    s2 = sh[4]+sh[5]+sh[6]+sh[7];
    const float mean = s*(1.f/KK);
    const float var  = s2*(1.f/KK) - mean*mean;
    const float rs = rsqrtf(var + 1e-5f);
    float2 gg = *(const float2*)(g + tid*2);
    float2 bb = *(const float2*)(be + tid*2);
    float ox = (v.x-mean)*rs*gg.x + bb.x;
    float oy = (v.y-mean)*rs*gg.y + bb.y;
    long o = (long)r*KK + tid*2;
    *(float2*)(y + o) = make_float2(ox, oy);
    if (yh16){ yh16[o] = f2bf(ox); yh16[o+1] = f2bf(oy); }
    if (sgh){
        float2 sv = *(const float2*)(sg + o);
        wsplit(sgh, sgl, o,   sv.x);
        wsplit(sgh, sgl, o+1, sv.y);
        if (osig) *(float2*)(osig + o) = sv;
    }
    if (ophi && tid < 3) ophi[(size_t)r*3 + tid] = phi[(size_t)r*3 + tid];
}

// ---------------------------------------------------------------- merged attention prep + V transpose
__global__ __launch_bounds__(512) void prepvt_k(
    const float* __restrict__ QKV, const float* __restrict__ SQSK,
    u16* __restrict__ CFh, u16* __restrict__ CFl,
    u16* __restrict__ KSh, u16* __restrict__ KSl, float* __restrict__ dvec,
    u16* __restrict__ VTh)
{
    __shared__ float t[64][65];
    const int bx = blockIdx.x;
    const int tid = threadIdx.x;
    if (bx < BN){
        const int bn = bx;
        const int b = bn / NN, n = bn % NN;
        const int h = tid >> 6, d = tid & 63;
        float q  = QKV[(size_t)bn*1536 + h*DHh + d];
        float k  = QKV[(size_t)bn*1536 + KK + h*DHh + d];
        float sq = SQSK[(size_t)bn*1024 + h*DHh + d] + 1e-8f;
        float sk = SQSK[(size_t)bn*1024 + KK + h*DHh + d] + 1e-8f;
        float inv = 1.f/sq;
        float nqi = -2.f*q*inv;
        float skk = sk + k*k;
        const size_t base = ((size_t)(h*BB + b)*NN + n)*128;
        wsplit(CFh, CFl, base+d,    inv);
        wsplit(CFh, CFl, base+64+d, nqi);
        wsplit(KSh, KSl, base+d,    skk);
        wsplit(KSh, KSl, base+64+d, k);
        float dv = __logf(sk);
        #pragma unroll
        for (int o=32;o>0;o>>=1) dv += __shfl_down(dv,o);
        if (d==0) dvec[((size_t)h*BB + b)*NN + n] = dv;
        return;
    }
    const int idx = bx - BN;
    const int n0 = (idx & 15)*64;
    const int h = (idx>>4)&7;
    const int b = idx>>7;
    const int c4 = (tid & 15) * 4;
    const int r0 = tid >> 4;     // 0..31
    for (int rr = r0; rr < 64; rr += 32){
        float4 v = *(const float4*)(QKV + (size_t)(b*NN + n0 + rr)*1536 + 1024 + h*DHh + c4);
        t[c4+0][rr] = v.x; t[c4+1][rr] = v.y; t[c4+2][rr] = v.z; t[c4+3][rr] = v.w;
    }
    __syncthreads();
    for (int dd = r0; dd < 64; dd += 32){
        size_t base = ((size_t)(h*BB + b)*64 + dd)*NN + n0 + c4;
        #pragma unroll
        for (int q=0;q<4;q++) VTh[base+q] = f2bf(t[dd][c4+q]);
    }
}

// ---------------------------------------------------------------- softmax, all 8 heads, register-resident, 2 barriers total
// S already holds the final score. All 8 head-rows loaded upfront (8x float4,
// static indexing); 8 independent max chains -> ONE barrier -> 8 exp/sum chains
// -> ONE barrier -> all stores. Reads complete before barrier 1, stores after
// barrier 2 => in-place overwrite safe. Same per-element op order as before.
// BMh zero-extended to the 128-aligned boundary (JEND2) for the bmh GEMM.
__global__ __launch_bounds__(256) void softmax_all_k(
    float* __restrict__ S, u16* __restrict__ BMh)
{
    __shared__ float s_redA[4][8], s_redB[4][8];
    const int tid = threadIdx.x;
    const int b = blockIdx.x >> 10, i = blockIdx.x & (NN-1);
    const int L = i + 1;
    const int JEND = ((i >> 6) + 1) << 6;
    const int JEND2 = ((i >> 7) + 1) << 7;
    const int j4 = tid*4;
    const bool act = (j4 < JEND);
    const int wv = tid >> 6;
    const bool lane0 = ((tid & 63) == 0);

    float4 rv[8];
    #pragma unroll
    for (int h=0; h<8; ++h){
        rv[h] = make_float4(0,0,0,0);
        if (act) rv[h] = *(const float4*)(S + ((long)(h*BB + b)*NN + i)*NN + j4);
    }
    float lm[8];
    #pragma unroll
    for (int h=0; h<8; ++h){
        float* rp = (float*)&rv[h];
        #pragma unroll
        for (int e=0;e<4;e++)
            rp[e] = (act && (j4 + e < L)) ? rp[e] : -3.0e38f;
        lm[h] = fmaxf(fmaxf(rp[0],rp[1]), fmaxf(rp[2],rp[3]));
    }
    #pragma unroll
    for (int h=0; h<8; ++h)
        #pragma unroll
        for (int o=32;o>0;o>>=1) lm[h] = fmaxf(lm[h], __shfl_xor(lm[h], o));
    if (lane0){
        #pragma unroll
        for (int h=0; h<8; ++h) s_redA[wv][h] = lm[h];
    }
    __syncthreads();
    float ps[8];
    #pragma unroll
    for (int h=0; h<8; ++h){
        const float mx = fmaxf(fmaxf(s_redA[0][h],s_redA[1][h]),
                               fmaxf(s_redA[2][h],s_redA[3][h]));
        float* rp = (float*)&rv[h];
        float p = 0.f;
        #pragma unroll
        for (int e=0;e<4;e++){
            float e1 = (act && (j4 + e < L)) ? __expf(rp[e]-mx) : 0.f;
            rp[e] = e1; p += e1;
        }
        ps[h] = p;
    }
    #pragma unroll
    for (int h=0; h<8; ++h)
        #pragma unroll
        for (int o=32;o>0;o>>=1) ps[h] += __shfl_xor(ps[h], o);
    if (lane0){
        #pragma unroll
        for (int h=0; h<8; ++h) s_redB[wv][h] = ps[h];
    }
    __syncthreads();
    float bm[4] = {0.f,0.f,0.f,0.f};
    #pragma unroll
    for (int h=0; h<8; ++h){
        const float isum = 1.f/(s_redB[0][h]+s_redB[1][h]+s_redB[2][h]+s_redB[3][h]);
        if (act){
            const float* rp = (const float*)&rv[h];
            u16* brow = (u16*)(S + ((long)(h*BB + b)*NN + i)*NN);
            ushort4 st;
            float w0=rp[0]*isum, w1=rp[1]*isum, w2=rp[2]*isum, w3=rp[3]*isum;
            bm[0]+=0.125f*w0; bm[1]+=0.125f*w1; bm[2]+=0.125f*w2; bm[3]+=0.125f*w3;
            st.x=f2bf(w0); st.y=f2bf(w1); st.z=f2bf(w2); st.w=f2bf(w3);
            *(ushort4*)(brow + j4) = st;
        }
    }
    if (j4 < JEND2){
        const long bmrow = ((long)b*NN + i)*NN;
        ushort4 st;
        st.x=f2bf(bm[0]); st.y=f2bf(bm[1]); st.z=f2bf(bm[2]); st.w=f2bf(bm[3]);
        *(ushort4*)(BMh + bmrow + j4) = st;
    }
}

// ---------------------------------------------------------------- PV, all 32 (head,batch) slices, grid (NN/64, 32)
// NBUF=3 counted-vmcnt single-barrier pipeline (48KB LDS; grid-limited 2 blk/CU).
__global__ __launch_bounds__(256) void pv_k(
    const u16* __restrict__ Sbeta,
    const u16* __restrict__ VTh,
    u16* __restrict__ xh)
{
    __shared__ u16 shA[3][64*64], shB[3][64*64];
    const int m0 = blockIdx.x*64;
    const int z = blockIdx.y;              // z = head*BB + b
    const int b = z & 3, head = z >> 2;
    const int tid = threadIdx.x;
    const int wave = tid>>6, lane = tid&63;
    const int quad = lane>>4, r16 = lane&15;
    f32x4 acc[4];
    #pragma unroll
    for (int j=0;j<4;j++) acc[j]=(f32x4){0.f,0.f,0.f,0.f};
    const int nsteps = (m0 >> 6) + 1;

    auto stage = [&](int sel, int j0){
        #pragma unroll
        for (int rep=0; rep<2; ++rep){
            int c = rep*256 + tid;
            int row = c >> 3;
            int k8 = ((c & 7) ^ (row & 7))*8;
            gload16(Sbeta + ((size_t)(z*NN + m0 + row))*(2*NN) + j0 + k8, &shA[sel][c*8]);
            gload16(VTh + ((size_t)(z*64 + row))*NN + j0 + k8, &shB[sel][c*8]);
        }
    };

    stage(0, 0);
    if (1 < nsteps) stage(1, 1<<6);
    for (int t = 0; t < nsteps; ++t){
        if (t+1 < nsteps) asm volatile("s_waitcnt vmcnt(4)" ::: "memory");
        else              asm volatile("s_waitcnt vmcnt(0)" ::: "memory");
        __builtin_amdgcn_s_barrier();
        if (t+2 < nsteps) stage((t+2)%3, (t+2)<<6);
        const int rd = t % 3;
        #pragma unroll
        for (int kk=0; kk<2; ++kk){
            const int s = (((kk<<2)+quad) ^ (r16 & 7))*8;
            bf16x8 af = *(const bf16x8*)&shA[rd][(wave*16 + r16)*64 + s];
            #pragma unroll
            for (int nj=0; nj<4; ++nj){
                bf16x8 bh = *(const bf16x8*)&shB[rd][(nj*16 + r16)*64 + s];
                acc[nj] = __builtin_amdgcn_mfma_f32_16x16x32_bf16(af, bh, acc[nj], 0,0,0);
            }
        }
    }
    #pragma unroll
    for (int nj=0;nj<4;nj++){
        #pragma unroll
        for (int r=0;r<4;r++){
            int i = m0 + wave*16 + quad*4 + r;
            int d = nj*16 + r16;
            size_t o = ((size_t)(b*NN)+i)*KK + head*64 + d;
            xh[o] = f2bf(acc[nj][r]);
        }
    }
}

// ---------------------------------------------------------------- launch
extern "C" void kernel_launch(void* const* d_in, const int* in_sizes, int n_in,
                              void* d_out, int out_size, void* d_ws, size_t ws_size,
                              hipStream_t stream) {
    const float* mu_q    = (const float*)d_in[0];
    const float* sigma_q = (const float*)d_in[1];
    const float* phi     = (const float*)d_in[2];
    const float* gen     = (const float*)d_in[3];
    const float* mu_prior= (const float*)d_in[5];
    const float* Wq = (const float*)d_in[6];
    const float* Wk = (const float*)d_in[7];
    const float* Wv = (const float*)d_in[8];
    const float* Wo = (const float*)d_in[9];
    const float* g1 = (const float*)d_in[10];
    const float* be1= (const float*)d_in[11];
    const float* g2 = (const float*)d_in[12];
    const float* be2= (const float*)d_in[13];
    const float* W1 = (const float*)d_in[14];
    const float* bh1= (const float*)d_in[15];
    const float* W2 = (const float*)d_in[16];
    const float* bh2= (const float*)d_in[17];
    const float* lr = (const float*)d_in[18];
    float* out = (float*)d_out;

    float* w = (float*)d_ws;
    size_t off = 0;
    auto alloc = [&](size_t n){ float* p = w + off; off += (n+3)&~(size_t)3; return p; };
    auto ualloc = [&](size_t n){ return (u16*)alloc((n+1)/2); };

    // Xb..REG is one contiguous 32*NN*NN-float region reused as Sbig in phase C.
    float* Xb   = alloc((size_t)BN*KK);        // mu_n; later mn2
    float* A1b  = alloc((size_t)BN*KK);        // a1 / bmh
    float* A2b  = alloc((size_t)BN*KK);        // (spacer; part of Sbig)
    float* QKVb = alloc((size_t)BN*3*KK);      // QKV; later WOb / Hb / MRb
    float* SQSKb= alloc((size_t)BN*2*KK);
    float* REG  = alloc((size_t)16*NN*NN);     // SGh/SGl/Xh/A1h/WOh | Sbig tail | ZH
    float* Sbig = Xb;                          // 32 * NN*NN floats
    u16*  SGh   = (u16*)REG;
    u16*  SGl   = SGh + (size_t)BN*KK;
    u16*  Xh    = SGl + (size_t)BN*KK;
    u16*  A1h   = Xh  + (size_t)BN*KK;
    u16*  WOh   = A1h + (size_t)BN*KK;
    u16*  ZH    = (u16*)REG;
    float* Db_  = alloc((size_t)HH*BB*NN);
    u16* AH  = ualloc((size_t)BN*HIDd); u16* AL  = ualloc((size_t)BN*HIDd);
    u16* CFh = AH;
    u16* CFl = AH + (size_t)HH*BB*NN*128;
    u16* KSh = AL;
    u16* KSl = AL + (size_t)HH*BB*NN*128;
    u16* VTh = ualloc((size_t)HH*BB*64*NN);
    u16* GFh = ualloc((size_t)3*KK*KK);
    u16* WQKVh= ualloc((size_t)3*KK*KK); u16* WQKVl= ualloc((size_t)3*KK*KK);
    u16* WSQKh= ualloc((size_t)2*KK*KK); u16* WSQKl= ualloc((size_t)2*KK*KK);
    u16* WoTh= ualloc((size_t)KK*KK);
    u16* W1Th= ualloc((size_t)KK*HIDd);
    u16* W2Th= ualloc((size_t)KK*HIDd);
    u16* BMh = ualloc((size_t)BB*NN*NN);
    u16* HTh = ualloc((size_t)BB*KK*NN);
    float* WOb = QKVb;
    float* Hb  = QKVb + (size_t)BN*KK;
    float* MRb = QKVb + 2*(size_t)BN*KK;
    float* MN2b= Xb;
    (void)A2b;

    // ---- weight prep: one dispatch ----
    {
        dim3 gw(64, 16, 9);
        wmega_k<<<gw, 256, 0, stream>>>(Wq, Wk, Wv, Wo, W1, W2, gen,
                                        WQKVh, WQKVl, WoTh, WSQKh, WSQKl,
                                        W1Th, W2Th, GFh);
    }

    // ---- phase A: LN1 (+bf16 out, +sigma split, +output copies) + forward transport ----
    ln_k<<<BN, 256, 0, stream>>>(mu_q, g1, be1, Xb, Xh, sigma_q, SGh, SGl,
                                 out + (size_t)BN*KK, phi, out + 2*(size_t)BN*KK);
    {
        dim3 tg(BN/64, KK/64, 1);
        tgemm_k<<<tg, 256, 0, stream>>>(Xh, GFh, phi, 1.f, A1b, A1h, 0, 0, 0, 0);
        tgemm_k<<<tg, 256, 0, stream>>>(A1h, GFh, phi, 1.f, 0, AH, AL, Xb, A1b, 0);
    }

    // ---- phase B: QKV (by 0..11) + SQSK (by 12..19) in ONE dispatch ----
    {
        dim3 g(BN/128, 20, 1);
        gemm_v3_k<3><<<g, 256, 0, stream>>>(AH, AL, WQKVh, WQKVl, QKVb,
            BN, KK, 3*KK, KK, 0, 0, 0, 0, 1,
            SGh, SGl, WSQKh, WSQKl, SQSKb, 12, 2*KK, 0);
    }
    prepvt_k<<<BN + 512, 512, 0, stream>>>(QKVb, SQSKb, CFh, CFl, KSh, KSl, Db_, VTh);

    // ---- phase C: attention, all 8 heads in 3 dispatches (Sbig = Xb..REG, 134 MB)
    //      S-GEMM stores the FINAL score (dvec folded); softmax skips dvec ----
    {
        dim3 sg(NN/128, NN/128, 32);
        gemm_v3_k<2><<<sg, 256, 0, stream>>>(CFh, CFl, KSh, KSl, Sbig,
            NN, 128, NN, 128, (long)NN*128, (long)NN*128, (long)NN*NN, 1, 2,
            0, 0, 0, 0, 0, 0, 0, Db_);
        softmax_all_k<<<BB*NN, 256, 0, stream>>>(Sbig, BMh);
        dim3 pg(NN/64, 32, 1);
        pv_k<<<pg, 256, 0, stream>>>((const u16*)Sbig, VTh, AH);
    }

    // ---- phase D: output proj + back transport (fused mrb) + LN2 ----
    {
        dim3 wg(BN/64, KK/64, 1);
        gemm64_k<<<wg, 256, 0, stream>>>(AH, WoTh, WOb, WOh, 0,
            BN, KK, KK, KK, 0,0,0, nullptr, 0, 0, 0,
            0,0,0,0,0,0,0,0,0,0);
        dim3 tg(BN/64, KK/64, 1);
        tgemm_k<<<tg, 256, 0, stream>>>(WOh, GFh, phi, -1.f, A1b, A1h, 0, 0, 0, 0);
        tgemm_k<<<tg, 256, 0, stream>>>(A1h, GFh, phi, -1.f, MRb, 0, 0, WOb, A1b, mu_q);
    }
    ln_k<<<BN, 256, 0, stream>>>(MRb, g2, be2, MN2b, AH, 0, 0, 0, 0, 0, 0);

    // ---- phase E: 2 VFE iterations: split_t, then [bmh || W1] in ONE dispatch,
    //      then W2 with fused update ----
    for (int it=0; it<2; ++it){
        const float* hin = (it==0) ? MN2b : Hb;
        {
            dim3 tg(KK/32, NN/32, BB);
            split_t_k<<<tg, 256, 0, stream>>>(hin, HTh, 0, NN, KK,
                                              (long)NN*KK, (long)KK*NN, 0);
        }
        {   // merged: by<4 -> bmh (128 blocks, launched first), by>=4 -> W1 (512)
            dim3 wg1(BN/128, 4 + HIDd/128, 1);
            gemm_mfma_k<<<wg1, 256, 0, stream>>>(AH, W1Th, 0, ZH, 0,
                BN, KK, HIDd, KK, 0, 0, 0, bh1, 1, 1,
                BMh, HTh, A1b, 4);
        }
        {   // W2 + fused FFN update, supertile swizzle
            dim3 wg(BN/64, KK/64, 1);
            gemm64_k<<<wg, 256, 0, stream>>>(ZH, W2Th, 0,0,0,
                                             BN, HIDd, KK, HIDd, 0,0,0, bh2, 0, 0, 1,
                                             hin, A1b, mu_prior, lr, AH, Hb, MRb, MN2b, out,
                                             (it==0) ? 1 : 2);
        }
    }

    (void)in_sizes; (void)n_in; (void)out_size; (void)ws_size;
}